// Round 3
// baseline (2805.663 us; speedup 1.0000x reference)
//
#include <hip/hip_runtime.h>

#define NN 50000
#define NE 500000
#define NGR 64
#define HD 128
#define INF 5
#define BN_EPS 1e-5f
#define BM 64
#define KC 32

// ---------- graph norm ----------
__global__ void k_init_deg(float* deg) {
    int i = blockIdx.x * 256 + threadIdx.x;
    if (i < NN) deg[i] = 1.0f;  // self-loop weight
}

__global__ void k_deg_edges(const int* __restrict__ ei, const float* __restrict__ ea,
                            float* __restrict__ deg) {
    int e = blockIdx.x * 256 + threadIdx.x;
    if (e < NE) atomicAdd(&deg[ei[NE + e]], ea[e]);  // col = ei[1]
}

__global__ void k_dinv(float* deg) {
    int i = blockIdx.x * 256 + threadIdx.x;
    if (i < NN) {
        float d = deg[i];
        deg[i] = d > 0.f ? rsqrtf(d) : 0.f;
    }
}

// ---------- CSR build (by destination/col) ----------
__global__ void k_hist(const int* __restrict__ ei, int* __restrict__ cnt) {
    int e = blockIdx.x * 256 + threadIdx.x;
    if (e < NE) atomicAdd(&cnt[ei[NE + e]], 1);
}

// single-pass scan: per-thread serial sums + one 1024-wide block scan
__global__ void k_scan(const int* __restrict__ cnt, int* __restrict__ col_ptr) {
    __shared__ int sm[1024];
    const int C = (NN + 1023) / 1024;  // 49
    int t = threadIdx.x;
    int lo = t * C, hi = min(lo + C, NN);
    int s = 0;
    for (int i = lo; i < hi; i++) s += cnt[i];
    sm[t] = s;
    __syncthreads();
    for (int off = 1; off < 1024; off <<= 1) {
        int v = (t >= off) ? sm[t - off] : 0;
        __syncthreads();
        sm[t] += v;
        __syncthreads();
    }
    int run = (t == 0) ? 0 : sm[t - 1];  // exclusive base
    for (int i = lo; i < hi; i++) {
        col_ptr[i] = run;
        run += cnt[i];
    }
    if (t == 1023) col_ptr[NN] = sm[1023];
}

__global__ void k_scatter(const int* __restrict__ ei, const float* __restrict__ ea,
                          const float* __restrict__ dinv, const int* __restrict__ col_ptr,
                          int* __restrict__ fill, int* __restrict__ csr_src,
                          float* __restrict__ csr_w) {
    int e = blockIdx.x * 256 + threadIdx.x;
    if (e >= NE) return;
    int r = ei[e], c = ei[NE + e];
    float w = dinv[r] * ea[e] * dinv[c];
    int pos = col_ptr[c] + atomicAdd(&fill[c], 1);
    csr_src[pos] = r;
    csr_w[pos] = w;
}

// ---------- layer-0 transform: m = x @ W0  (K=5) ----------
__global__ void k_gemm0(const float* __restrict__ x, const float* __restrict__ W,
                        float* __restrict__ m) {
    __shared__ float Ws[INF][HD];
    int t = threadIdx.x;  // 256
    for (int i = t; i < INF * HD; i += 256) ((float*)Ws)[i] = W[i];
    __syncthreads();
    int row = blockIdx.x * 2 + (t >> 7);
    if (row >= NN) return;
    int c = t & 127;
    float acc = 0.f;
#pragma unroll
    for (int k = 0; k < INF; k++) acc += x[row * INF + k] * Ws[k][c];
    m[(size_t)row * HD + c] = acc;
}

// ---------- fused BN(prev)+SiLU + GEMM: m = silu(bn(hpre)) @ W ----------
// 256 threads, 64-row tile, W double-buffered in 32-row LDS chunks.
__global__ __launch_bounds__(256) void k_gemm128(
    const float* __restrict__ hpre,   // prev layer pre-BN [NN][HD]
    const float* __restrict__ stats,  // prev layer (sum, sumsq)
    const float* __restrict__ gamma, const float* __restrict__ beta,
    const float* __restrict__ W,      // [HD][HD]
    float* __restrict__ m) {
    __shared__ float hs[BM][HD];        // 32 KB
    __shared__ float Ws[2][KC][HD];     // 32 KB
    int t = threadIdx.x;
    int r0 = blockIdx.x * BM;
    const float invn = 1.0f / NN;

    // stage h tile with fused BN + SiLU (8 float4 per thread)
#pragma unroll
    for (int i = 0; i < 8; i++) {
        int idx4 = i * 256 + t;       // float4 index within tile
        int r = idx4 >> 5;            // 32 float4 per row
        int c4 = idx4 & 31;
        float4 v = make_float4(0.f, 0.f, 0.f, 0.f);
        if (r0 + r < NN) v = ((const float4*)hpre)[(size_t)(r0 + r) * 32 + c4];
        int c = c4 * 4;
#pragma unroll
        for (int q = 0; q < 4; q++) {
            float mu = stats[c + q] * invn;
            float var = stats[HD + c + q] * invn - mu * mu;
            float y = gamma[c + q] * ((&v.x)[q] - mu) * rsqrtf(var + BN_EPS) + beta[c + q];
            (&v.x)[q] = y / (1.f + __expf(-y));
        }
        ((float4*)&hs[0][0])[idx4] = v;
    }
    // stage W chunk 0
#pragma unroll
    for (int i = 0; i < 4; i++)
        ((float4*)&Ws[0][0][0])[i * 256 + t] = ((const float4*)W)[i * 256 + t];
    __syncthreads();

    int rg = t >> 5, cg = t & 31;
    int rr = rg * 8, cc = cg * 4;
    float acc[8][4];
#pragma unroll
    for (int i = 0; i < 8; i++)
#pragma unroll
        for (int j = 0; j < 4; j++) acc[i][j] = 0.f;

#pragma unroll
    for (int kb = 0; kb < HD / KC; kb++) {
        int buf = kb & 1;
        if (kb < HD / KC - 1) {  // prefetch next chunk into other buffer
#pragma unroll
            for (int i = 0; i < 4; i++)
                ((float4*)&Ws[buf ^ 1][0][0])[i * 256 + t] =
                    ((const float4*)W)[(kb + 1) * 1024 + i * 256 + t];
        }
#pragma unroll
        for (int k4 = 0; k4 < KC / 4; k4++) {
            float4 wv0 = *(const float4*)&Ws[buf][k4 * 4 + 0][cc];
            float4 wv1 = *(const float4*)&Ws[buf][k4 * 4 + 1][cc];
            float4 wv2 = *(const float4*)&Ws[buf][k4 * 4 + 2][cc];
            float4 wv3 = *(const float4*)&Ws[buf][k4 * 4 + 3][cc];
#pragma unroll
            for (int i = 0; i < 8; i++) {
                float4 hv = *(const float4*)&hs[rr + i][kb * KC + k4 * 4];
                acc[i][0] += hv.x * wv0.x + hv.y * wv1.x + hv.z * wv2.x + hv.w * wv3.x;
                acc[i][1] += hv.x * wv0.y + hv.y * wv1.y + hv.z * wv2.y + hv.w * wv3.y;
                acc[i][2] += hv.x * wv0.z + hv.y * wv1.z + hv.z * wv2.z + hv.w * wv3.z;
                acc[i][3] += hv.x * wv0.w + hv.y * wv1.w + hv.z * wv2.w + hv.w * wv3.w;
            }
        }
        __syncthreads();
    }

#pragma unroll
    for (int i = 0; i < 8; i++) {
        int r = r0 + rr + i;
        if (r < NN)
            *(float4*)&m[(size_t)r * HD + cc] =
                make_float4(acc[i][0], acc[i][1], acc[i][2], acc[i][3]);
    }
}

// ---------- sparse aggregation (CSR gather, no atomics, 4x unroll) ----------
__global__ void k_agg(const float* __restrict__ m, const int* __restrict__ col_ptr,
                      const int* __restrict__ csr_src, const float* __restrict__ csr_w,
                      const float* __restrict__ dinv, const float* __restrict__ bias,
                      float* __restrict__ hpre) {
    int node = blockIdx.x * 4 + (threadIdx.x >> 6);  // 4 waves/block, 1 node/wave
    if (node >= NN) return;
    int lane = threadIdx.x & 63;
    const float2* m2 = (const float2*)m;  // row stride 64 float2
    float di = dinv[node];
    float2 vs = m2[(size_t)node * 64 + lane];
    float a0 = di * di * vs.x;
    float a1 = di * di * vs.y;
    int beg = col_ptr[node], end = col_ptr[node + 1];
    int p = beg;
    for (; p + 4 <= end; p += 4) {
        int s0 = csr_src[p], s1 = csr_src[p + 1], s2 = csr_src[p + 2], s3 = csr_src[p + 3];
        float w0 = csr_w[p], w1 = csr_w[p + 1], w2 = csr_w[p + 2], w3 = csr_w[p + 3];
        float2 v0 = m2[(size_t)s0 * 64 + lane];
        float2 v1 = m2[(size_t)s1 * 64 + lane];
        float2 v2 = m2[(size_t)s2 * 64 + lane];
        float2 v3 = m2[(size_t)s3 * 64 + lane];
        a0 += w0 * v0.x + w1 * v1.x + w2 * v2.x + w3 * v3.x;
        a1 += w0 * v0.y + w1 * v1.y + w2 * v2.y + w3 * v3.y;
    }
    for (; p < end; p++) {
        int s = csr_src[p];
        float w = csr_w[p];
        float2 v = m2[(size_t)s * 64 + lane];
        a0 += w * v.x;
        a1 += w * v.y;
    }
    float2 b = ((const float2*)bias)[lane];
    float2 o;
    o.x = a0 + b.x;
    o.y = a1 + b.y;
    ((float2*)hpre)[(size_t)node * 64 + lane] = o;
}

// ---------- batchnorm stats (sum, sumsq per channel) ----------
__global__ void k_bnstats(const float* __restrict__ hpre, float* __restrict__ stats) {
    int t = threadIdx.x;  // channel, block = 128
    float s = 0.f, s2 = 0.f;
    for (int r = blockIdx.x; r < NN; r += gridDim.x) {
        float v = hpre[(size_t)r * HD + t];
        s += v;
        s2 += v * v;
    }
    atomicAdd(&stats[t], s);
    atomicAdd(&stats[HD + t], s2);
}

// ---------- batchnorm apply + SiLU (final layer only) ----------
__global__ void k_bnapply(const float* __restrict__ hpre, const float* __restrict__ stats,
                          const float* __restrict__ gamma, const float* __restrict__ beta,
                          float* __restrict__ h) {
    int idx = blockIdx.x * 256 + threadIdx.x;
    if (idx >= NN * HD) return;
    int c = idx & (HD - 1);
    const float invn = 1.0f / NN;
    float mu = stats[c] * invn;
    float var = stats[HD + c] * invn - mu * mu;
    float xn = (hpre[idx] - mu) * rsqrtf(var + BN_EPS);
    float y = gamma[c] * xn + beta[c];
    h[idx] = y / (1.f + __expf(-y));  // SiLU
}

// ---------- graph boundaries (batch is sorted) ----------
__global__ void k_gbounds(const int* __restrict__ batch, int* __restrict__ gstart) {
    int g = threadIdx.x;
    if (g > NGR) return;
    int lo = 0, hi = NN;
    while (lo < hi) {
        int mid = (lo + hi) >> 1;
        if (batch[mid] < g) lo = mid + 1;
        else hi = mid;
    }
    gstart[g] = lo;
}

// ---------- global mean pool: one block per graph, no atomics ----------
__global__ void k_pool(const float* __restrict__ h, const int* __restrict__ gstart,
                       float* __restrict__ pooled, float* __restrict__ gcount) {
    int g = blockIdx.x;
    int t = threadIdx.x;  // 512
    int c = t & (HD - 1);
    int ro = t >> 7;
    int beg = gstart[g], end = gstart[g + 1];
    float acc = 0.f;
    for (int r = beg + ro; r < end; r += 4) acc += h[(size_t)r * HD + c];
    __shared__ float sm[512];
    sm[t] = acc;
    __syncthreads();
    if (t < 256) sm[t] += sm[t + 256];
    __syncthreads();
    if (t < 128) {
        float cnt = (float)(end - beg);
        pooled[g * HD + t] = (sm[t] + sm[t + 128]) / fmaxf(cnt, 1.0f);
        if (t == 0) gcount[g] = cnt;
    }
}

// ---------- head MLP ----------
__global__ void k_head(const float* __restrict__ pooled, const float* __restrict__ gcount,
                       const float* __restrict__ fc1w, const float* __restrict__ fc1b,
                       const float* __restrict__ fc2w, const float* __restrict__ fc2b,
                       float* __restrict__ out) {
    int g = blockIdx.x;
    int j = threadIdx.x;  // 64 threads = 1 wave
    __shared__ float pa[HD];
    pa[j] = pooled[g * HD + j];
    pa[j + 64] = pooled[g * HD + 64 + j];
    __syncthreads();
    float a = fc1b[j];
    for (int k = 0; k < HD; k++) a += pa[k] * fc1w[k * 64 + j];
    a = a / (1.f + __expf(-a));  // SiLU
    float v = a * fc2w[j];
    for (int off = 32; off > 0; off >>= 1) v += __shfl_down(v, off);
    if (j == 0) out[g] = 1.f / (1.f + __expf(-(v + fc2b[0])));
}

extern "C" void kernel_launch(void* const* d_in, const int* in_sizes, int n_in,
                              void* d_out, int out_size, void* d_ws, size_t ws_size,
                              hipStream_t stream) {
    const float* x = (const float*)d_in[0];
    const int* ei = (const int*)d_in[1];  // [2, E]: row=ei[0..E), col=ei[E..2E)
    const float* ea = (const float*)d_in[2];
    const int* batch = (const int*)d_in[3];
    const float* conv0_w = (const float*)d_in[5];
    const float* conv0_b = (const float*)d_in[6];
    const float* conv_ws = (const float*)d_in[7];
    const float* conv_bs = (const float*)d_in[8];
    const float* bn_gamma = (const float*)d_in[9];
    const float* bn_beta = (const float*)d_in[10];
    const float* fc1w = (const float*)d_in[11];
    const float* fc1b = (const float*)d_in[12];
    const float* fc2w = (const float*)d_in[13];
    const float* fc2b = (const float*)d_in[14];
    float* out = (float*)d_out;

    char* ws = (char*)d_ws;
    size_t off = 0;
    auto alloc = [&](size_t bytes) -> char* {
        char* p = ws + off;
        off = (off + bytes + 255) & ~(size_t)255;
        return p;
    };
    float* dinv = (float*)alloc(NN * 4);
    int* cnt = (int*)alloc(NN * 4);
    int* col_ptr = (int*)alloc((NN + 1) * 4);
    int* fill = (int*)alloc(NN * 4);
    int* csr_src = (int*)alloc(NE * 4);
    float* csr_w = (float*)alloc(NE * 4);
    float* mbuf = (float*)alloc((size_t)NN * HD * 4);
    float* hA = (float*)alloc((size_t)NN * HD * 4);
    float* hB = (float*)alloc((size_t)NN * HD * 4);
    float* stats = (float*)alloc(4 * 2 * HD * 4);
    float* pooled = (float*)alloc(NGR * HD * 4);
    float* gcount = (float*)alloc(NGR * 4);
    int* gstart = (int*)alloc((NGR + 1) * 4);

    hipMemsetAsync(cnt, 0, NN * 4, stream);
    hipMemsetAsync(fill, 0, NN * 4, stream);
    hipMemsetAsync(stats, 0, 4 * 2 * HD * 4, stream);

    k_init_deg<<<(NN + 255) / 256, 256, 0, stream>>>(dinv);
    k_deg_edges<<<(NE + 255) / 256, 256, 0, stream>>>(ei, ea, dinv);
    k_dinv<<<(NN + 255) / 256, 256, 0, stream>>>(dinv);
    k_hist<<<(NE + 255) / 256, 256, 0, stream>>>(ei, cnt);
    k_scan<<<1, 1024, 0, stream>>>(cnt, col_ptr);
    k_scatter<<<(NE + 255) / 256, 256, 0, stream>>>(ei, ea, dinv, col_ptr, fill, csr_src, csr_w);
    k_gbounds<<<1, 128, 0, stream>>>(batch, gstart);

    const int NG128 = (NN + BM - 1) / BM;
    float* st0 = stats;
    float* st1 = stats + 2 * HD;
    float* st2 = stats + 4 * HD;
    float* st3 = stats + 6 * HD;

    // L0
    k_gemm0<<<(NN + 1) / 2, 256, 0, stream>>>(x, conv0_w, mbuf);
    k_agg<<<(NN + 3) / 4, 256, 0, stream>>>(mbuf, col_ptr, csr_src, csr_w, dinv, conv0_b, hA);
    k_bnstats<<<512, HD, 0, stream>>>(hA, st0);
    // L1: BN0+SiLU fused into GEMM
    k_gemm128<<<NG128, 256, 0, stream>>>(hA, st0, bn_gamma, bn_beta, conv_ws, mbuf);
    k_agg<<<(NN + 3) / 4, 256, 0, stream>>>(mbuf, col_ptr, csr_src, csr_w, dinv, conv_bs, hB);
    k_bnstats<<<512, HD, 0, stream>>>(hB, st1);
    // L2
    k_gemm128<<<NG128, 256, 0, stream>>>(hB, st1, bn_gamma + HD, bn_beta + HD,
                                         conv_ws + (size_t)HD * HD, mbuf);
    k_agg<<<(NN + 3) / 4, 256, 0, stream>>>(mbuf, col_ptr, csr_src, csr_w, dinv, conv_bs + HD, hA);
    k_bnstats<<<512, HD, 0, stream>>>(hA, st2);
    // L3
    k_gemm128<<<NG128, 256, 0, stream>>>(hA, st2, bn_gamma + 2 * HD, bn_beta + 2 * HD,
                                         conv_ws + (size_t)2 * HD * HD, mbuf);
    k_agg<<<(NN + 3) / 4, 256, 0, stream>>>(mbuf, col_ptr, csr_src, csr_w, dinv, conv_bs + 2 * HD, hB);
    k_bnstats<<<512, HD, 0, stream>>>(hB, st3);
    // final BN+SiLU, pool, head
    k_bnapply<<<(NN * HD + 255) / 256, 256, 0, stream>>>(hB, st3, bn_gamma + 3 * HD,
                                                         bn_beta + 3 * HD, hA);
    k_pool<<<NGR, 512, 0, stream>>>(hA, gstart, pooled, gcount);
    k_head<<<NGR, 64, 0, stream>>>(pooled, gcount, fc1w, fc1b, fc2w, fc2b, out);
}

// Round 4
// 762.305 us; speedup vs baseline: 3.6805x; 3.6805x over previous
//
#include <hip/hip_runtime.h>

#define NN 50000
#define NE 500000
#define NGR 64
#define HD 128
#define INF 5
#define BN_EPS 1e-5f
#define BM 64
#define KC 32

// ---------- graph norm ----------
__global__ void k_init_deg(float* deg) {
    int i = blockIdx.x * 256 + threadIdx.x;
    if (i < NN) deg[i] = 1.0f;  // self-loop weight
}

__global__ void k_deg_edges(const int* __restrict__ ei, const float* __restrict__ ea,
                            float* __restrict__ deg) {
    int e = blockIdx.x * 256 + threadIdx.x;
    if (e < NE) atomicAdd(&deg[ei[NE + e]], ea[e]);  // col = ei[1]
}

__global__ void k_dinv(float* deg) {
    int i = blockIdx.x * 256 + threadIdx.x;
    if (i < NN) {
        float d = deg[i];
        deg[i] = d > 0.f ? rsqrtf(d) : 0.f;
    }
}

// ---------- CSR build (by destination/col) ----------
__global__ void k_hist(const int* __restrict__ ei, int* __restrict__ cnt) {
    int e = blockIdx.x * 256 + threadIdx.x;
    if (e < NE) atomicAdd(&cnt[ei[NE + e]], 1);
}

// single-pass scan: per-thread serial sums + one 1024-wide block scan
__global__ void k_scan(const int* __restrict__ cnt, int* __restrict__ col_ptr) {
    __shared__ int sm[1024];
    const int C = (NN + 1023) / 1024;  // 49
    int t = threadIdx.x;
    int lo = t * C, hi = min(lo + C, NN);
    int s = 0;
    for (int i = lo; i < hi; i++) s += cnt[i];
    sm[t] = s;
    __syncthreads();
    for (int off = 1; off < 1024; off <<= 1) {
        int v = (t >= off) ? sm[t - off] : 0;
        __syncthreads();
        sm[t] += v;
        __syncthreads();
    }
    int run = (t == 0) ? 0 : sm[t - 1];  // exclusive base
    for (int i = lo; i < hi; i++) {
        col_ptr[i] = run;
        run += cnt[i];
    }
    if (t == 1023) col_ptr[NN] = sm[1023];
}

__global__ void k_scatter(const int* __restrict__ ei, const float* __restrict__ ea,
                          const float* __restrict__ dinv, const int* __restrict__ col_ptr,
                          int* __restrict__ fill, int* __restrict__ csr_src,
                          float* __restrict__ csr_w) {
    int e = blockIdx.x * 256 + threadIdx.x;
    if (e >= NE) return;
    int r = ei[e], c = ei[NE + e];
    float w = dinv[r] * ea[e] * dinv[c];
    int pos = col_ptr[c] + atomicAdd(&fill[c], 1);
    csr_src[pos] = r;
    csr_w[pos] = w;
}

// ---------- layer-0 transform: m = x @ W0  (K=5) ----------
__global__ void k_gemm0(const float* __restrict__ x, const float* __restrict__ W,
                        float* __restrict__ m) {
    __shared__ float Ws[INF][HD];
    int t = threadIdx.x;  // 256
    for (int i = t; i < INF * HD; i += 256) ((float*)Ws)[i] = W[i];
    __syncthreads();
    int row = blockIdx.x * 2 + (t >> 7);
    if (row >= NN) return;
    int c = t & 127;
    float acc = 0.f;
#pragma unroll
    for (int k = 0; k < INF; k++) acc += x[row * INF + k] * Ws[k][c];
    m[(size_t)row * HD + c] = acc;
}

// ---------- fused BN(prev)+SiLU + GEMM: m = silu(bn(hpre)) @ W ----------
// 256 threads, 64-row tile; W streamed through a single 32-row LDS chunk.
__global__ __launch_bounds__(256) void k_gemm128(
    const float* __restrict__ hpre,   // prev layer pre-BN [NN][HD]
    const float* __restrict__ stats,  // prev layer (sum, sumsq)
    const float* __restrict__ gamma, const float* __restrict__ beta,
    const float* __restrict__ W,      // [HD][HD]
    float* __restrict__ m) {
    __shared__ float hs[BM][HD];   // 32 KB
    __shared__ float Ws[KC][HD];   // 16 KB
    __shared__ float sc[HD], sh[HD];
    int t = threadIdx.x;
    int r0 = blockIdx.x * BM;
    const float invn = 1.0f / NN;

    // per-channel BN scale/shift, once
    if (t < HD) {
        float mu = stats[t] * invn;
        float var = stats[HD + t] * invn - mu * mu;
        float s = gamma[t] * rsqrtf(var + BN_EPS);
        sc[t] = s;
        sh[t] = beta[t] - mu * s;
    }
    __syncthreads();

    // stage h tile with fused BN + SiLU (8 float4 per thread)
#pragma unroll
    for (int i = 0; i < 8; i++) {
        int idx4 = i * 256 + t;  // float4 index within tile
        int r = idx4 >> 5;       // 32 float4 per row
        int c4 = idx4 & 31;
        float4 v = make_float4(0.f, 0.f, 0.f, 0.f);
        if (r0 + r < NN) v = ((const float4*)hpre)[(size_t)(r0 + r) * 32 + c4];
        int c = c4 * 4;
#pragma unroll
        for (int q = 0; q < 4; q++) {
            float y = sc[c + q] * (&v.x)[q] + sh[c + q];
            (&v.x)[q] = y / (1.f + __expf(-y));
        }
        ((float4*)&hs[0][0])[idx4] = v;
    }

    int rg = t >> 5, cg = t & 31;
    int rr = rg * 8, cc = cg * 4;
    float acc[8][4];
#pragma unroll
    for (int i = 0; i < 8; i++)
#pragma unroll
        for (int j = 0; j < 4; j++) acc[i][j] = 0.f;

#pragma unroll 1
    for (int kb = 0; kb < HD / KC; kb++) {
        __syncthreads();
        // stage W chunk (4 float4 per thread)
#pragma unroll
        for (int i = 0; i < 4; i++)
            ((float4*)&Ws[0][0])[i * 256 + t] = ((const float4*)W)[kb * 1024 + i * 256 + t];
        __syncthreads();
#pragma unroll
        for (int k4 = 0; k4 < KC / 4; k4++) {
            float4 wv0 = *(const float4*)&Ws[k4 * 4 + 0][cc];
            float4 wv1 = *(const float4*)&Ws[k4 * 4 + 1][cc];
            float4 wv2 = *(const float4*)&Ws[k4 * 4 + 2][cc];
            float4 wv3 = *(const float4*)&Ws[k4 * 4 + 3][cc];
#pragma unroll
            for (int i = 0; i < 8; i++) {
                float4 hv = *(const float4*)&hs[rr + i][kb * KC + k4 * 4];
                acc[i][0] += hv.x * wv0.x + hv.y * wv1.x + hv.z * wv2.x + hv.w * wv3.x;
                acc[i][1] += hv.x * wv0.y + hv.y * wv1.y + hv.z * wv2.y + hv.w * wv3.y;
                acc[i][2] += hv.x * wv0.z + hv.y * wv1.z + hv.z * wv2.z + hv.w * wv3.z;
                acc[i][3] += hv.x * wv0.w + hv.y * wv1.w + hv.z * wv2.w + hv.w * wv3.w;
            }
        }
    }

#pragma unroll
    for (int i = 0; i < 8; i++) {
        int r = r0 + rr + i;
        if (r < NN)
            *(float4*)&m[(size_t)r * HD + cc] =
                make_float4(acc[i][0], acc[i][1], acc[i][2], acc[i][3]);
    }
}

// ---------- sparse aggregation (CSR gather, no atomics, 4x unroll) ----------
__global__ void k_agg(const float* __restrict__ m, const int* __restrict__ col_ptr,
                      const int* __restrict__ csr_src, const float* __restrict__ csr_w,
                      const float* __restrict__ dinv, const float* __restrict__ bias,
                      float* __restrict__ hpre) {
    int node = blockIdx.x * 4 + (threadIdx.x >> 6);  // 4 waves/block, 1 node/wave
    if (node >= NN) return;
    int lane = threadIdx.x & 63;
    const float2* m2 = (const float2*)m;  // row stride 64 float2
    float di = dinv[node];
    float2 vs = m2[(size_t)node * 64 + lane];
    float a0 = di * di * vs.x;
    float a1 = di * di * vs.y;
    int beg = col_ptr[node], end = col_ptr[node + 1];
    int p = beg;
    for (; p + 4 <= end; p += 4) {
        int s0 = csr_src[p], s1 = csr_src[p + 1], s2 = csr_src[p + 2], s3 = csr_src[p + 3];
        float w0 = csr_w[p], w1 = csr_w[p + 1], w2 = csr_w[p + 2], w3 = csr_w[p + 3];
        float2 v0 = m2[(size_t)s0 * 64 + lane];
        float2 v1 = m2[(size_t)s1 * 64 + lane];
        float2 v2 = m2[(size_t)s2 * 64 + lane];
        float2 v3 = m2[(size_t)s3 * 64 + lane];
        a0 += w0 * v0.x + w1 * v1.x + w2 * v2.x + w3 * v3.x;
        a1 += w0 * v0.y + w1 * v1.y + w2 * v2.y + w3 * v3.y;
    }
    for (; p < end; p++) {
        int s = csr_src[p];
        float w = csr_w[p];
        float2 v = m2[(size_t)s * 64 + lane];
        a0 += w * v.x;
        a1 += w * v.y;
    }
    float2 b = ((const float2*)bias)[lane];
    float2 o;
    o.x = a0 + b.x;
    o.y = a1 + b.y;
    ((float2*)hpre)[(size_t)node * 64 + lane] = o;
}

// ---------- batchnorm stats (sum, sumsq per channel) ----------
__global__ void k_bnstats(const float* __restrict__ hpre, float* __restrict__ stats) {
    int t = threadIdx.x;  // channel, block = 128
    float s = 0.f, s2 = 0.f;
    for (int r = blockIdx.x; r < NN; r += gridDim.x) {
        float v = hpre[(size_t)r * HD + t];
        s += v;
        s2 += v * v;
    }
    atomicAdd(&stats[t], s);
    atomicAdd(&stats[HD + t], s2);
}

// ---------- batchnorm apply + SiLU (final layer only) ----------
__global__ void k_bnapply(const float* __restrict__ hpre, const float* __restrict__ stats,
                          const float* __restrict__ gamma, const float* __restrict__ beta,
                          float* __restrict__ h) {
    int idx = blockIdx.x * 256 + threadIdx.x;
    if (idx >= NN * HD) return;
    int c = idx & (HD - 1);
    const float invn = 1.0f / NN;
    float mu = stats[c] * invn;
    float var = stats[HD + c] * invn - mu * mu;
    float xn = (hpre[idx] - mu) * rsqrtf(var + BN_EPS);
    float y = gamma[c] * xn + beta[c];
    h[idx] = y / (1.f + __expf(-y));  // SiLU
}

// ---------- graph boundaries (batch is sorted) ----------
__global__ void k_gbounds(const int* __restrict__ batch, int* __restrict__ gstart) {
    int g = threadIdx.x;
    if (g > NGR) return;
    int lo = 0, hi = NN;
    while (lo < hi) {
        int mid = (lo + hi) >> 1;
        if (batch[mid] < g) lo = mid + 1;
        else hi = mid;
    }
    gstart[g] = lo;
}

// ---------- global mean pool: one block per graph, no atomics ----------
__global__ void k_pool(const float* __restrict__ h, const int* __restrict__ gstart,
                       float* __restrict__ pooled, float* __restrict__ gcount) {
    int g = blockIdx.x;
    int t = threadIdx.x;  // 512
    int c = t & (HD - 1);
    int ro = t >> 7;
    int beg = gstart[g], end = gstart[g + 1];
    float acc = 0.f;
    for (int r = beg + ro; r < end; r += 4) acc += h[(size_t)r * HD + c];
    __shared__ float sm[512];
    sm[t] = acc;
    __syncthreads();
    if (t < 256) sm[t] += sm[t + 256];
    __syncthreads();
    if (t < 128) {
        float cnt = (float)(end - beg);
        pooled[g * HD + t] = (sm[t] + sm[t + 128]) / fmaxf(cnt, 1.0f);
        if (t == 0) gcount[g] = cnt;
    }
}

// ---------- head MLP ----------
__global__ void k_head(const float* __restrict__ pooled, const float* __restrict__ gcount,
                       const float* __restrict__ fc1w, const float* __restrict__ fc1b,
                       const float* __restrict__ fc2w, const float* __restrict__ fc2b,
                       float* __restrict__ out) {
    int g = blockIdx.x;
    int j = threadIdx.x;  // 64 threads = 1 wave
    __shared__ float pa[HD];
    pa[j] = pooled[g * HD + j];
    pa[j + 64] = pooled[g * HD + 64 + j];
    __syncthreads();
    float a = fc1b[j];
    for (int k = 0; k < HD; k++) a += pa[k] * fc1w[k * 64 + j];
    a = a / (1.f + __expf(-a));  // SiLU
    float v = a * fc2w[j];
    for (int off = 32; off > 0; off >>= 1) v += __shfl_down(v, off);
    if (j == 0) out[g] = 1.f / (1.f + __expf(-(v + fc2b[0])));
}

extern "C" void kernel_launch(void* const* d_in, const int* in_sizes, int n_in,
                              void* d_out, int out_size, void* d_ws, size_t ws_size,
                              hipStream_t stream) {
    const float* x = (const float*)d_in[0];
    const int* ei = (const int*)d_in[1];  // [2, E]: row=ei[0..E), col=ei[E..2E)
    const float* ea = (const float*)d_in[2];
    const int* batch = (const int*)d_in[3];
    const float* conv0_w = (const float*)d_in[5];
    const float* conv0_b = (const float*)d_in[6];
    const float* conv_ws = (const float*)d_in[7];
    const float* conv_bs = (const float*)d_in[8];
    const float* bn_gamma = (const float*)d_in[9];
    const float* bn_beta = (const float*)d_in[10];
    const float* fc1w = (const float*)d_in[11];
    const float* fc1b = (const float*)d_in[12];
    const float* fc2w = (const float*)d_in[13];
    const float* fc2b = (const float*)d_in[14];
    float* out = (float*)d_out;

    char* ws = (char*)d_ws;
    size_t off = 0;
    auto alloc = [&](size_t bytes) -> char* {
        char* p = ws + off;
        off = (off + bytes + 255) & ~(size_t)255;
        return p;
    };
    float* dinv = (float*)alloc(NN * 4);
    int* cnt = (int*)alloc(NN * 4);
    int* col_ptr = (int*)alloc((NN + 1) * 4);
    int* fill = (int*)alloc(NN * 4);
    int* csr_src = (int*)alloc(NE * 4);
    float* csr_w = (float*)alloc(NE * 4);
    float* mbuf = (float*)alloc((size_t)NN * HD * 4);
    float* hA = (float*)alloc((size_t)NN * HD * 4);
    float* hB = (float*)alloc((size_t)NN * HD * 4);
    float* stats = (float*)alloc(4 * 2 * HD * 4);
    float* pooled = (float*)alloc(NGR * HD * 4);
    float* gcount = (float*)alloc(NGR * 4);
    int* gstart = (int*)alloc((NGR + 1) * 4);

    hipMemsetAsync(cnt, 0, NN * 4, stream);
    hipMemsetAsync(fill, 0, NN * 4, stream);
    hipMemsetAsync(stats, 0, 4 * 2 * HD * 4, stream);

    k_init_deg<<<(NN + 255) / 256, 256, 0, stream>>>(dinv);
    k_deg_edges<<<(NE + 255) / 256, 256, 0, stream>>>(ei, ea, dinv);
    k_dinv<<<(NN + 255) / 256, 256, 0, stream>>>(dinv);
    k_hist<<<(NE + 255) / 256, 256, 0, stream>>>(ei, cnt);
    k_scan<<<1, 1024, 0, stream>>>(cnt, col_ptr);
    k_scatter<<<(NE + 255) / 256, 256, 0, stream>>>(ei, ea, dinv, col_ptr, fill, csr_src, csr_w);
    k_gbounds<<<1, 128, 0, stream>>>(batch, gstart);

    const int NG128 = (NN + BM - 1) / BM;
    float* st0 = stats;
    float* st1 = stats + 2 * HD;
    float* st2 = stats + 4 * HD;
    float* st3 = stats + 6 * HD;

    // L0
    k_gemm0<<<(NN + 1) / 2, 256, 0, stream>>>(x, conv0_w, mbuf);
    k_agg<<<(NN + 3) / 4, 256, 0, stream>>>(mbuf, col_ptr, csr_src, csr_w, dinv, conv0_b, hA);
    k_bnstats<<<512, HD, 0, stream>>>(hA, st0);
    // L1: BN0+SiLU fused into GEMM
    k_gemm128<<<NG128, 256, 0, stream>>>(hA, st0, bn_gamma, bn_beta, conv_ws, mbuf);
    k_agg<<<(NN + 3) / 4, 256, 0, stream>>>(mbuf, col_ptr, csr_src, csr_w, dinv, conv_bs, hB);
    k_bnstats<<<512, HD, 0, stream>>>(hB, st1);
    // L2
    k_gemm128<<<NG128, 256, 0, stream>>>(hB, st1, bn_gamma + HD, bn_beta + HD,
                                         conv_ws + (size_t)HD * HD, mbuf);
    k_agg<<<(NN + 3) / 4, 256, 0, stream>>>(mbuf, col_ptr, csr_src, csr_w, dinv, conv_bs + HD, hA);
    k_bnstats<<<512, HD, 0, stream>>>(hA, st2);
    // L3
    k_gemm128<<<NG128, 256, 0, stream>>>(hA, st2, bn_gamma + 2 * HD, bn_beta + 2 * HD,
                                         conv_ws + (size_t)2 * HD * HD, mbuf);
    k_agg<<<(NN + 3) / 4, 256, 0, stream>>>(mbuf, col_ptr, csr_src, csr_w, dinv, conv_bs + 2 * HD, hB);
    k_bnstats<<<512, HD, 0, stream>>>(hB, st3);
    // final BN+SiLU, pool, head
    k_bnapply<<<(NN * HD + 255) / 256, 256, 0, stream>>>(hB, st3, bn_gamma + 3 * HD,
                                                         bn_beta + 3 * HD, hA);
    k_pool<<<NGR, 512, 0, stream>>>(hA, gstart, pooled, gcount);
    k_head<<<NGR, 64, 0, stream>>>(pooled, gcount, fc1w, fc1b, fc2w, fc2b, out);
}

// Round 5
// 688.332 us; speedup vs baseline: 4.0760x; 1.1075x over previous
//
#include <hip/hip_runtime.h>

#define NN 50000
#define NE 500000
#define NGR 64
#define HD 128
#define INF 5
#define BN_EPS 1e-5f
#define BM 64
#define KC 32
#define SCB 128                      // scan blocks
#define SCT 256                      // scan threads per block
#define SCH ((NN + SCB - 1) / SCB)   // chunk per scan block (391)

// ---------- init: deg=1 (self-loop), cnt=0, fill=0 ----------
__global__ void k_init(float* deg, int* cnt, int* fill) {
    int i = blockIdx.x * 256 + threadIdx.x;
    if (i < NN) {
        deg[i] = 1.0f;
        cnt[i] = 0;
        fill[i] = 0;
    }
}

// ---------- one edge pass: weighted degree + histogram ----------
__global__ void k_deg_hist(const int* __restrict__ ei, const float* __restrict__ ea,
                           float* __restrict__ deg, int* __restrict__ cnt) {
    int e = blockIdx.x * 256 + threadIdx.x;
    if (e < NE) {
        int c = ei[NE + e];
        atomicAdd(&deg[c], ea[e]);
        atomicAdd(&cnt[c], 1);
    }
}

__global__ void k_dinv(float* deg) {
    int i = blockIdx.x * 256 + threadIdx.x;
    if (i < NN) {
        float d = deg[i];
        deg[i] = d > 0.f ? rsqrtf(d) : 0.f;
    }
}

// ---------- hierarchical scan ----------
__global__ void k_scan1(const int* __restrict__ cnt, int* __restrict__ bsum) {
    __shared__ int sm[SCT];
    int b = blockIdx.x, t = threadIdx.x;
    int lo = b * SCH, hi = min(lo + SCH, NN);
    int s = 0;
    for (int i = lo + t; i < hi; i += SCT) s += cnt[i];
    sm[t] = s;
    __syncthreads();
    for (int off = SCT / 2; off > 0; off >>= 1) {
        if (t < off) sm[t] += sm[t + off];
        __syncthreads();
    }
    if (t == 0) bsum[b] = sm[0];
}

__global__ void k_scan2(const int* __restrict__ bsum, int* __restrict__ boff) {
    __shared__ int sm[SCB];
    int t = threadIdx.x;  // SCB threads
    sm[t] = bsum[t];
    __syncthreads();
    for (int off = 1; off < SCB; off <<= 1) {
        int v = (t >= off) ? sm[t - off] : 0;
        __syncthreads();
        sm[t] += v;
        __syncthreads();
    }
    boff[t] = (t == 0) ? 0 : sm[t - 1];
    if (t == SCB - 1) boff[SCB] = sm[SCB - 1];
}

__global__ void k_scan3(const int* __restrict__ cnt, const int* __restrict__ boff,
                        int* __restrict__ col_ptr) {
    __shared__ int sm[SCT];
    int b = blockIdx.x, t = threadIdx.x;
    int lo = b * SCH, hi = min(lo + SCH, NN);
    int e0 = lo + 2 * t, e1 = e0 + 1;
    int c0 = (e0 < hi) ? cnt[e0] : 0;
    int c1 = (e1 < hi) ? cnt[e1] : 0;
    sm[t] = c0 + c1;
    __syncthreads();
    for (int off = 1; off < SCT; off <<= 1) {
        int v = (t >= off) ? sm[t - off] : 0;
        __syncthreads();
        sm[t] += v;
        __syncthreads();
    }
    int base = boff[b] + ((t == 0) ? 0 : sm[t - 1]);
    if (e0 < hi) col_ptr[e0] = base;
    if (e1 < hi) col_ptr[e1] = base + c0;
    if (b == SCB - 1 && t == SCT - 1) col_ptr[NN] = boff[SCB];
}

__global__ void k_scatter(const int* __restrict__ ei, const float* __restrict__ ea,
                          const float* __restrict__ dinv, const int* __restrict__ col_ptr,
                          int* __restrict__ fill, int* __restrict__ csr_src,
                          float* __restrict__ csr_w) {
    int e = blockIdx.x * 256 + threadIdx.x;
    if (e >= NE) return;
    int r = ei[e], c = ei[NE + e];
    float w = dinv[r] * ea[e] * dinv[c];
    int pos = col_ptr[c] + atomicAdd(&fill[c], 1);
    csr_src[pos] = r;
    csr_w[pos] = w;
}

// ---------- layer-0 transform: m = x @ W0  (K=5) ----------
__global__ void k_gemm0(const float* __restrict__ x, const float* __restrict__ W,
                        float* __restrict__ m) {
    __shared__ float Ws[INF][HD];
    int t = threadIdx.x;  // 256
    for (int i = t; i < INF * HD; i += 256) ((float*)Ws)[i] = W[i];
    __syncthreads();
    int row = blockIdx.x * 2 + (t >> 7);
    if (row >= NN) return;
    int c = t & 127;
    float acc = 0.f;
#pragma unroll
    for (int k = 0; k < INF; k++) acc += x[row * INF + k] * Ws[k][c];
    m[(size_t)row * HD + c] = acc;
}

// ---------- fused BN(prev)+SiLU + GEMM: m = silu(bn(hpre)) @ W ----------
__global__ __launch_bounds__(256) void k_gemm128(
    const float* __restrict__ hpre, const float* __restrict__ stats,
    const float* __restrict__ gamma, const float* __restrict__ beta,
    const float* __restrict__ W, float* __restrict__ m) {
    __shared__ float hs[BM][HD];   // 32 KB
    __shared__ float Ws[KC][HD];   // 16 KB
    __shared__ float sc[HD], sh[HD];
    int t = threadIdx.x;
    int r0 = blockIdx.x * BM;
    const float invn = 1.0f / NN;

    if (t < HD) {
        float mu = stats[t] * invn;
        float var = stats[HD + t] * invn - mu * mu;
        float s = gamma[t] * rsqrtf(var + BN_EPS);
        sc[t] = s;
        sh[t] = beta[t] - mu * s;
    }
    __syncthreads();

#pragma unroll
    for (int i = 0; i < 8; i++) {
        int idx4 = i * 256 + t;
        int r = idx4 >> 5;
        int c4 = idx4 & 31;
        float4 v = make_float4(0.f, 0.f, 0.f, 0.f);
        if (r0 + r < NN) v = ((const float4*)hpre)[(size_t)(r0 + r) * 32 + c4];
        int c = c4 * 4;
#pragma unroll
        for (int q = 0; q < 4; q++) {
            float y = sc[c + q] * (&v.x)[q] + sh[c + q];
            (&v.x)[q] = y / (1.f + __expf(-y));
        }
        ((float4*)&hs[0][0])[idx4] = v;
    }

    int rg = t >> 5, cg = t & 31;
    int rr = rg * 8, cc = cg * 4;
    float acc[8][4];
#pragma unroll
    for (int i = 0; i < 8; i++)
#pragma unroll
        for (int j = 0; j < 4; j++) acc[i][j] = 0.f;

#pragma unroll 1
    for (int kb = 0; kb < HD / KC; kb++) {
        __syncthreads();
#pragma unroll
        for (int i = 0; i < 4; i++)
            ((float4*)&Ws[0][0])[i * 256 + t] = ((const float4*)W)[kb * 1024 + i * 256 + t];
        __syncthreads();
#pragma unroll
        for (int k4 = 0; k4 < KC / 4; k4++) {
            float4 wv0 = *(const float4*)&Ws[k4 * 4 + 0][cc];
            float4 wv1 = *(const float4*)&Ws[k4 * 4 + 1][cc];
            float4 wv2 = *(const float4*)&Ws[k4 * 4 + 2][cc];
            float4 wv3 = *(const float4*)&Ws[k4 * 4 + 3][cc];
#pragma unroll
            for (int i = 0; i < 8; i++) {
                float4 hv = *(const float4*)&hs[rr + i][kb * KC + k4 * 4];
                acc[i][0] += hv.x * wv0.x + hv.y * wv1.x + hv.z * wv2.x + hv.w * wv3.x;
                acc[i][1] += hv.x * wv0.y + hv.y * wv1.y + hv.z * wv2.y + hv.w * wv3.y;
                acc[i][2] += hv.x * wv0.z + hv.y * wv1.z + hv.z * wv2.z + hv.w * wv3.z;
                acc[i][3] += hv.x * wv0.w + hv.y * wv1.w + hv.z * wv2.w + hv.w * wv3.w;
            }
        }
    }

#pragma unroll
    for (int i = 0; i < 8; i++) {
        int r = r0 + rr + i;
        if (r < NN)
            *(float4*)&m[(size_t)r * HD + cc] =
                make_float4(acc[i][0], acc[i][1], acc[i][2], acc[i][3]);
    }
}

// ---------- sparse aggregation (CSR gather, no atomics, 4x unroll) ----------
__global__ void k_agg(const float* __restrict__ m, const int* __restrict__ col_ptr,
                      const int* __restrict__ csr_src, const float* __restrict__ csr_w,
                      const float* __restrict__ dinv, const float* __restrict__ bias,
                      float* __restrict__ hpre) {
    int node = blockIdx.x * 4 + (threadIdx.x >> 6);  // 4 waves/block, 1 node/wave
    if (node >= NN) return;
    int lane = threadIdx.x & 63;
    const float2* m2 = (const float2*)m;
    float di = dinv[node];
    float2 vs = m2[(size_t)node * 64 + lane];
    float a0 = di * di * vs.x;
    float a1 = di * di * vs.y;
    int beg = col_ptr[node], end = col_ptr[node + 1];
    int p = beg;
    for (; p + 4 <= end; p += 4) {
        int s0 = csr_src[p], s1 = csr_src[p + 1], s2 = csr_src[p + 2], s3 = csr_src[p + 3];
        float w0 = csr_w[p], w1 = csr_w[p + 1], w2 = csr_w[p + 2], w3 = csr_w[p + 3];
        float2 v0 = m2[(size_t)s0 * 64 + lane];
        float2 v1 = m2[(size_t)s1 * 64 + lane];
        float2 v2 = m2[(size_t)s2 * 64 + lane];
        float2 v3 = m2[(size_t)s3 * 64 + lane];
        a0 += w0 * v0.x + w1 * v1.x + w2 * v2.x + w3 * v3.x;
        a1 += w0 * v0.y + w1 * v1.y + w2 * v2.y + w3 * v3.y;
    }
    for (; p < end; p++) {
        int s = csr_src[p];
        float w = csr_w[p];
        float2 v = m2[(size_t)s * 64 + lane];
        a0 += w * v.x;
        a1 += w * v.y;
    }
    float2 b = ((const float2*)bias)[lane];
    float2 o;
    o.x = a0 + b.x;
    o.y = a1 + b.y;
    ((float2*)hpre)[(size_t)node * 64 + lane] = o;
}

// ---------- batchnorm stats (sum, sumsq per channel) ----------
__global__ void k_bnstats(const float* __restrict__ hpre, float* __restrict__ stats) {
    int t = threadIdx.x;  // channel, block = 128
    float s = 0.f, s2 = 0.f;
    for (int r = blockIdx.x; r < NN; r += gridDim.x) {
        float v = hpre[(size_t)r * HD + t];
        s += v;
        s2 += v * v;
    }
    atomicAdd(&stats[t], s);
    atomicAdd(&stats[HD + t], s2);
}

// ---------- batchnorm apply + SiLU (final layer only) ----------
__global__ void k_bnapply(const float* __restrict__ hpre, const float* __restrict__ stats,
                          const float* __restrict__ gamma, const float* __restrict__ beta,
                          float* __restrict__ h) {
    int idx = blockIdx.x * 256 + threadIdx.x;
    if (idx >= NN * HD) return;
    int c = idx & (HD - 1);
    const float invn = 1.0f / NN;
    float mu = stats[c] * invn;
    float var = stats[HD + c] * invn - mu * mu;
    float xn = (hpre[idx] - mu) * rsqrtf(var + BN_EPS);
    float y = gamma[c] * xn + beta[c];
    h[idx] = y / (1.f + __expf(-y));  // SiLU
}

// ---------- graph boundaries (batch is sorted) ----------
__global__ void k_gbounds(const int* __restrict__ batch, int* __restrict__ gstart) {
    int g = threadIdx.x;
    if (g > NGR) return;
    int lo = 0, hi = NN;
    while (lo < hi) {
        int mid = (lo + hi) >> 1;
        if (batch[mid] < g) lo = mid + 1;
        else hi = mid;
    }
    gstart[g] = lo;
}

// ---------- global mean pool: one block per graph, no atomics ----------
__global__ void k_pool(const float* __restrict__ h, const int* __restrict__ gstart,
                       float* __restrict__ pooled, float* __restrict__ gcount) {
    int g = blockIdx.x;
    int t = threadIdx.x;  // 512
    int c = t & (HD - 1);
    int ro = t >> 7;
    int beg = gstart[g], end = gstart[g + 1];
    float acc = 0.f;
    for (int r = beg + ro; r < end; r += 4) acc += h[(size_t)r * HD + c];
    __shared__ float sm[512];
    sm[t] = acc;
    __syncthreads();
    if (t < 256) sm[t] += sm[t + 256];
    __syncthreads();
    if (t < 128) {
        float cnt = (float)(end - beg);
        pooled[g * HD + t] = (sm[t] + sm[t + 128]) / fmaxf(cnt, 1.0f);
        if (t == 0) gcount[g] = cnt;
    }
}

// ---------- head MLP ----------
__global__ void k_head(const float* __restrict__ pooled, const float* __restrict__ gcount,
                       const float* __restrict__ fc1w, const float* __restrict__ fc1b,
                       const float* __restrict__ fc2w, const float* __restrict__ fc2b,
                       float* __restrict__ out) {
    int g = blockIdx.x;
    int j = threadIdx.x;  // 64 threads = 1 wave
    __shared__ float pa[HD];
    pa[j] = pooled[g * HD + j];
    pa[j + 64] = pooled[g * HD + 64 + j];
    __syncthreads();
    float a = fc1b[j];
    for (int k = 0; k < HD; k++) a += pa[k] * fc1w[k * 64 + j];
    a = a / (1.f + __expf(-a));  // SiLU
    float v = a * fc2w[j];
    for (int off = 32; off > 0; off >>= 1) v += __shfl_down(v, off);
    if (j == 0) out[g] = 1.f / (1.f + __expf(-(v + fc2b[0])));
}

extern "C" void kernel_launch(void* const* d_in, const int* in_sizes, int n_in,
                              void* d_out, int out_size, void* d_ws, size_t ws_size,
                              hipStream_t stream) {
    const float* x = (const float*)d_in[0];
    const int* ei = (const int*)d_in[1];  // [2, E]: row=ei[0..E), col=ei[E..2E)
    const float* ea = (const float*)d_in[2];
    const int* batch = (const int*)d_in[3];
    const float* conv0_w = (const float*)d_in[5];
    const float* conv0_b = (const float*)d_in[6];
    const float* conv_ws = (const float*)d_in[7];
    const float* conv_bs = (const float*)d_in[8];
    const float* bn_gamma = (const float*)d_in[9];
    const float* bn_beta = (const float*)d_in[10];
    const float* fc1w = (const float*)d_in[11];
    const float* fc1b = (const float*)d_in[12];
    const float* fc2w = (const float*)d_in[13];
    const float* fc2b = (const float*)d_in[14];
    float* out = (float*)d_out;

    char* ws = (char*)d_ws;
    size_t off = 0;
    auto alloc = [&](size_t bytes) -> char* {
        char* p = ws + off;
        off = (off + bytes + 255) & ~(size_t)255;
        return p;
    };
    float* dinv = (float*)alloc(NN * 4);
    int* cnt = (int*)alloc(NN * 4);
    int* col_ptr = (int*)alloc((NN + 1) * 4);
    int* fill = (int*)alloc(NN * 4);
    int* csr_src = (int*)alloc(NE * 4);
    float* csr_w = (float*)alloc(NE * 4);
    float* mbuf = (float*)alloc((size_t)NN * HD * 4);
    float* hA = (float*)alloc((size_t)NN * HD * 4);
    float* hB = (float*)alloc((size_t)NN * HD * 4);
    float* stats = (float*)alloc(4 * 2 * HD * 4);
    float* pooled = (float*)alloc(NGR * HD * 4);
    float* gcount = (float*)alloc(NGR * 4);
    int* gstart = (int*)alloc((NGR + 1) * 4);
    int* bsum = (int*)alloc(SCB * 4);
    int* boff = (int*)alloc((SCB + 1) * 4);

    hipMemsetAsync(stats, 0, 4 * 2 * HD * 4, stream);

    k_init<<<(NN + 255) / 256, 256, 0, stream>>>(dinv, cnt, fill);
    k_deg_hist<<<(NE + 255) / 256, 256, 0, stream>>>(ei, ea, dinv, cnt);
    k_dinv<<<(NN + 255) / 256, 256, 0, stream>>>(dinv);
    k_scan1<<<SCB, SCT, 0, stream>>>(cnt, bsum);
    k_scan2<<<1, SCB, 0, stream>>>(bsum, boff);
    k_scan3<<<SCB, SCT, 0, stream>>>(cnt, boff, col_ptr);
    k_scatter<<<(NE + 255) / 256, 256, 0, stream>>>(ei, ea, dinv, col_ptr, fill, csr_src, csr_w);
    k_gbounds<<<1, 128, 0, stream>>>(batch, gstart);

    const int NG128 = (NN + BM - 1) / BM;
    float* st0 = stats;
    float* st1 = stats + 2 * HD;
    float* st2 = stats + 4 * HD;
    float* st3 = stats + 6 * HD;

    // L0
    k_gemm0<<<(NN + 1) / 2, 256, 0, stream>>>(x, conv0_w, mbuf);
    k_agg<<<(NN + 3) / 4, 256, 0, stream>>>(mbuf, col_ptr, csr_src, csr_w, dinv, conv0_b, hA);
    k_bnstats<<<512, HD, 0, stream>>>(hA, st0);
    // L1
    k_gemm128<<<NG128, 256, 0, stream>>>(hA, st0, bn_gamma, bn_beta, conv_ws, mbuf);
    k_agg<<<(NN + 3) / 4, 256, 0, stream>>>(mbuf, col_ptr, csr_src, csr_w, dinv, conv_bs, hB);
    k_bnstats<<<512, HD, 0, stream>>>(hB, st1);
    // L2
    k_gemm128<<<NG128, 256, 0, stream>>>(hB, st1, bn_gamma + HD, bn_beta + HD,
                                         conv_ws + (size_t)HD * HD, mbuf);
    k_agg<<<(NN + 3) / 4, 256, 0, stream>>>(mbuf, col_ptr, csr_src, csr_w, dinv, conv_bs + HD, hA);
    k_bnstats<<<512, HD, 0, stream>>>(hA, st2);
    // L3
    k_gemm128<<<NG128, 256, 0, stream>>>(hA, st2, bn_gamma + 2 * HD, bn_beta + 2 * HD,
                                         conv_ws + (size_t)2 * HD * HD, mbuf);
    k_agg<<<(NN + 3) / 4, 256, 0, stream>>>(mbuf, col_ptr, csr_src, csr_w, dinv, conv_bs + 2 * HD, hB);
    k_bnstats<<<512, HD, 0, stream>>>(hB, st3);
    // final BN+SiLU, pool, head
    k_bnapply<<<(NN * HD + 255) / 256, 256, 0, stream>>>(hB, st3, bn_gamma + 3 * HD,
                                                         bn_beta + 3 * HD, hA);
    k_pool<<<NGR, 512, 0, stream>>>(hA, gstart, pooled, gcount);
    k_head<<<NGR, 64, 0, stream>>>(pooled, gcount, fc1w, fc1b, fc2w, fc2b, out);
}

// Round 6
// 601.079 us; speedup vs baseline: 4.6677x; 1.1452x over previous
//
#include <hip/hip_runtime.h>

#define NN 50000
#define NE 500000
#define NGR 64
#define HD 128
#define INF 5
#define BN_EPS 1e-5f
#define BM 64
#define SCB 128                      // scan blocks
#define SCT 256                      // scan threads per block
#define SCH ((NN + SCB - 1) / SCB)   // chunk per scan block (391)

// ---------- init: deg=1 (self-loop), cnt=0, fill=0 ----------
__global__ void k_init(float* deg, int* cnt, int* fill) {
    int i = blockIdx.x * 256 + threadIdx.x;
    if (i < NN) {
        deg[i] = 1.0f;
        cnt[i] = 0;
        fill[i] = 0;
    }
}

// ---------- one edge pass: weighted degree + histogram ----------
__global__ void k_deg_hist(const int* __restrict__ ei, const float* __restrict__ ea,
                           float* __restrict__ deg, int* __restrict__ cnt) {
    int e = blockIdx.x * 256 + threadIdx.x;
    if (e < NE) {
        int c = ei[NE + e];
        atomicAdd(&deg[c], ea[e]);
        atomicAdd(&cnt[c], 1);
    }
}

__global__ void k_dinv(float* deg) {
    int i = blockIdx.x * 256 + threadIdx.x;
    if (i < NN) {
        float d = deg[i];
        deg[i] = d > 0.f ? rsqrtf(d) : 0.f;
    }
}

// ---------- hierarchical scan ----------
__global__ void k_scan1(const int* __restrict__ cnt, int* __restrict__ bsum) {
    __shared__ int sm[SCT];
    int b = blockIdx.x, t = threadIdx.x;
    int lo = b * SCH, hi = min(lo + SCH, NN);
    int s = 0;
    for (int i = lo + t; i < hi; i += SCT) s += cnt[i];
    sm[t] = s;
    __syncthreads();
    for (int off = SCT / 2; off > 0; off >>= 1) {
        if (t < off) sm[t] += sm[t + off];
        __syncthreads();
    }
    if (t == 0) bsum[b] = sm[0];
}

__global__ void k_scan2(const int* __restrict__ bsum, int* __restrict__ boff) {
    __shared__ int sm[SCB];
    int t = threadIdx.x;  // SCB threads
    sm[t] = bsum[t];
    __syncthreads();
    for (int off = 1; off < SCB; off <<= 1) {
        int v = (t >= off) ? sm[t - off] : 0;
        __syncthreads();
        sm[t] += v;
        __syncthreads();
    }
    boff[t] = (t == 0) ? 0 : sm[t - 1];
    if (t == SCB - 1) boff[SCB] = sm[SCB - 1];
}

__global__ void k_scan3(const int* __restrict__ cnt, const int* __restrict__ boff,
                        int* __restrict__ col_ptr) {
    __shared__ int sm[SCT];
    int b = blockIdx.x, t = threadIdx.x;
    int lo = b * SCH, hi = min(lo + SCH, NN);
    int e0 = lo + 2 * t, e1 = e0 + 1;
    int c0 = (e0 < hi) ? cnt[e0] : 0;
    int c1 = (e1 < hi) ? cnt[e1] : 0;
    sm[t] = c0 + c1;
    __syncthreads();
    for (int off = 1; off < SCT; off <<= 1) {
        int v = (t >= off) ? sm[t - off] : 0;
        __syncthreads();
        sm[t] += v;
        __syncthreads();
    }
    int base = boff[b] + ((t == 0) ? 0 : sm[t - 1]);
    if (e0 < hi) col_ptr[e0] = base;
    if (e1 < hi) col_ptr[e1] = base + c0;
    if (b == SCB - 1 && t == SCT - 1) col_ptr[NN] = boff[SCB];
}

__global__ void k_scatter(const int* __restrict__ ei, const float* __restrict__ ea,
                          const float* __restrict__ dinv, const int* __restrict__ col_ptr,
                          int* __restrict__ fill, int* __restrict__ csr_src,
                          float* __restrict__ csr_w) {
    int e = blockIdx.x * 256 + threadIdx.x;
    if (e >= NE) return;
    int r = ei[e], c = ei[NE + e];
    float w = dinv[r] * ea[e] * dinv[c];
    int pos = col_ptr[c] + atomicAdd(&fill[c], 1);
    csr_src[pos] = r;
    csr_w[pos] = w;
}

// ---------- layer-0 transform: m = x @ W0  (K=5) ----------
__global__ void k_gemm0(const float* __restrict__ x, const float* __restrict__ W,
                        float* __restrict__ m) {
    __shared__ float Ws[INF][HD];
    int t = threadIdx.x;  // 256
    for (int i = t; i < INF * HD; i += 256) ((float*)Ws)[i] = W[i];
    __syncthreads();
    int row = blockIdx.x * 2 + (t >> 7);
    if (row >= NN) return;
    int c = t & 127;
    float acc = 0.f;
#pragma unroll
    for (int k = 0; k < INF; k++) acc += x[row * INF + k] * Ws[k][c];
    m[(size_t)row * HD + c] = acc;
}

// ---------- fused BN(prev)+SiLU + GEMM: m = silu(bn(hpre)) @ W ----------
// h tile in LDS; W streamed from global (L2-resident, 64 KB shared by all
// blocks). No in-loop barriers. launch_bounds(256,4) -> VGPR<=128, 4 wv/SIMD.
__global__ __launch_bounds__(256, 4) void k_gemm128(
    const float* __restrict__ hpre, const float* __restrict__ stats,
    const float* __restrict__ gamma, const float* __restrict__ beta,
    const float* __restrict__ W, float* __restrict__ m) {
    __shared__ float hs[BM][HD];   // 32 KB
    __shared__ float sc[HD], sh[HD];
    int t = threadIdx.x;
    int r0 = blockIdx.x * BM;
    const float invn = 1.0f / NN;

    if (t < HD) {
        float mu = stats[t] * invn;
        float var = stats[HD + t] * invn - mu * mu;
        float s = gamma[t] * rsqrtf(var + BN_EPS);
        sc[t] = s;
        sh[t] = beta[t] - mu * s;
    }
    __syncthreads();

    // stage h tile with fused BN + SiLU (8 float4 per thread)
#pragma unroll
    for (int i = 0; i < 8; i++) {
        int idx4 = i * 256 + t;
        int r = idx4 >> 5;
        int c4 = idx4 & 31;
        float4 v = make_float4(0.f, 0.f, 0.f, 0.f);
        if (r0 + r < NN) v = ((const float4*)hpre)[(size_t)(r0 + r) * 32 + c4];
        int c = c4 * 4;
#pragma unroll
        for (int q = 0; q < 4; q++) {
            float y = sc[c + q] * (&v.x)[q] + sh[c + q];
            (&v.x)[q] = y / (1.f + __expf(-y));
        }
        ((float4*)&hs[0][0])[idx4] = v;
    }
    __syncthreads();

    int rg = t >> 5, cg = t & 31;
    int rr = rg * 8;
    int cc = cg * 4;
    float acc[8][4];
#pragma unroll
    for (int i = 0; i < 8; i++)
#pragma unroll
        for (int j = 0; j < 4; j++) acc[i][j] = 0.f;

    const float4* Wp = (const float4*)W;  // [HD][32] float4 view
#pragma unroll 2
    for (int k4 = 0; k4 < HD / 4; k4++) {
        float4 wv0 = Wp[(k4 * 4 + 0) * 32 + cg];
        float4 wv1 = Wp[(k4 * 4 + 1) * 32 + cg];
        float4 wv2 = Wp[(k4 * 4 + 2) * 32 + cg];
        float4 wv3 = Wp[(k4 * 4 + 3) * 32 + cg];
#pragma unroll
        for (int i = 0; i < 8; i++) {
            float4 hv = *(const float4*)&hs[rr + i][k4 * 4];
            acc[i][0] += hv.x * wv0.x + hv.y * wv1.x + hv.z * wv2.x + hv.w * wv3.x;
            acc[i][1] += hv.x * wv0.y + hv.y * wv1.y + hv.z * wv2.y + hv.w * wv3.y;
            acc[i][2] += hv.x * wv0.z + hv.y * wv1.z + hv.z * wv2.z + hv.w * wv3.z;
            acc[i][3] += hv.x * wv0.w + hv.y * wv1.w + hv.z * wv2.w + hv.w * wv3.w;
        }
    }

#pragma unroll
    for (int i = 0; i < 8; i++) {
        int r = r0 + rr + i;
        if (r < NN)
            *(float4*)&m[(size_t)r * HD + cc] =
                make_float4(acc[i][0], acc[i][1], acc[i][2], acc[i][3]);
    }
}

// ---------- sparse aggregation (CSR gather, no atomics, 8x unroll) ----------
__global__ void k_agg(const float* __restrict__ m, const int* __restrict__ col_ptr,
                      const int* __restrict__ csr_src, const float* __restrict__ csr_w,
                      const float* __restrict__ dinv, const float* __restrict__ bias,
                      float* __restrict__ hpre) {
    int node = blockIdx.x * 4 + (threadIdx.x >> 6);  // 4 waves/block, 1 node/wave
    if (node >= NN) return;
    int lane = threadIdx.x & 63;
    const float2* m2 = (const float2*)m;
    float di = dinv[node];
    float2 vs = m2[(size_t)node * 64 + lane];
    float a0 = di * di * vs.x;
    float a1 = di * di * vs.y;
    int beg = col_ptr[node], end = col_ptr[node + 1];
    int p = beg;
    for (; p + 8 <= end; p += 8) {
        int s0 = csr_src[p], s1 = csr_src[p + 1], s2 = csr_src[p + 2], s3 = csr_src[p + 3];
        int s4 = csr_src[p + 4], s5 = csr_src[p + 5], s6 = csr_src[p + 6], s7 = csr_src[p + 7];
        float w0 = csr_w[p], w1 = csr_w[p + 1], w2 = csr_w[p + 2], w3 = csr_w[p + 3];
        float w4 = csr_w[p + 4], w5 = csr_w[p + 5], w6 = csr_w[p + 6], w7 = csr_w[p + 7];
        float2 v0 = m2[(size_t)s0 * 64 + lane];
        float2 v1 = m2[(size_t)s1 * 64 + lane];
        float2 v2 = m2[(size_t)s2 * 64 + lane];
        float2 v3 = m2[(size_t)s3 * 64 + lane];
        float2 v4 = m2[(size_t)s4 * 64 + lane];
        float2 v5 = m2[(size_t)s5 * 64 + lane];
        float2 v6 = m2[(size_t)s6 * 64 + lane];
        float2 v7 = m2[(size_t)s7 * 64 + lane];
        a0 += w0 * v0.x + w1 * v1.x + w2 * v2.x + w3 * v3.x;
        a1 += w0 * v0.y + w1 * v1.y + w2 * v2.y + w3 * v3.y;
        a0 += w4 * v4.x + w5 * v5.x + w6 * v6.x + w7 * v7.x;
        a1 += w4 * v4.y + w5 * v5.y + w6 * v6.y + w7 * v7.y;
    }
    for (; p + 4 <= end; p += 4) {
        int s0 = csr_src[p], s1 = csr_src[p + 1], s2 = csr_src[p + 2], s3 = csr_src[p + 3];
        float w0 = csr_w[p], w1 = csr_w[p + 1], w2 = csr_w[p + 2], w3 = csr_w[p + 3];
        float2 v0 = m2[(size_t)s0 * 64 + lane];
        float2 v1 = m2[(size_t)s1 * 64 + lane];
        float2 v2 = m2[(size_t)s2 * 64 + lane];
        float2 v3 = m2[(size_t)s3 * 64 + lane];
        a0 += w0 * v0.x + w1 * v1.x + w2 * v2.x + w3 * v3.x;
        a1 += w0 * v0.y + w1 * v1.y + w2 * v2.y + w3 * v3.y;
    }
    for (; p < end; p++) {
        int s = csr_src[p];
        float w = csr_w[p];
        float2 v = m2[(size_t)s * 64 + lane];
        a0 += w * v.x;
        a1 += w * v.y;
    }
    float2 b = ((const float2*)bias)[lane];
    float2 o;
    o.x = a0 + b.x;
    o.y = a1 + b.y;
    ((float2*)hpre)[(size_t)node * 64 + lane] = o;
}

// ---------- batchnorm stats (sum, sumsq per channel) ----------
__global__ void k_bnstats(const float* __restrict__ hpre, float* __restrict__ stats) {
    int t = threadIdx.x;  // channel, block = 128
    float s = 0.f, s2 = 0.f;
    for (int r = blockIdx.x; r < NN; r += gridDim.x) {
        float v = hpre[(size_t)r * HD + t];
        s += v;
        s2 += v * v;
    }
    atomicAdd(&stats[t], s);
    atomicAdd(&stats[HD + t], s2);
}

// ---------- batchnorm apply + SiLU (final layer only) ----------
__global__ void k_bnapply(const float* __restrict__ hpre, const float* __restrict__ stats,
                          const float* __restrict__ gamma, const float* __restrict__ beta,
                          float* __restrict__ h) {
    int idx = blockIdx.x * 256 + threadIdx.x;
    if (idx >= NN * HD) return;
    int c = idx & (HD - 1);
    const float invn = 1.0f / NN;
    float mu = stats[c] * invn;
    float var = stats[HD + c] * invn - mu * mu;
    float xn = (hpre[idx] - mu) * rsqrtf(var + BN_EPS);
    float y = gamma[c] * xn + beta[c];
    h[idx] = y / (1.f + __expf(-y));  // SiLU
}

// ---------- graph boundaries (batch is sorted) ----------
__global__ void k_gbounds(const int* __restrict__ batch, int* __restrict__ gstart) {
    int g = threadIdx.x;
    if (g > NGR) return;
    int lo = 0, hi = NN;
    while (lo < hi) {
        int mid = (lo + hi) >> 1;
        if (batch[mid] < g) lo = mid + 1;
        else hi = mid;
    }
    gstart[g] = lo;
}

// ---------- global mean pool: one block per graph, no atomics ----------
__global__ void k_pool(const float* __restrict__ h, const int* __restrict__ gstart,
                       float* __restrict__ pooled, float* __restrict__ gcount) {
    int g = blockIdx.x;
    int t = threadIdx.x;  // 512
    int c = t & (HD - 1);
    int ro = t >> 7;
    int beg = gstart[g], end = gstart[g + 1];
    float acc = 0.f;
    for (int r = beg + ro; r < end; r += 4) acc += h[(size_t)r * HD + c];
    __shared__ float sm[512];
    sm[t] = acc;
    __syncthreads();
    if (t < 256) sm[t] += sm[t + 256];
    __syncthreads();
    if (t < 128) {
        float cnt = (float)(end - beg);
        pooled[g * HD + t] = (sm[t] + sm[t + 128]) / fmaxf(cnt, 1.0f);
        if (t == 0) gcount[g] = cnt;
    }
}

// ---------- head MLP ----------
__global__ void k_head(const float* __restrict__ pooled, const float* __restrict__ gcount,
                       const float* __restrict__ fc1w, const float* __restrict__ fc1b,
                       const float* __restrict__ fc2w, const float* __restrict__ fc2b,
                       float* __restrict__ out) {
    int g = blockIdx.x;
    int j = threadIdx.x;  // 64 threads = 1 wave
    __shared__ float pa[HD];
    pa[j] = pooled[g * HD + j];
    pa[j + 64] = pooled[g * HD + 64 + j];
    __syncthreads();
    float a = fc1b[j];
    for (int k = 0; k < HD; k++) a += pa[k] * fc1w[k * 64 + j];
    a = a / (1.f + __expf(-a));  // SiLU
    float v = a * fc2w[j];
    for (int off = 32; off > 0; off >>= 1) v += __shfl_down(v, off);
    if (j == 0) out[g] = 1.f / (1.f + __expf(-(v + fc2b[0])));
}

extern "C" void kernel_launch(void* const* d_in, const int* in_sizes, int n_in,
                              void* d_out, int out_size, void* d_ws, size_t ws_size,
                              hipStream_t stream) {
    const float* x = (const float*)d_in[0];
    const int* ei = (const int*)d_in[1];  // [2, E]: row=ei[0..E), col=ei[E..2E)
    const float* ea = (const float*)d_in[2];
    const int* batch = (const int*)d_in[3];
    const float* conv0_w = (const float*)d_in[5];
    const float* conv0_b = (const float*)d_in[6];
    const float* conv_ws = (const float*)d_in[7];
    const float* conv_bs = (const float*)d_in[8];
    const float* bn_gamma = (const float*)d_in[9];
    const float* bn_beta = (const float*)d_in[10];
    const float* fc1w = (const float*)d_in[11];
    const float* fc1b = (const float*)d_in[12];
    const float* fc2w = (const float*)d_in[13];
    const float* fc2b = (const float*)d_in[14];
    float* out = (float*)d_out;

    char* ws = (char*)d_ws;
    size_t off = 0;
    auto alloc = [&](size_t bytes) -> char* {
        char* p = ws + off;
        off = (off + bytes + 255) & ~(size_t)255;
        return p;
    };
    float* dinv = (float*)alloc(NN * 4);
    int* cnt = (int*)alloc(NN * 4);
    int* col_ptr = (int*)alloc((NN + 1) * 4);
    int* fill = (int*)alloc(NN * 4);
    int* csr_src = (int*)alloc(NE * 4);
    float* csr_w = (float*)alloc(NE * 4);
    float* mbuf = (float*)alloc((size_t)NN * HD * 4);
    float* hA = (float*)alloc((size_t)NN * HD * 4);
    float* hB = (float*)alloc((size_t)NN * HD * 4);
    float* stats = (float*)alloc(4 * 2 * HD * 4);
    float* pooled = (float*)alloc(NGR * HD * 4);
    float* gcount = (float*)alloc(NGR * 4);
    int* gstart = (int*)alloc((NGR + 1) * 4);
    int* bsum = (int*)alloc(SCB * 4);
    int* boff = (int*)alloc((SCB + 1) * 4);

    hipMemsetAsync(stats, 0, 4 * 2 * HD * 4, stream);

    k_init<<<(NN + 255) / 256, 256, 0, stream>>>(dinv, cnt, fill);
    k_deg_hist<<<(NE + 255) / 256, 256, 0, stream>>>(ei, ea, dinv, cnt);
    k_dinv<<<(NN + 255) / 256, 256, 0, stream>>>(dinv);
    k_scan1<<<SCB, SCT, 0, stream>>>(cnt, bsum);
    k_scan2<<<1, SCB, 0, stream>>>(bsum, boff);
    k_scan3<<<SCB, SCT, 0, stream>>>(cnt, boff, col_ptr);
    k_scatter<<<(NE + 255) / 256, 256, 0, stream>>>(ei, ea, dinv, col_ptr, fill, csr_src, csr_w);
    k_gbounds<<<1, 128, 0, stream>>>(batch, gstart);

    const int NG128 = (NN + BM - 1) / BM;
    float* st0 = stats;
    float* st1 = stats + 2 * HD;
    float* st2 = stats + 4 * HD;
    float* st3 = stats + 6 * HD;

    // L0
    k_gemm0<<<(NN + 1) / 2, 256, 0, stream>>>(x, conv0_w, mbuf);
    k_agg<<<(NN + 3) / 4, 256, 0, stream>>>(mbuf, col_ptr, csr_src, csr_w, dinv, conv0_b, hA);
    k_bnstats<<<512, HD, 0, stream>>>(hA, st0);
    // L1
    k_gemm128<<<NG128, 256, 0, stream>>>(hA, st0, bn_gamma, bn_beta, conv_ws, mbuf);
    k_agg<<<(NN + 3) / 4, 256, 0, stream>>>(mbuf, col_ptr, csr_src, csr_w, dinv, conv_bs, hB);
    k_bnstats<<<512, HD, 0, stream>>>(hB, st1);
    // L2
    k_gemm128<<<NG128, 256, 0, stream>>>(hB, st1, bn_gamma + HD, bn_beta + HD,
                                         conv_ws + (size_t)HD * HD, mbuf);
    k_agg<<<(NN + 3) / 4, 256, 0, stream>>>(mbuf, col_ptr, csr_src, csr_w, dinv, conv_bs + HD, hA);
    k_bnstats<<<512, HD, 0, stream>>>(hA, st2);
    // L3
    k_gemm128<<<NG128, 256, 0, stream>>>(hA, st2, bn_gamma + 2 * HD, bn_beta + 2 * HD,
                                         conv_ws + (size_t)2 * HD * HD, mbuf);
    k_agg<<<(NN + 3) / 4, 256, 0, stream>>>(mbuf, col_ptr, csr_src, csr_w, dinv, conv_bs + 2 * HD, hB);
    k_bnstats<<<512, HD, 0, stream>>>(hB, st3);
    // final BN+SiLU, pool, head
    k_bnapply<<<(NN * HD + 255) / 256, 256, 0, stream>>>(hB, st3, bn_gamma + 3 * HD,
                                                         bn_beta + 3 * HD, hA);
    k_pool<<<NGR, 512, 0, stream>>>(hA, gstart, pooled, gcount);
    k_head<<<NGR, 64, 0, stream>>>(pooled, gcount, fc1w, fc1b, fc2w, fc2b, out);
}

// Round 7
// 562.600 us; speedup vs baseline: 4.9870x; 1.0684x over previous
//
#include <hip/hip_runtime.h>

#define NN 50000
#define NE 500000
#define NGR 64
#define HD 128
#define INF 5
#define BN_EPS 1e-5f
#define BM 64
#define SCB 128
#define SCT 256
#define SCH ((NN + SCB - 1) / SCB)
#define PP 16   // pooling parts per graph

// ---------- init: deg=1 (self-loop), cnt=0, fill=0 ----------
__global__ void k_init(float* deg, int* cnt, int* fill) {
    int i = blockIdx.x * 256 + threadIdx.x;
    if (i < NN) {
        deg[i] = 1.0f;
        cnt[i] = 0;
        fill[i] = 0;
    }
}

// ---------- one edge pass: weighted degree + histogram ----------
__global__ void k_deg_hist(const int* __restrict__ ei, const float* __restrict__ ea,
                           float* __restrict__ deg, int* __restrict__ cnt) {
    int e = blockIdx.x * 256 + threadIdx.x;
    if (e < NE) {
        int c = ei[NE + e];
        atomicAdd(&deg[c], ea[e]);
        atomicAdd(&cnt[c], 1);
    }
}

__global__ void k_dinv(float* deg) {
    int i = blockIdx.x * 256 + threadIdx.x;
    if (i < NN) {
        float d = deg[i];
        deg[i] = d > 0.f ? rsqrtf(d) : 0.f;
    }
}

// ---------- hierarchical scan ----------
__global__ void k_scan1(const int* __restrict__ cnt, int* __restrict__ bsum) {
    __shared__ int sm[SCT];
    int b = blockIdx.x, t = threadIdx.x;
    int lo = b * SCH, hi = min(lo + SCH, NN);
    int s = 0;
    for (int i = lo + t; i < hi; i += SCT) s += cnt[i];
    sm[t] = s;
    __syncthreads();
    for (int off = SCT / 2; off > 0; off >>= 1) {
        if (t < off) sm[t] += sm[t + off];
        __syncthreads();
    }
    if (t == 0) bsum[b] = sm[0];
}

__global__ void k_scan2(const int* __restrict__ bsum, int* __restrict__ boff) {
    __shared__ int sm[SCB];
    int t = threadIdx.x;
    sm[t] = bsum[t];
    __syncthreads();
    for (int off = 1; off < SCB; off <<= 1) {
        int v = (t >= off) ? sm[t - off] : 0;
        __syncthreads();
        sm[t] += v;
        __syncthreads();
    }
    boff[t] = (t == 0) ? 0 : sm[t - 1];
    if (t == SCB - 1) boff[SCB] = sm[SCB - 1];
}

__global__ void k_scan3(const int* __restrict__ cnt, const int* __restrict__ boff,
                        int* __restrict__ col_ptr) {
    __shared__ int sm[SCT];
    int b = blockIdx.x, t = threadIdx.x;
    int lo = b * SCH, hi = min(lo + SCH, NN);
    int e0 = lo + 2 * t, e1 = e0 + 1;
    int c0 = (e0 < hi) ? cnt[e0] : 0;
    int c1 = (e1 < hi) ? cnt[e1] : 0;
    sm[t] = c0 + c1;
    __syncthreads();
    for (int off = 1; off < SCT; off <<= 1) {
        int v = (t >= off) ? sm[t - off] : 0;
        __syncthreads();
        sm[t] += v;
        __syncthreads();
    }
    int base = boff[b] + ((t == 0) ? 0 : sm[t - 1]);
    if (e0 < hi) col_ptr[e0] = base;
    if (e1 < hi) col_ptr[e1] = base + c0;
    if (b == SCB - 1 && t == SCT - 1) col_ptr[NN] = boff[SCB];
}

__global__ void k_scatter(const int* __restrict__ ei, const float* __restrict__ ea,
                          const float* __restrict__ dinv, const int* __restrict__ col_ptr,
                          int* __restrict__ fill, int* __restrict__ csr_src,
                          float* __restrict__ csr_w) {
    int e = blockIdx.x * 256 + threadIdx.x;
    if (e >= NE) return;
    int r = ei[e], c = ei[NE + e];
    float w = dinv[r] * ea[e] * dinv[c];
    int pos = col_ptr[c] + atomicAdd(&fill[c], 1);
    csr_src[pos] = r;
    csr_w[pos] = w;
}

// ---------- layer-0 transform: m = x @ W0  (K=5) ----------
__global__ void k_gemm0(const float* __restrict__ x, const float* __restrict__ W,
                        float* __restrict__ m) {
    __shared__ float Ws[INF][HD];
    int t = threadIdx.x;  // 256
    for (int i = t; i < INF * HD; i += 256) ((float*)Ws)[i] = W[i];
    __syncthreads();
    int row = blockIdx.x * 2 + (t >> 7);
    if (row >= NN) return;
    int c = t & 127;
    float acc = 0.f;
#pragma unroll
    for (int k = 0; k < INF; k++) acc += x[row * INF + k] * Ws[k][c];
    m[(size_t)row * HD + c] = acc;
}

// ---------- fused BN(prev)+SiLU + GEMM: m = silu(bn(hpre)) @ W ----------
__global__ __launch_bounds__(256, 4) void k_gemm128(
    const float* __restrict__ hpre, const float* __restrict__ stats,
    const float* __restrict__ gamma, const float* __restrict__ beta,
    const float* __restrict__ W, float* __restrict__ m) {
    __shared__ float hs[BM][HD];   // 32 KB
    __shared__ float sc[HD], sh[HD];
    int t = threadIdx.x;
    int r0 = blockIdx.x * BM;
    const float invn = 1.0f / NN;

    if (t < HD) {
        float mu = stats[t] * invn;
        float var = stats[HD + t] * invn - mu * mu;
        float s = gamma[t] * rsqrtf(var + BN_EPS);
        sc[t] = s;
        sh[t] = beta[t] - mu * s;
    }
    __syncthreads();

#pragma unroll
    for (int i = 0; i < 8; i++) {
        int idx4 = i * 256 + t;
        int r = idx4 >> 5;
        int c4 = idx4 & 31;
        float4 v = make_float4(0.f, 0.f, 0.f, 0.f);
        if (r0 + r < NN) v = ((const float4*)hpre)[(size_t)(r0 + r) * 32 + c4];
        int c = c4 * 4;
#pragma unroll
        for (int q = 0; q < 4; q++) {
            float y = sc[c + q] * (&v.x)[q] + sh[c + q];
            (&v.x)[q] = y / (1.f + __expf(-y));
        }
        ((float4*)&hs[0][0])[idx4] = v;
    }
    __syncthreads();

    int rg = t >> 5, cg = t & 31;
    int rr = rg * 8;
    int cc = cg * 4;
    float acc[8][4];
#pragma unroll
    for (int i = 0; i < 8; i++)
#pragma unroll
        for (int j = 0; j < 4; j++) acc[i][j] = 0.f;

    const float4* Wp = (const float4*)W;  // [HD][32] float4 view
#pragma unroll 2
    for (int k4 = 0; k4 < HD / 4; k4++) {
        float4 wv0 = Wp[(k4 * 4 + 0) * 32 + cg];
        float4 wv1 = Wp[(k4 * 4 + 1) * 32 + cg];
        float4 wv2 = Wp[(k4 * 4 + 2) * 32 + cg];
        float4 wv3 = Wp[(k4 * 4 + 3) * 32 + cg];
#pragma unroll
        for (int i = 0; i < 8; i++) {
            float4 hv = *(const float4*)&hs[rr + i][k4 * 4];
            acc[i][0] += hv.x * wv0.x + hv.y * wv1.x + hv.z * wv2.x + hv.w * wv3.x;
            acc[i][1] += hv.x * wv0.y + hv.y * wv1.y + hv.z * wv2.y + hv.w * wv3.y;
            acc[i][2] += hv.x * wv0.z + hv.y * wv1.z + hv.z * wv2.z + hv.w * wv3.z;
            acc[i][3] += hv.x * wv0.w + hv.y * wv1.w + hv.z * wv2.w + hv.w * wv3.w;
        }
    }

#pragma unroll
    for (int i = 0; i < 8; i++) {
        int r = r0 + rr + i;
        if (r < NN)
            *(float4*)&m[(size_t)r * HD + cc] =
                make_float4(acc[i][0], acc[i][1], acc[i][2], acc[i][3]);
    }
}

// ---------- sparse aggregation (CSR gather, no atomics, 8x unroll) ----------
__global__ void k_agg(const float* __restrict__ m, const int* __restrict__ col_ptr,
                      const int* __restrict__ csr_src, const float* __restrict__ csr_w,
                      const float* __restrict__ dinv, const float* __restrict__ bias,
                      float* __restrict__ hpre) {
    int node = blockIdx.x * 4 + (threadIdx.x >> 6);
    if (node >= NN) return;
    int lane = threadIdx.x & 63;
    const float2* m2 = (const float2*)m;
    float di = dinv[node];
    float2 vs = m2[(size_t)node * 64 + lane];
    float a0 = di * di * vs.x;
    float a1 = di * di * vs.y;
    int beg = col_ptr[node], end = col_ptr[node + 1];
    int p = beg;
    for (; p + 8 <= end; p += 8) {
        int s0 = csr_src[p], s1 = csr_src[p + 1], s2 = csr_src[p + 2], s3 = csr_src[p + 3];
        int s4 = csr_src[p + 4], s5 = csr_src[p + 5], s6 = csr_src[p + 6], s7 = csr_src[p + 7];
        float w0 = csr_w[p], w1 = csr_w[p + 1], w2 = csr_w[p + 2], w3 = csr_w[p + 3];
        float w4 = csr_w[p + 4], w5 = csr_w[p + 5], w6 = csr_w[p + 6], w7 = csr_w[p + 7];
        float2 v0 = m2[(size_t)s0 * 64 + lane];
        float2 v1 = m2[(size_t)s1 * 64 + lane];
        float2 v2 = m2[(size_t)s2 * 64 + lane];
        float2 v3 = m2[(size_t)s3 * 64 + lane];
        float2 v4 = m2[(size_t)s4 * 64 + lane];
        float2 v5 = m2[(size_t)s5 * 64 + lane];
        float2 v6 = m2[(size_t)s6 * 64 + lane];
        float2 v7 = m2[(size_t)s7 * 64 + lane];
        a0 += w0 * v0.x + w1 * v1.x + w2 * v2.x + w3 * v3.x;
        a1 += w0 * v0.y + w1 * v1.y + w2 * v2.y + w3 * v3.y;
        a0 += w4 * v4.x + w5 * v5.x + w6 * v6.x + w7 * v7.x;
        a1 += w4 * v4.y + w5 * v5.y + w6 * v6.y + w7 * v7.y;
    }
    for (; p + 4 <= end; p += 4) {
        int s0 = csr_src[p], s1 = csr_src[p + 1], s2 = csr_src[p + 2], s3 = csr_src[p + 3];
        float w0 = csr_w[p], w1 = csr_w[p + 1], w2 = csr_w[p + 2], w3 = csr_w[p + 3];
        float2 v0 = m2[(size_t)s0 * 64 + lane];
        float2 v1 = m2[(size_t)s1 * 64 + lane];
        float2 v2 = m2[(size_t)s2 * 64 + lane];
        float2 v3 = m2[(size_t)s3 * 64 + lane];
        a0 += w0 * v0.x + w1 * v1.x + w2 * v2.x + w3 * v3.x;
        a1 += w0 * v0.y + w1 * v1.y + w2 * v2.y + w3 * v3.y;
    }
    for (; p < end; p++) {
        int s = csr_src[p];
        float w = csr_w[p];
        float2 v = m2[(size_t)s * 64 + lane];
        a0 += w * v.x;
        a1 += w * v.y;
    }
    float2 b = ((const float2*)bias)[lane];
    float2 o;
    o.x = a0 + b.x;
    o.y = a1 + b.y;
    ((float2*)hpre)[(size_t)node * 64 + lane] = o;
}

// ---------- batchnorm stats (sum, sumsq per channel) ----------
__global__ void k_bnstats(const float* __restrict__ hpre, float* __restrict__ stats) {
    int t = threadIdx.x;  // channel, block = 128
    float s = 0.f, s2 = 0.f;
    for (int r = blockIdx.x; r < NN; r += gridDim.x) {
        float v = hpre[(size_t)r * HD + t];
        s += v;
        s2 += v * v;
    }
    atomicAdd(&stats[t], s);
    atomicAdd(&stats[HD + t], s2);
}

// ---------- batchnorm apply + SiLU (final layer only) ----------
__global__ void k_bnapply(const float* __restrict__ hpre, const float* __restrict__ stats,
                          const float* __restrict__ gamma, const float* __restrict__ beta,
                          float* __restrict__ h) {
    int idx = blockIdx.x * 256 + threadIdx.x;
    if (idx >= NN * HD) return;
    int c = idx & (HD - 1);
    const float invn = 1.0f / NN;
    float mu = stats[c] * invn;
    float var = stats[HD + c] * invn - mu * mu;
    float xn = (hpre[idx] - mu) * rsqrtf(var + BN_EPS);
    float y = gamma[c] * xn + beta[c];
    h[idx] = y / (1.f + __expf(-y));  // SiLU
}

// ---------- graph boundaries (batch is sorted) ----------
__global__ void k_gbounds(const int* __restrict__ batch, int* __restrict__ gstart) {
    int g = threadIdx.x;
    if (g > NGR) return;
    int lo = 0, hi = NN;
    while (lo < hi) {
        int mid = (lo + hi) >> 1;
        if (batch[mid] < g) lo = mid + 1;
        else hi = mid;
    }
    gstart[g] = lo;
}

// ---------- pooling stage 1: 16 partial blocks per graph ----------
__global__ void k_poolp(const float* __restrict__ h, const int* __restrict__ gstart,
                        float* __restrict__ ppool) {
    int g = blockIdx.x / PP, p = blockIdx.x % PP;
    int t = threadIdx.x;          // 256
    int c4 = t & 31;              // float4 channel index
    int ro = t >> 5;              // row subgroup 0..7
    int beg = gstart[g], end = gstart[g + 1];
    const float4* h4 = (const float4*)h;
    float4 acc = make_float4(0.f, 0.f, 0.f, 0.f);
    for (int r = beg + p * 8 + ro; r < end; r += PP * 8) {
        float4 v = h4[(size_t)r * 32 + c4];
        acc.x += v.x; acc.y += v.y; acc.z += v.z; acc.w += v.w;
    }
    __shared__ float4 sm[256];
    sm[t] = acc;
    __syncthreads();
    if (t < 128) {
        float4 o = sm[t + 128];
        sm[t].x += o.x; sm[t].y += o.y; sm[t].z += o.z; sm[t].w += o.w;
    }
    __syncthreads();
    if (t < 64) {
        float4 o = sm[t + 64];
        sm[t].x += o.x; sm[t].y += o.y; sm[t].z += o.z; sm[t].w += o.w;
    }
    __syncthreads();
    if (t < 32) {
        float4 o = sm[t + 32];
        float4 r = sm[t];
        r.x += o.x; r.y += o.y; r.z += o.z; r.w += o.w;
        ((float4*)ppool)[(size_t)blockIdx.x * 32 + t] = r;
    }
}

// ---------- pooling stage 2: reduce PP partials, mean ----------
__global__ void k_pool2(const float* __restrict__ ppool, const int* __restrict__ gstart,
                        float* __restrict__ pooled) {
    int g = blockIdx.x;
    int c = threadIdx.x;  // 128
    float s = 0.f;
    for (int p = 0; p < PP; p++) s += ppool[(size_t)(g * PP + p) * HD + c];
    float cnt = (float)(gstart[g + 1] - gstart[g]);
    pooled[g * HD + c] = s / fmaxf(cnt, 1.0f);
}

// ---------- head MLP ----------
__global__ void k_head(const float* __restrict__ pooled,
                       const float* __restrict__ fc1w, const float* __restrict__ fc1b,
                       const float* __restrict__ fc2w, const float* __restrict__ fc2b,
                       float* __restrict__ out) {
    int g = blockIdx.x;
    int j = threadIdx.x;  // 64 threads = 1 wave
    __shared__ float pa[HD];
    pa[j] = pooled[g * HD + j];
    pa[j + 64] = pooled[g * HD + 64 + j];
    __syncthreads();
    float a = fc1b[j];
    for (int k = 0; k < HD; k++) a += pa[k] * fc1w[k * 64 + j];
    a = a / (1.f + __expf(-a));  // SiLU
    float v = a * fc2w[j];
    for (int off = 32; off > 0; off >>= 1) v += __shfl_down(v, off);
    if (j == 0) out[g] = 1.f / (1.f + __expf(-(v + fc2b[0])));
}

extern "C" void kernel_launch(void* const* d_in, const int* in_sizes, int n_in,
                              void* d_out, int out_size, void* d_ws, size_t ws_size,
                              hipStream_t stream) {
    const float* x = (const float*)d_in[0];
    const int* ei = (const int*)d_in[1];  // [2, E]: row=ei[0..E), col=ei[E..2E)
    const float* ea = (const float*)d_in[2];
    const int* batch = (const int*)d_in[3];
    const float* conv0_w = (const float*)d_in[5];
    const float* conv0_b = (const float*)d_in[6];
    const float* conv_ws = (const float*)d_in[7];
    const float* conv_bs = (const float*)d_in[8];
    const float* bn_gamma = (const float*)d_in[9];
    const float* bn_beta = (const float*)d_in[10];
    const float* fc1w = (const float*)d_in[11];
    const float* fc1b = (const float*)d_in[12];
    const float* fc2w = (const float*)d_in[13];
    const float* fc2b = (const float*)d_in[14];
    float* out = (float*)d_out;

    char* ws = (char*)d_ws;
    size_t off = 0;
    auto alloc = [&](size_t bytes) -> char* {
        char* p = ws + off;
        off = (off + bytes + 255) & ~(size_t)255;
        return p;
    };
    float* dinv = (float*)alloc(NN * 4);
    int* cnt = (int*)alloc(NN * 4);
    int* col_ptr = (int*)alloc((NN + 1) * 4);
    int* fill = (int*)alloc(NN * 4);
    int* csr_src = (int*)alloc(NE * 4);
    float* csr_w = (float*)alloc(NE * 4);
    float* mbuf = (float*)alloc((size_t)NN * HD * 4);
    float* hA = (float*)alloc((size_t)NN * HD * 4);
    float* hB = (float*)alloc((size_t)NN * HD * 4);
    float* stats = (float*)alloc(4 * 2 * HD * 4);
    float* pooled = (float*)alloc(NGR * HD * 4);
    float* ppool = (float*)alloc((size_t)NGR * PP * HD * 4);
    int* gstart = (int*)alloc((NGR + 1) * 4);
    int* bsum = (int*)alloc(SCB * 4);
    int* boff = (int*)alloc((SCB + 1) * 4);

    hipMemsetAsync(stats, 0, 4 * 2 * HD * 4, stream);

    k_init<<<(NN + 255) / 256, 256, 0, stream>>>(dinv, cnt, fill);
    k_deg_hist<<<(NE + 255) / 256, 256, 0, stream>>>(ei, ea, dinv, cnt);
    k_dinv<<<(NN + 255) / 256, 256, 0, stream>>>(dinv);
    k_scan1<<<SCB, SCT, 0, stream>>>(cnt, bsum);
    k_scan2<<<1, SCB, 0, stream>>>(bsum, boff);
    k_scan3<<<SCB, SCT, 0, stream>>>(cnt, boff, col_ptr);
    k_scatter<<<(NE + 255) / 256, 256, 0, stream>>>(ei, ea, dinv, col_ptr, fill, csr_src, csr_w);
    k_gbounds<<<1, 128, 0, stream>>>(batch, gstart);

    const int NG128 = (NN + BM - 1) / BM;
    float* st0 = stats;
    float* st1 = stats + 2 * HD;
    float* st2 = stats + 4 * HD;
    float* st3 = stats + 6 * HD;

    // L0
    k_gemm0<<<(NN + 1) / 2, 256, 0, stream>>>(x, conv0_w, mbuf);
    k_agg<<<(NN + 3) / 4, 256, 0, stream>>>(mbuf, col_ptr, csr_src, csr_w, dinv, conv0_b, hA);
    k_bnstats<<<512, HD, 0, stream>>>(hA, st0);
    // L1
    k_gemm128<<<NG128, 256, 0, stream>>>(hA, st0, bn_gamma, bn_beta, conv_ws, mbuf);
    k_agg<<<(NN + 3) / 4, 256, 0, stream>>>(mbuf, col_ptr, csr_src, csr_w, dinv, conv_bs, hB);
    k_bnstats<<<512, HD, 0, stream>>>(hB, st1);
    // L2
    k_gemm128<<<NG128, 256, 0, stream>>>(hB, st1, bn_gamma + HD, bn_beta + HD,
                                         conv_ws + (size_t)HD * HD, mbuf);
    k_agg<<<(NN + 3) / 4, 256, 0, stream>>>(mbuf, col_ptr, csr_src, csr_w, dinv, conv_bs + HD, hA);
    k_bnstats<<<512, HD, 0, stream>>>(hA, st2);
    // L3
    k_gemm128<<<NG128, 256, 0, stream>>>(hA, st2, bn_gamma + 2 * HD, bn_beta + 2 * HD,
                                         conv_ws + (size_t)2 * HD * HD, mbuf);
    k_agg<<<(NN + 3) / 4, 256, 0, stream>>>(mbuf, col_ptr, csr_src, csr_w, dinv, conv_bs + 2 * HD, hB);
    k_bnstats<<<512, HD, 0, stream>>>(hB, st3);
    // final BN+SiLU, pool, head
    k_bnapply<<<(NN * HD + 255) / 256, 256, 0, stream>>>(hB, st3, bn_gamma + 3 * HD,
                                                         bn_beta + 3 * HD, hA);
    k_poolp<<<NGR * PP, 256, 0, stream>>>(hA, gstart, ppool);
    k_pool2<<<NGR, HD, 0, stream>>>(ppool, gstart, pooled);
    k_head<<<NGR, 64, 0, stream>>>(pooled, fc1w, fc1b, fc2w, fc2b, out);
}

// Round 8
// 489.193 us; speedup vs baseline: 5.7353x; 1.1501x over previous
//
#include <hip/hip_runtime.h>

#define NN 50000
#define NE 500000
#define NGR 64
#define HD 128
#define INF 5
#define BN_EPS 1e-5f
#define BM 64
#define SCB 128
#define SCT 256
#define SCH ((NN + SCB - 1) / SCB)
#define PP 16   // pooling parts per graph

// ---------- bf16 helpers ----------
__device__ __forceinline__ float bflo(unsigned u) { return __uint_as_float(u << 16); }
__device__ __forceinline__ float bfhi(unsigned u) { return __uint_as_float(u & 0xffff0000u); }
__device__ __forceinline__ unsigned bfpack(float a, float b) {
    unsigned ua = __float_as_uint(a), ub = __float_as_uint(b);
    ua = (ua + 0x7fffu + ((ua >> 16) & 1u)) >> 16;
    ub = (ub + 0x7fffu + ((ub >> 16) & 1u)) >> 16;
    return ua | (ub << 16);
}

// ---------- init ----------
__global__ void k_init(int* fill) {
    int i = blockIdx.x * 256 + threadIdx.x;
    if (i < NN) fill[i] = 0;
}

// ---------- pass A: per-edge bucket position (the ONLY atomic pass) ----------
__global__ void k_pos(const int* __restrict__ ei, int* __restrict__ fill,
                      int* __restrict__ pos) {
    int e = blockIdx.x * 256 + threadIdx.x;
    if (e < NE) pos[e] = atomicAdd(&fill[ei[NE + e]], 1);
}

// ---------- hierarchical scan of fill -> col_ptr ----------
__global__ void k_scan1(const int* __restrict__ cnt, int* __restrict__ bsum) {
    __shared__ int sm[SCT];
    int b = blockIdx.x, t = threadIdx.x;
    int lo = b * SCH, hi = min(lo + SCH, NN);
    int s = 0;
    for (int i = lo + t; i < hi; i += SCT) s += cnt[i];
    sm[t] = s;
    __syncthreads();
    for (int off = SCT / 2; off > 0; off >>= 1) {
        if (t < off) sm[t] += sm[t + off];
        __syncthreads();
    }
    if (t == 0) bsum[b] = sm[0];
}

__global__ void k_scan2(const int* __restrict__ bsum, int* __restrict__ boff) {
    __shared__ int sm[SCB];
    int t = threadIdx.x;
    sm[t] = bsum[t];
    __syncthreads();
    for (int off = 1; off < SCB; off <<= 1) {
        int v = (t >= off) ? sm[t - off] : 0;
        __syncthreads();
        sm[t] += v;
        __syncthreads();
    }
    boff[t] = (t == 0) ? 0 : sm[t - 1];
    if (t == SCB - 1) boff[SCB] = sm[SCB - 1];
}

__global__ void k_scan3(const int* __restrict__ cnt, const int* __restrict__ boff,
                        int* __restrict__ col_ptr) {
    __shared__ int sm[SCT];
    int b = blockIdx.x, t = threadIdx.x;
    int lo = b * SCH, hi = min(lo + SCH, NN);
    int e0 = lo + 2 * t, e1 = e0 + 1;
    int c0 = (e0 < hi) ? cnt[e0] : 0;
    int c1 = (e1 < hi) ? cnt[e1] : 0;
    sm[t] = c0 + c1;
    __syncthreads();
    for (int off = 1; off < SCT; off <<= 1) {
        int v = (t >= off) ? sm[t - off] : 0;
        __syncthreads();
        sm[t] += v;
        __syncthreads();
    }
    int base = boff[b] + ((t == 0) ? 0 : sm[t - 1]);
    if (e0 < hi) col_ptr[e0] = base;
    if (e1 < hi) col_ptr[e1] = base + c0;
    if (b == SCB - 1 && t == SCT - 1) col_ptr[NN] = boff[SCB];
}

// ---------- pass B: scatter {src, ea} as int2, no atomics ----------
__global__ void k_scatter(const int* __restrict__ ei, const float* __restrict__ ea,
                          const int* __restrict__ col_ptr, const int* __restrict__ pos,
                          int2* __restrict__ sw) {
    int e = blockIdx.x * 256 + threadIdx.x;
    if (e >= NE) return;
    int c = ei[NE + e];
    int p = col_ptr[c] + pos[e];
    sw[p] = make_int2(ei[e], __float_as_int(ea[e]));
}

// ---------- weighted degree via segment sum -> dinv (no atomics) ----------
__global__ void k_degsum(const int* __restrict__ col_ptr, const int2* __restrict__ sw,
                         float* __restrict__ dinv) {
    int i = blockIdx.x * 256 + threadIdx.x;
    if (i >= NN) return;
    int beg = col_ptr[i], end = col_ptr[i + 1];
    float s = 1.0f;  // self-loop weight
    for (int p = beg; p < end; p++) s += __int_as_float(sw[p].y);
    dinv[i] = rsqrtf(s);
}

// ---------- rewrite ea -> normalized weight in place ----------
__global__ void k_wnorm(const int* __restrict__ col_ptr, const float* __restrict__ dinv,
                        int2* __restrict__ sw) {
    int i = blockIdx.x * 256 + threadIdx.x;
    if (i >= NN) return;
    int beg = col_ptr[i], end = col_ptr[i + 1];
    float di = dinv[i];
    for (int p = beg; p < end; p++) {
        int2 v = sw[p];
        float w = dinv[v.x] * __int_as_float(v.y) * di;
        sw[p].y = __float_as_int(w);
    }
}

// ---------- layer-0 transform: m = x @ W0 (K=5), bf16 output ----------
__global__ void k_gemm0(const float* __restrict__ x, const float* __restrict__ W,
                        unsigned* __restrict__ m32) {
    __shared__ float Ws[INF][HD];
    int t = threadIdx.x;  // 256
    for (int i = t; i < INF * HD; i += 256) ((float*)Ws)[i] = W[i];
    __syncthreads();
    int row = blockIdx.x * 4 + (t >> 6);
    if (row >= NN) return;
    int lane = t & 63;
    int c0 = 2 * lane;
    float xv[INF];
#pragma unroll
    for (int k = 0; k < INF; k++) xv[k] = x[row * INF + k];
    float a0 = 0.f, a1 = 0.f;
#pragma unroll
    for (int k = 0; k < INF; k++) {
        a0 += xv[k] * Ws[k][c0];
        a1 += xv[k] * Ws[k][c0 + 1];
    }
    m32[(size_t)row * 64 + lane] = bfpack(a0, a1);
}

// ---------- fused BN(prev)+SiLU + GEMM: m = silu(bn(hpre)) @ W, bf16 out ----------
__global__ __launch_bounds__(256, 4) void k_gemm128(
    const float* __restrict__ hpre, const float* __restrict__ stats,
    const float* __restrict__ gamma, const float* __restrict__ beta,
    const float* __restrict__ W, unsigned* __restrict__ m32) {
    __shared__ float hs[BM][HD];   // 32 KB
    __shared__ float sc[HD], sh[HD];
    int t = threadIdx.x;
    int r0 = blockIdx.x * BM;
    const float invn = 1.0f / NN;

    if (t < HD) {
        float mu = stats[t] * invn;
        float var = stats[HD + t] * invn - mu * mu;
        float s = gamma[t] * rsqrtf(var + BN_EPS);
        sc[t] = s;
        sh[t] = beta[t] - mu * s;
    }
    __syncthreads();

#pragma unroll
    for (int i = 0; i < 8; i++) {
        int idx4 = i * 256 + t;
        int r = idx4 >> 5;
        int c4 = idx4 & 31;
        float4 v = make_float4(0.f, 0.f, 0.f, 0.f);
        if (r0 + r < NN) v = ((const float4*)hpre)[(size_t)(r0 + r) * 32 + c4];
        int c = c4 * 4;
#pragma unroll
        for (int q = 0; q < 4; q++) {
            float y = sc[c + q] * (&v.x)[q] + sh[c + q];
            (&v.x)[q] = y / (1.f + __expf(-y));
        }
        ((float4*)&hs[0][0])[idx4] = v;
    }
    __syncthreads();

    int rg = t >> 5, cg = t & 31;
    int rr = rg * 8;
    float acc[8][4];
#pragma unroll
    for (int i = 0; i < 8; i++)
#pragma unroll
        for (int j = 0; j < 4; j++) acc[i][j] = 0.f;

    const float4* Wp = (const float4*)W;  // [HD][32] float4 view
#pragma unroll 2
    for (int k4 = 0; k4 < HD / 4; k4++) {
        float4 wv0 = Wp[(k4 * 4 + 0) * 32 + cg];
        float4 wv1 = Wp[(k4 * 4 + 1) * 32 + cg];
        float4 wv2 = Wp[(k4 * 4 + 2) * 32 + cg];
        float4 wv3 = Wp[(k4 * 4 + 3) * 32 + cg];
#pragma unroll
        for (int i = 0; i < 8; i++) {
            float4 hv = *(const float4*)&hs[rr + i][k4 * 4];
            acc[i][0] += hv.x * wv0.x + hv.y * wv1.x + hv.z * wv2.x + hv.w * wv3.x;
            acc[i][1] += hv.x * wv0.y + hv.y * wv1.y + hv.z * wv2.y + hv.w * wv3.y;
            acc[i][2] += hv.x * wv0.z + hv.y * wv1.z + hv.z * wv2.z + hv.w * wv3.z;
            acc[i][3] += hv.x * wv0.w + hv.y * wv1.w + hv.z * wv2.w + hv.w * wv3.w;
        }
    }

#pragma unroll
    for (int i = 0; i < 8; i++) {
        int r = r0 + rr + i;
        if (r < NN) {
            uint2 pk = make_uint2(bfpack(acc[i][0], acc[i][1]), bfpack(acc[i][2], acc[i][3]));
            ((uint2*)m32)[(size_t)r * 32 + cg] = pk;
        }
    }
}

// ---------- sparse aggregation: bf16 gathers, f32 accumulate ----------
__global__ void k_agg(const unsigned* __restrict__ m32, const int* __restrict__ col_ptr,
                      const int2* __restrict__ sw, const float* __restrict__ dinv,
                      const float* __restrict__ bias, float* __restrict__ hpre) {
    int node = blockIdx.x * 4 + (threadIdx.x >> 6);
    if (node >= NN) return;
    int lane = threadIdx.x & 63;
    float di = dinv[node];
    unsigned sv = m32[(size_t)node * 64 + lane];
    float a0 = di * di * bflo(sv);
    float a1 = di * di * bfhi(sv);
    int beg = col_ptr[node], end = col_ptr[node + 1];
    int p = beg;
    for (; p + 8 <= end; p += 8) {
        int2 e0 = sw[p], e1 = sw[p + 1], e2 = sw[p + 2], e3 = sw[p + 3];
        int2 e4 = sw[p + 4], e5 = sw[p + 5], e6 = sw[p + 6], e7 = sw[p + 7];
        unsigned v0 = m32[(size_t)e0.x * 64 + lane];
        unsigned v1 = m32[(size_t)e1.x * 64 + lane];
        unsigned v2 = m32[(size_t)e2.x * 64 + lane];
        unsigned v3 = m32[(size_t)e3.x * 64 + lane];
        unsigned v4 = m32[(size_t)e4.x * 64 + lane];
        unsigned v5 = m32[(size_t)e5.x * 64 + lane];
        unsigned v6 = m32[(size_t)e6.x * 64 + lane];
        unsigned v7 = m32[(size_t)e7.x * 64 + lane];
        float w0 = __int_as_float(e0.y), w1 = __int_as_float(e1.y);
        float w2 = __int_as_float(e2.y), w3 = __int_as_float(e3.y);
        float w4 = __int_as_float(e4.y), w5 = __int_as_float(e5.y);
        float w6 = __int_as_float(e6.y), w7 = __int_as_float(e7.y);
        a0 += w0 * bflo(v0) + w1 * bflo(v1) + w2 * bflo(v2) + w3 * bflo(v3);
        a1 += w0 * bfhi(v0) + w1 * bfhi(v1) + w2 * bfhi(v2) + w3 * bfhi(v3);
        a0 += w4 * bflo(v4) + w5 * bflo(v5) + w6 * bflo(v6) + w7 * bflo(v7);
        a1 += w4 * bfhi(v4) + w5 * bfhi(v5) + w6 * bfhi(v6) + w7 * bfhi(v7);
    }
    for (; p < end; p++) {
        int2 e = sw[p];
        unsigned v = m32[(size_t)e.x * 64 + lane];
        float w = __int_as_float(e.y);
        a0 += w * bflo(v);
        a1 += w * bfhi(v);
    }
    float2 b = ((const float2*)bias)[lane];
    float2 o;
    o.x = a0 + b.x;
    o.y = a1 + b.y;
    ((float2*)hpre)[(size_t)node * 64 + lane] = o;
}

// ---------- batchnorm stats (sum, sumsq per channel) ----------
__global__ void k_bnstats(const float* __restrict__ hpre, float* __restrict__ stats) {
    int t = threadIdx.x;  // channel, block = 128
    float s = 0.f, s2 = 0.f;
    for (int r = blockIdx.x; r < NN; r += gridDim.x) {
        float v = hpre[(size_t)r * HD + t];
        s += v;
        s2 += v * v;
    }
    atomicAdd(&stats[t], s);
    atomicAdd(&stats[HD + t], s2);
}

// ---------- batchnorm apply + SiLU (final layer only) ----------
__global__ void k_bnapply(const float* __restrict__ hpre, const float* __restrict__ stats,
                          const float* __restrict__ gamma, const float* __restrict__ beta,
                          float* __restrict__ h) {
    int idx = blockIdx.x * 256 + threadIdx.x;
    if (idx >= NN * HD) return;
    int c = idx & (HD - 1);
    const float invn = 1.0f / NN;
    float mu = stats[c] * invn;
    float var = stats[HD + c] * invn - mu * mu;
    float xn = (hpre[idx] - mu) * rsqrtf(var + BN_EPS);
    float y = gamma[c] * xn + beta[c];
    h[idx] = y / (1.f + __expf(-y));  // SiLU
}

// ---------- graph boundaries (batch is sorted) ----------
__global__ void k_gbounds(const int* __restrict__ batch, int* __restrict__ gstart) {
    int g = threadIdx.x;
    if (g > NGR) return;
    int lo = 0, hi = NN;
    while (lo < hi) {
        int mid = (lo + hi) >> 1;
        if (batch[mid] < g) lo = mid + 1;
        else hi = mid;
    }
    gstart[g] = lo;
}

// ---------- pooling stage 1: 16 partial blocks per graph ----------
__global__ void k_poolp(const float* __restrict__ h, const int* __restrict__ gstart,
                        float* __restrict__ ppool) {
    int g = blockIdx.x / PP, p = blockIdx.x % PP;
    int t = threadIdx.x;          // 256
    int c4 = t & 31;
    int ro = t >> 5;
    int beg = gstart[g], end = gstart[g + 1];
    const float4* h4 = (const float4*)h;
    float4 acc = make_float4(0.f, 0.f, 0.f, 0.f);
    for (int r = beg + p * 8 + ro; r < end; r += PP * 8) {
        float4 v = h4[(size_t)r * 32 + c4];
        acc.x += v.x; acc.y += v.y; acc.z += v.z; acc.w += v.w;
    }
    __shared__ float4 sm[256];
    sm[t] = acc;
    __syncthreads();
    if (t < 128) {
        float4 o = sm[t + 128];
        sm[t].x += o.x; sm[t].y += o.y; sm[t].z += o.z; sm[t].w += o.w;
    }
    __syncthreads();
    if (t < 64) {
        float4 o = sm[t + 64];
        sm[t].x += o.x; sm[t].y += o.y; sm[t].z += o.z; sm[t].w += o.w;
    }
    __syncthreads();
    if (t < 32) {
        float4 o = sm[t + 32];
        float4 r = sm[t];
        r.x += o.x; r.y += o.y; r.z += o.z; r.w += o.w;
        ((float4*)ppool)[(size_t)blockIdx.x * 32 + t] = r;
    }
}

// ---------- pooling stage 2: reduce PP partials, mean ----------
__global__ void k_pool2(const float* __restrict__ ppool, const int* __restrict__ gstart,
                        float* __restrict__ pooled) {
    int g = blockIdx.x;
    int c = threadIdx.x;  // 128
    float s = 0.f;
    for (int p = 0; p < PP; p++) s += ppool[(size_t)(g * PP + p) * HD + c];
    float cnt = (float)(gstart[g + 1] - gstart[g]);
    pooled[g * HD + c] = s / fmaxf(cnt, 1.0f);
}

// ---------- head MLP ----------
__global__ void k_head(const float* __restrict__ pooled,
                       const float* __restrict__ fc1w, const float* __restrict__ fc1b,
                       const float* __restrict__ fc2w, const float* __restrict__ fc2b,
                       float* __restrict__ out) {
    int g = blockIdx.x;
    int j = threadIdx.x;  // 64 threads = 1 wave
    __shared__ float pa[HD];
    pa[j] = pooled[g * HD + j];
    pa[j + 64] = pooled[g * HD + 64 + j];
    __syncthreads();
    float a = fc1b[j];
    for (int k = 0; k < HD; k++) a += pa[k] * fc1w[k * 64 + j];
    a = a / (1.f + __expf(-a));  // SiLU
    float v = a * fc2w[j];
    for (int off = 32; off > 0; off >>= 1) v += __shfl_down(v, off);
    if (j == 0) out[g] = 1.f / (1.f + __expf(-(v + fc2b[0])));
}

extern "C" void kernel_launch(void* const* d_in, const int* in_sizes, int n_in,
                              void* d_out, int out_size, void* d_ws, size_t ws_size,
                              hipStream_t stream) {
    const float* x = (const float*)d_in[0];
    const int* ei = (const int*)d_in[1];  // [2, E]: row=ei[0..E), col=ei[E..2E)
    const float* ea = (const float*)d_in[2];
    const int* batch = (const int*)d_in[3];
    const float* conv0_w = (const float*)d_in[5];
    const float* conv0_b = (const float*)d_in[6];
    const float* conv_ws = (const float*)d_in[7];
    const float* conv_bs = (const float*)d_in[8];
    const float* bn_gamma = (const float*)d_in[9];
    const float* bn_beta = (const float*)d_in[10];
    const float* fc1w = (const float*)d_in[11];
    const float* fc1b = (const float*)d_in[12];
    const float* fc2w = (const float*)d_in[13];
    const float* fc2b = (const float*)d_in[14];
    float* out = (float*)d_out;

    char* ws = (char*)d_ws;
    size_t off = 0;
    auto alloc = [&](size_t bytes) -> char* {
        char* p = ws + off;
        off = (off + bytes + 255) & ~(size_t)255;
        return p;
    };
    float* dinv = (float*)alloc(NN * 4);
    int* fill = (int*)alloc(NN * 4);
    int* col_ptr = (int*)alloc((NN + 1) * 4);
    int* pos = (int*)alloc(NE * 4);
    int2* sw = (int2*)alloc((size_t)NE * 8);
    unsigned* mbuf = (unsigned*)alloc((size_t)NN * HD * 2);  // bf16 packed
    float* hA = (float*)alloc((size_t)NN * HD * 4);
    float* hB = (float*)alloc((size_t)NN * HD * 4);
    float* stats = (float*)alloc(4 * 2 * HD * 4);
    float* pooled = (float*)alloc(NGR * HD * 4);
    float* ppool = (float*)alloc((size_t)NGR * PP * HD * 4);
    int* gstart = (int*)alloc((NGR + 1) * 4);
    int* bsum = (int*)alloc(SCB * 4);
    int* boff = (int*)alloc((SCB + 1) * 4);

    hipMemsetAsync(stats, 0, 4 * 2 * HD * 4, stream);

    k_init<<<(NN + 255) / 256, 256, 0, stream>>>(fill);
    k_pos<<<(NE + 255) / 256, 256, 0, stream>>>(ei, fill, pos);
    k_scan1<<<SCB, SCT, 0, stream>>>(fill, bsum);
    k_scan2<<<1, SCB, 0, stream>>>(bsum, boff);
    k_scan3<<<SCB, SCT, 0, stream>>>(fill, boff, col_ptr);
    k_scatter<<<(NE + 255) / 256, 256, 0, stream>>>(ei, ea, col_ptr, pos, sw);
    k_degsum<<<(NN + 255) / 256, 256, 0, stream>>>(col_ptr, sw, dinv);
    k_wnorm<<<(NN + 255) / 256, 256, 0, stream>>>(col_ptr, dinv, sw);
    k_gbounds<<<1, 128, 0, stream>>>(batch, gstart);

    const int NG128 = (NN + BM - 1) / BM;
    float* st0 = stats;
    float* st1 = stats + 2 * HD;
    float* st2 = stats + 4 * HD;
    float* st3 = stats + 6 * HD;

    // L0
    k_gemm0<<<(NN + 3) / 4, 256, 0, stream>>>(x, conv0_w, mbuf);
    k_agg<<<(NN + 3) / 4, 256, 0, stream>>>(mbuf, col_ptr, sw, dinv, conv0_b, hA);
    k_bnstats<<<512, HD, 0, stream>>>(hA, st0);
    // L1
    k_gemm128<<<NG128, 256, 0, stream>>>(hA, st0, bn_gamma, bn_beta, conv_ws, mbuf);
    k_agg<<<(NN + 3) / 4, 256, 0, stream>>>(mbuf, col_ptr, sw, dinv, conv_bs, hB);
    k_bnstats<<<512, HD, 0, stream>>>(hB, st1);
    // L2
    k_gemm128<<<NG128, 256, 0, stream>>>(hB, st1, bn_gamma + HD, bn_beta + HD,
                                         conv_ws + (size_t)HD * HD, mbuf);
    k_agg<<<(NN + 3) / 4, 256, 0, stream>>>(mbuf, col_ptr, sw, dinv, conv_bs + HD, hA);
    k_bnstats<<<512, HD, 0, stream>>>(hA, st2);
    // L3
    k_gemm128<<<NG128, 256, 0, stream>>>(hA, st2, bn_gamma + 2 * HD, bn_beta + 2 * HD,
                                         conv_ws + (size_t)2 * HD * HD, mbuf);
    k_agg<<<(NN + 3) / 4, 256, 0, stream>>>(mbuf, col_ptr, sw, dinv, conv_bs + 2 * HD, hB);
    k_bnstats<<<512, HD, 0, stream>>>(hB, st3);
    // final BN+SiLU, pool, head
    k_bnapply<<<(NN * HD + 255) / 256, 256, 0, stream>>>(hB, st3, bn_gamma + 3 * HD,
                                                         bn_beta + 3 * HD, hA);
    k_poolp<<<NGR * PP, 256, 0, stream>>>(hA, gstart, ppool);
    k_pool2<<<NGR, HD, 0, stream>>>(ppool, gstart, pooled);
    k_head<<<NGR, 64, 0, stream>>>(pooled, fc1w, fc1b, fc2w, fc2b, out);
}

// Round 9
// 479.778 us; speedup vs baseline: 5.8478x; 1.0196x over previous
//
#include <hip/hip_runtime.h>

#define NN 50000
#define NE 500000
#define NGR 64
#define HD 128
#define INF 5
#define BN_EPS 1e-5f
#define BM 64
#define SCB 128
#define SCT 256
#define SCH ((NN + SCB - 1) / SCB)
#define PP 16   // pooling parts per graph

// ---------- bf16 helpers ----------
__device__ __forceinline__ float bflo(unsigned u) { return __uint_as_float(u << 16); }
__device__ __forceinline__ float bfhi(unsigned u) { return __uint_as_float(u & 0xffff0000u); }
__device__ __forceinline__ unsigned bfpack(float a, float b) {
    unsigned ua = __float_as_uint(a), ub = __float_as_uint(b);
    ua = (ua + 0x7fffu + ((ua >> 16) & 1u)) >> 16;
    ub = (ub + 0x7fffu + ((ub >> 16) & 1u)) >> 16;
    return ua | (ub << 16);
}

// ---------- init: fill=0, stats=0 ----------
__global__ void k_init(int* fill, float* stats) {
    int i = blockIdx.x * 256 + threadIdx.x;
    if (i < NN) fill[i] = 0;
    if (blockIdx.x == 0) {
        for (int j = threadIdx.x; j < 4 * 2 * HD; j += 256) stats[j] = 0.f;
    }
}

// ---------- pass A: per-edge bucket position (the ONLY atomic pass) ----------
__global__ void k_pos(const int* __restrict__ ei, int* __restrict__ fill,
                      int* __restrict__ pos) {
    int e = blockIdx.x * 256 + threadIdx.x;
    if (e < NE) pos[e] = atomicAdd(&fill[ei[NE + e]], 1);
}

// ---------- hierarchical scan of fill -> col_ptr ----------
__global__ void k_scan1(const int* __restrict__ cnt, int* __restrict__ bsum) {
    __shared__ int sm[SCT];
    int b = blockIdx.x, t = threadIdx.x;
    int lo = b * SCH, hi = min(lo + SCH, NN);
    int s = 0;
    for (int i = lo + t; i < hi; i += SCT) s += cnt[i];
    sm[t] = s;
    __syncthreads();
    for (int off = SCT / 2; off > 0; off >>= 1) {
        if (t < off) sm[t] += sm[t + off];
        __syncthreads();
    }
    if (t == 0) bsum[b] = sm[0];
}

__global__ void k_scan2(const int* __restrict__ bsum, int* __restrict__ boff) {
    __shared__ int sm[SCB];
    int t = threadIdx.x;
    sm[t] = bsum[t];
    __syncthreads();
    for (int off = 1; off < SCB; off <<= 1) {
        int v = (t >= off) ? sm[t - off] : 0;
        __syncthreads();
        sm[t] += v;
        __syncthreads();
    }
    boff[t] = (t == 0) ? 0 : sm[t - 1];
    if (t == SCB - 1) boff[SCB] = sm[SCB - 1];
}

__global__ void k_scan3(const int* __restrict__ cnt, const int* __restrict__ boff,
                        int* __restrict__ col_ptr) {
    __shared__ int sm[SCT];
    int b = blockIdx.x, t = threadIdx.x;
    int lo = b * SCH, hi = min(lo + SCH, NN);
    int e0 = lo + 2 * t, e1 = e0 + 1;
    int c0 = (e0 < hi) ? cnt[e0] : 0;
    int c1 = (e1 < hi) ? cnt[e1] : 0;
    sm[t] = c0 + c1;
    __syncthreads();
    for (int off = 1; off < SCT; off <<= 1) {
        int v = (t >= off) ? sm[t - off] : 0;
        __syncthreads();
        sm[t] += v;
        __syncthreads();
    }
    int base = boff[b] + ((t == 0) ? 0 : sm[t - 1]);
    if (e0 < hi) col_ptr[e0] = base;
    if (e1 < hi) col_ptr[e1] = base + c0;
    if (b == SCB - 1 && t == SCT - 1) col_ptr[NN] = boff[SCB];
}

// ---------- pass B: scatter {src, ea} as int2 + dst per slot, no atomics ----------
__global__ void k_scatter(const int* __restrict__ ei, const float* __restrict__ ea,
                          const int* __restrict__ col_ptr, const int* __restrict__ pos,
                          int2* __restrict__ sw, int* __restrict__ dst) {
    int e = blockIdx.x * 256 + threadIdx.x;
    if (e >= NE) return;
    int c = ei[NE + e];
    int p = col_ptr[c] + pos[e];
    sw[p] = make_int2(ei[e], __float_as_int(ea[e]));
    dst[p] = c;
}

// ---------- weighted degree via segment sum -> dinv (no atomics) ----------
__global__ void k_degsum(const int* __restrict__ col_ptr, const int2* __restrict__ sw,
                         float* __restrict__ dinv) {
    int i = blockIdx.x * 256 + threadIdx.x;
    if (i >= NN) return;
    int beg = col_ptr[i], end = col_ptr[i + 1];
    float s = 1.0f;  // self-loop weight
    for (int p = beg; p < end; p++) s += __int_as_float(sw[p].y);
    dinv[i] = rsqrtf(s);
}

// ---------- edge-parallel weight normalization ----------
__global__ void k_wnorm(const float* __restrict__ dinv, const int* __restrict__ dst,
                        int2* __restrict__ sw) {
    int p = blockIdx.x * 256 + threadIdx.x;
    if (p >= NE) return;
    int2 v = sw[p];
    float w = dinv[v.x] * __int_as_float(v.y) * dinv[dst[p]];
    sw[p] = make_int2(v.x, __float_as_int(w));
}

// ---------- layer-0 transform: m = x @ W0 (K=5), bf16 output ----------
__global__ void k_gemm0(const float* __restrict__ x, const float* __restrict__ W,
                        unsigned* __restrict__ m32) {
    __shared__ float Ws[INF][HD];
    int t = threadIdx.x;  // 256
    for (int i = t; i < INF * HD; i += 256) ((float*)Ws)[i] = W[i];
    __syncthreads();
    int row = blockIdx.x * 4 + (t >> 6);
    if (row >= NN) return;
    int lane = t & 63;
    int c0 = 2 * lane;
    float xv[INF];
#pragma unroll
    for (int k = 0; k < INF; k++) xv[k] = x[row * INF + k];
    float a0 = 0.f, a1 = 0.f;
#pragma unroll
    for (int k = 0; k < INF; k++) {
        a0 += xv[k] * Ws[k][c0];
        a1 += xv[k] * Ws[k][c0 + 1];
    }
    m32[(size_t)row * 64 + lane] = bfpack(a0, a1);
}

// ---------- fused BN(prev)+SiLU + GEMM: m = silu(bn(hpre)) @ W, bf16 out ----------
__global__ __launch_bounds__(256, 4) void k_gemm128(
    const float* __restrict__ hpre, const float* __restrict__ stats,
    const float* __restrict__ gamma, const float* __restrict__ beta,
    const float* __restrict__ W, unsigned* __restrict__ m32) {
    __shared__ float hs[BM][HD];   // 32 KB
    __shared__ float sc[HD], sh[HD];
    int t = threadIdx.x;
    int r0 = blockIdx.x * BM;
    const float invn = 1.0f / NN;

    if (t < HD) {
        float mu = stats[t] * invn;
        float var = stats[HD + t] * invn - mu * mu;
        float s = gamma[t] * rsqrtf(var + BN_EPS);
        sc[t] = s;
        sh[t] = beta[t] - mu * s;
    }
    __syncthreads();

#pragma unroll
    for (int i = 0; i < 8; i++) {
        int idx4 = i * 256 + t;
        int r = idx4 >> 5;
        int c4 = idx4 & 31;
        float4 v = make_float4(0.f, 0.f, 0.f, 0.f);
        if (r0 + r < NN) v = ((const float4*)hpre)[(size_t)(r0 + r) * 32 + c4];
        int c = c4 * 4;
#pragma unroll
        for (int q = 0; q < 4; q++) {
            float y = sc[c + q] * (&v.x)[q] + sh[c + q];
            (&v.x)[q] = y / (1.f + __expf(-y));
        }
        ((float4*)&hs[0][0])[idx4] = v;
    }
    __syncthreads();

    int rg = t >> 5, cg = t & 31;
    int rr = rg * 8;
    float acc[8][4];
#pragma unroll
    for (int i = 0; i < 8; i++)
#pragma unroll
        for (int j = 0; j < 4; j++) acc[i][j] = 0.f;

    const float4* Wp = (const float4*)W;  // [HD][32] float4 view
#pragma unroll 2
    for (int k4 = 0; k4 < HD / 4; k4++) {
        float4 wv0 = Wp[(k4 * 4 + 0) * 32 + cg];
        float4 wv1 = Wp[(k4 * 4 + 1) * 32 + cg];
        float4 wv2 = Wp[(k4 * 4 + 2) * 32 + cg];
        float4 wv3 = Wp[(k4 * 4 + 3) * 32 + cg];
#pragma unroll
        for (int i = 0; i < 8; i++) {
            float4 hv = *(const float4*)&hs[rr + i][k4 * 4];
            acc[i][0] += hv.x * wv0.x + hv.y * wv1.x + hv.z * wv2.x + hv.w * wv3.x;
            acc[i][1] += hv.x * wv0.y + hv.y * wv1.y + hv.z * wv2.y + hv.w * wv3.y;
            acc[i][2] += hv.x * wv0.z + hv.y * wv1.z + hv.z * wv2.z + hv.w * wv3.z;
            acc[i][3] += hv.x * wv0.w + hv.y * wv1.w + hv.z * wv2.w + hv.w * wv3.w;
        }
    }

#pragma unroll
    for (int i = 0; i < 8; i++) {
        int r = r0 + rr + i;
        if (r < NN) {
            uint2 pk = make_uint2(bfpack(acc[i][0], acc[i][1]), bfpack(acc[i][2], acc[i][3]));
            ((uint2*)m32)[(size_t)r * 32 + cg] = pk;
        }
    }
}

// ---------- sparse aggregation: bf16 gathers, f32 accumulate ----------
__global__ void k_agg(const unsigned* __restrict__ m32, const int* __restrict__ col_ptr,
                      const int2* __restrict__ sw, const float* __restrict__ dinv,
                      const float* __restrict__ bias, float* __restrict__ hpre) {
    int node = blockIdx.x * 4 + (threadIdx.x >> 6);
    if (node >= NN) return;
    int lane = threadIdx.x & 63;
    float di = dinv[node];
    unsigned sv = m32[(size_t)node * 64 + lane];
    float a0 = di * di * bflo(sv);
    float a1 = di * di * bfhi(sv);
    int beg = col_ptr[node], end = col_ptr[node + 1];
    int p = beg;
    for (; p + 8 <= end; p += 8) {
        int2 e0 = sw[p], e1 = sw[p + 1], e2 = sw[p + 2], e3 = sw[p + 3];
        int2 e4 = sw[p + 4], e5 = sw[p + 5], e6 = sw[p + 6], e7 = sw[p + 7];
        unsigned v0 = m32[(size_t)e0.x * 64 + lane];
        unsigned v1 = m32[(size_t)e1.x * 64 + lane];
        unsigned v2 = m32[(size_t)e2.x * 64 + lane];
        unsigned v3 = m32[(size_t)e3.x * 64 + lane];
        unsigned v4 = m32[(size_t)e4.x * 64 + lane];
        unsigned v5 = m32[(size_t)e5.x * 64 + lane];
        unsigned v6 = m32[(size_t)e6.x * 64 + lane];
        unsigned v7 = m32[(size_t)e7.x * 64 + lane];
        float w0 = __int_as_float(e0.y), w1 = __int_as_float(e1.y);
        float w2 = __int_as_float(e2.y), w3 = __int_as_float(e3.y);
        float w4 = __int_as_float(e4.y), w5 = __int_as_float(e5.y);
        float w6 = __int_as_float(e6.y), w7 = __int_as_float(e7.y);
        a0 += w0 * bflo(v0) + w1 * bflo(v1) + w2 * bflo(v2) + w3 * bflo(v3);
        a1 += w0 * bfhi(v0) + w1 * bfhi(v1) + w2 * bfhi(v2) + w3 * bfhi(v3);
        a0 += w4 * bflo(v4) + w5 * bflo(v5) + w6 * bflo(v6) + w7 * bflo(v7);
        a1 += w4 * bfhi(v4) + w5 * bfhi(v5) + w6 * bfhi(v6) + w7 * bfhi(v7);
    }
    for (; p < end; p++) {
        int2 e = sw[p];
        unsigned v = m32[(size_t)e.x * 64 + lane];
        float w = __int_as_float(e.y);
        a0 += w * bflo(v);
        a1 += w * bfhi(v);
    }
    float2 b = ((const float2*)bias)[lane];
    float2 o;
    o.x = a0 + b.x;
    o.y = a1 + b.y;
    ((float2*)hpre)[(size_t)node * 64 + lane] = o;
}

// ---------- batchnorm stats (sum, sumsq per channel) ----------
__global__ void k_bnstats(const float* __restrict__ hpre, float* __restrict__ stats) {
    int t = threadIdx.x;  // channel, block = 128
    float s = 0.f, s2 = 0.f;
    for (int r = blockIdx.x; r < NN; r += gridDim.x) {
        float v = hpre[(size_t)r * HD + t];
        s += v;
        s2 += v * v;
    }
    atomicAdd(&stats[t], s);
    atomicAdd(&stats[HD + t], s2);
}

// ---------- graph boundaries (batch is sorted) ----------
__global__ void k_gbounds(const int* __restrict__ batch, int* __restrict__ gstart) {
    int g = threadIdx.x;
    if (g > NGR) return;
    int lo = 0, hi = NN;
    while (lo < hi) {
        int mid = (lo + hi) >> 1;
        if (batch[mid] < g) lo = mid + 1;
        else hi = mid;
    }
    gstart[g] = lo;
}

// ---------- pooling stage 1 (fused final BN+SiLU): 16 partial blocks/graph ----------
__global__ void k_poolp(const float* __restrict__ hpre, const float* __restrict__ stats,
                        const float* __restrict__ gamma, const float* __restrict__ beta,
                        const int* __restrict__ gstart, float* __restrict__ ppool) {
    int g = blockIdx.x / PP, p = blockIdx.x % PP;
    int t = threadIdx.x;          // 256
    int c4 = t & 31;
    int ro = t >> 5;
    const float invn = 1.0f / NN;
    // per-thread BN scale/shift for 4 channels
    float sc[4], sh[4];
#pragma unroll
    for (int q = 0; q < 4; q++) {
        int c = c4 * 4 + q;
        float mu = stats[c] * invn;
        float var = stats[HD + c] * invn - mu * mu;
        float s = gamma[c] * rsqrtf(var + BN_EPS);
        sc[q] = s;
        sh[q] = beta[c] - mu * s;
    }
    int beg = gstart[g], end = gstart[g + 1];
    const float4* h4 = (const float4*)hpre;
    float4 acc = make_float4(0.f, 0.f, 0.f, 0.f);
    for (int r = beg + p * 8 + ro; r < end; r += PP * 8) {
        float4 v = h4[(size_t)r * 32 + c4];
#pragma unroll
        for (int q = 0; q < 4; q++) {
            float y = sc[q] * (&v.x)[q] + sh[q];
            (&v.x)[q] = y / (1.f + __expf(-y));
        }
        acc.x += v.x; acc.y += v.y; acc.z += v.z; acc.w += v.w;
    }
    __shared__ float4 sm[256];
    sm[t] = acc;
    __syncthreads();
    if (t < 128) {
        float4 o = sm[t + 128];
        sm[t].x += o.x; sm[t].y += o.y; sm[t].z += o.z; sm[t].w += o.w;
    }
    __syncthreads();
    if (t < 64) {
        float4 o = sm[t + 64];
        sm[t].x += o.x; sm[t].y += o.y; sm[t].z += o.z; sm[t].w += o.w;
    }
    __syncthreads();
    if (t < 32) {
        float4 o = sm[t + 32];
        float4 r = sm[t];
        r.x += o.x; r.y += o.y; r.z += o.z; r.w += o.w;
        ((float4*)ppool)[(size_t)blockIdx.x * 32 + t] = r;
    }
}

// ---------- pooling stage 2 + head MLP fused: one block per graph ----------
__global__ void k_pool_head(const float* __restrict__ ppool, const int* __restrict__ gstart,
                            const float* __restrict__ fc1w, const float* __restrict__ fc1b,
                            const float* __restrict__ fc2w, const float* __restrict__ fc2b,
                            float* __restrict__ out) {
    int g = blockIdx.x;
    int t = threadIdx.x;  // 128
    __shared__ float pa[HD];
    float s = 0.f;
    for (int p = 0; p < PP; p++) s += ppool[(size_t)(g * PP + p) * HD + t];
    float cnt = (float)(gstart[g + 1] - gstart[g]);
    pa[t] = s / fmaxf(cnt, 1.0f);
    __syncthreads();
    if (t < 64) {
        float a = fc1b[t];
        for (int k = 0; k < HD; k++) a += pa[k] * fc1w[k * 64 + t];
        a = a / (1.f + __expf(-a));  // SiLU
        float v = a * fc2w[t];
        for (int off = 32; off > 0; off >>= 1) v += __shfl_down(v, off);
        if (t == 0) out[g] = 1.f / (1.f + __expf(-(v + fc2b[0])));
    }
}

extern "C" void kernel_launch(void* const* d_in, const int* in_sizes, int n_in,
                              void* d_out, int out_size, void* d_ws, size_t ws_size,
                              hipStream_t stream) {
    const float* x = (const float*)d_in[0];
    const int* ei = (const int*)d_in[1];  // [2, E]: row=ei[0..E), col=ei[E..2E)
    const float* ea = (const float*)d_in[2];
    const int* batch = (const int*)d_in[3];
    const float* conv0_w = (const float*)d_in[5];
    const float* conv0_b = (const float*)d_in[6];
    const float* conv_ws = (const float*)d_in[7];
    const float* conv_bs = (const float*)d_in[8];
    const float* bn_gamma = (const float*)d_in[9];
    const float* bn_beta = (const float*)d_in[10];
    const float* fc1w = (const float*)d_in[11];
    const float* fc1b = (const float*)d_in[12];
    const float* fc2w = (const float*)d_in[13];
    const float* fc2b = (const float*)d_in[14];
    float* out = (float*)d_out;

    char* ws = (char*)d_ws;
    size_t off = 0;
    auto alloc = [&](size_t bytes) -> char* {
        char* p = ws + off;
        off = (off + bytes + 255) & ~(size_t)255;
        return p;
    };
    float* dinv = (float*)alloc(NN * 4);
    int* fill = (int*)alloc(NN * 4);
    int* col_ptr = (int*)alloc((NN + 1) * 4);
    int* pos = (int*)alloc(NE * 4);
    int* dstv = (int*)alloc(NE * 4);
    int2* sw = (int2*)alloc((size_t)NE * 8);
    unsigned* mbuf = (unsigned*)alloc((size_t)NN * HD * 2);  // bf16 packed
    float* hA = (float*)alloc((size_t)NN * HD * 4);
    float* hB = (float*)alloc((size_t)NN * HD * 4);
    float* stats = (float*)alloc(4 * 2 * HD * 4);
    float* ppool = (float*)alloc((size_t)NGR * PP * HD * 4);
    int* gstart = (int*)alloc((NGR + 1) * 4);
    int* bsum = (int*)alloc(SCB * 4);
    int* boff = (int*)alloc((SCB + 1) * 4);

    k_init<<<(NN + 255) / 256, 256, 0, stream>>>(fill, stats);
    k_pos<<<(NE + 255) / 256, 256, 0, stream>>>(ei, fill, pos);
    k_scan1<<<SCB, SCT, 0, stream>>>(fill, bsum);
    k_scan2<<<1, SCB, 0, stream>>>(bsum, boff);
    k_scan3<<<SCB, SCT, 0, stream>>>(fill, boff, col_ptr);
    k_scatter<<<(NE + 255) / 256, 256, 0, stream>>>(ei, ea, col_ptr, pos, sw, dstv);
    k_degsum<<<(NN + 255) / 256, 256, 0, stream>>>(col_ptr, sw, dinv);
    k_wnorm<<<(NE + 255) / 256, 256, 0, stream>>>(dinv, dstv, sw);
    k_gbounds<<<1, 128, 0, stream>>>(batch, gstart);

    const int NG128 = (NN + BM - 1) / BM;
    float* st0 = stats;
    float* st1 = stats + 2 * HD;
    float* st2 = stats + 4 * HD;
    float* st3 = stats + 6 * HD;

    // L0
    k_gemm0<<<(NN + 3) / 4, 256, 0, stream>>>(x, conv0_w, mbuf);
    k_agg<<<(NN + 3) / 4, 256, 0, stream>>>(mbuf, col_ptr, sw, dinv, conv0_b, hA);
    k_bnstats<<<512, HD, 0, stream>>>(hA, st0);
    // L1
    k_gemm128<<<NG128, 256, 0, stream>>>(hA, st0, bn_gamma, bn_beta, conv_ws, mbuf);
    k_agg<<<(NN + 3) / 4, 256, 0, stream>>>(mbuf, col_ptr, sw, dinv, conv_bs, hB);
    k_bnstats<<<512, HD, 0, stream>>>(hB, st1);
    // L2
    k_gemm128<<<NG128, 256, 0, stream>>>(hB, st1, bn_gamma + HD, bn_beta + HD,
                                         conv_ws + (size_t)HD * HD, mbuf);
    k_agg<<<(NN + 3) / 4, 256, 0, stream>>>(mbuf, col_ptr, sw, dinv, conv_bs + HD, hA);
    k_bnstats<<<512, HD, 0, stream>>>(hA, st2);
    // L3
    k_gemm128<<<NG128, 256, 0, stream>>>(hA, st2, bn_gamma + 2 * HD, bn_beta + 2 * HD,
                                         conv_ws + (size_t)2 * HD * HD, mbuf);
    k_agg<<<(NN + 3) / 4, 256, 0, stream>>>(mbuf, col_ptr, sw, dinv, conv_bs + 2 * HD, hB);
    k_bnstats<<<512, HD, 0, stream>>>(hB, st3);
    // fused final BN+SiLU + pool + head
    k_poolp<<<NGR * PP, 256, 0, stream>>>(hB, st3, bn_gamma + 3 * HD, bn_beta + 3 * HD,
                                          gstart, ppool);
    k_pool_head<<<NGR, HD, 0, stream>>>(ppool, gstart, fc1w, fc1b, fc2w, fc2b, out);
}

// Round 10
// 411.840 us; speedup vs baseline: 6.8125x; 1.1650x over previous
//
#include <hip/hip_runtime.h>

#define NN 50000
#define NE 500000
#define NGR 64
#define HD 128
#define INF 5
#define BN_EPS 1e-5f
#define BM 64
#define SCB 128
#define SCT 256
#define SCH ((NN + SCB - 1) / SCB)
#define PP 16   // pooling parts per graph
#define NWW (3 * HD * 64)  // packed W words

// ---------- bf16 helpers ----------
__device__ __forceinline__ float bflo(unsigned u) { return __uint_as_float(u << 16); }
__device__ __forceinline__ float bfhi(unsigned u) { return __uint_as_float(u & 0xffff0000u); }
__device__ __forceinline__ unsigned bfpack(float a, float b) {
    unsigned ua = __float_as_uint(a), ub = __float_as_uint(b);
    ua = (ua + 0x7fffu + ((ua >> 16) & 1u)) >> 16;
    ub = (ub + 0x7fffu + ((ub >> 16) & 1u)) >> 16;
    return ua | (ub << 16);
}

// ---------- init: fill=0, stats=0, pack conv weights to bf16 ----------
__global__ void k_init(int* fill, float* stats, const float* __restrict__ conv_ws,
                       unsigned* __restrict__ wbf) {
    int i = blockIdx.x * 256 + threadIdx.x;
    if (i < NN) fill[i] = 0;
    if (i < NWW) wbf[i] = bfpack(conv_ws[2 * i], conv_ws[2 * i + 1]);
    if (i < 4 * 2 * HD) stats[i] = 0.f;
}

// ---------- pass A: per-edge bucket position (the ONLY atomic pass) ----------
__global__ void k_pos(const int* __restrict__ ei, int* __restrict__ fill,
                      int* __restrict__ pos) {
    int e = blockIdx.x * 256 + threadIdx.x;
    if (e < NE) pos[e] = atomicAdd(&fill[ei[NE + e]], 1);
}

// ---------- hierarchical scan of fill -> col_ptr ----------
__global__ void k_scan1(const int* __restrict__ cnt, int* __restrict__ bsum) {
    __shared__ int sm[SCT];
    int b = blockIdx.x, t = threadIdx.x;
    int lo = b * SCH, hi = min(lo + SCH, NN);
    int s = 0;
    for (int i = lo + t; i < hi; i += SCT) s += cnt[i];
    sm[t] = s;
    __syncthreads();
    for (int off = SCT / 2; off > 0; off >>= 1) {
        if (t < off) sm[t] += sm[t + off];
        __syncthreads();
    }
    if (t == 0) bsum[b] = sm[0];
}

// block 0: scan of block sums; block 1: graph boundaries
__global__ void k_scan2_gb(const int* __restrict__ bsum, int* __restrict__ boff,
                           const int* __restrict__ batch, int* __restrict__ gstart) {
    int t = threadIdx.x;  // 128
    if (blockIdx.x == 1) {
        int g = t;
        if (g > NGR) return;
        int lo = 0, hi = NN;
        while (lo < hi) {
            int mid = (lo + hi) >> 1;
            if (batch[mid] < g) lo = mid + 1;
            else hi = mid;
        }
        gstart[g] = lo;
        return;
    }
    __shared__ int sm[SCB];
    sm[t] = bsum[t];
    __syncthreads();
    for (int off = 1; off < SCB; off <<= 1) {
        int v = (t >= off) ? sm[t - off] : 0;
        __syncthreads();
        sm[t] += v;
        __syncthreads();
    }
    boff[t] = (t == 0) ? 0 : sm[t - 1];
    if (t == SCB - 1) boff[SCB] = sm[SCB - 1];
}

__global__ void k_scan3(const int* __restrict__ cnt, const int* __restrict__ boff,
                        int* __restrict__ col_ptr) {
    __shared__ int sm[SCT];
    int b = blockIdx.x, t = threadIdx.x;
    int lo = b * SCH, hi = min(lo + SCH, NN);
    int e0 = lo + 2 * t, e1 = e0 + 1;
    int c0 = (e0 < hi) ? cnt[e0] : 0;
    int c1 = (e1 < hi) ? cnt[e1] : 0;
    sm[t] = c0 + c1;
    __syncthreads();
    for (int off = 1; off < SCT; off <<= 1) {
        int v = (t >= off) ? sm[t - off] : 0;
        __syncthreads();
        sm[t] += v;
        __syncthreads();
    }
    int base = boff[b] + ((t == 0) ? 0 : sm[t - 1]);
    if (e0 < hi) col_ptr[e0] = base;
    if (e1 < hi) col_ptr[e1] = base + c0;
    if (b == SCB - 1 && t == SCT - 1) col_ptr[NN] = boff[SCB];
}

// ---------- pass B: scatter {src, ea} as int2, no atomics ----------
__global__ void k_scatter(const int* __restrict__ ei, const float* __restrict__ ea,
                          const int* __restrict__ col_ptr, const int* __restrict__ pos,
                          int2* __restrict__ sw) {
    int e = blockIdx.x * 256 + threadIdx.x;
    if (e >= NE) return;
    int c = ei[NE + e];
    int p = col_ptr[c] + pos[e];
    sw[p] = make_int2(ei[e], __float_as_int(ea[e]));
}

// ---------- weighted degree via segment sum -> dinv (no atomics) ----------
__global__ void k_degsum(const int* __restrict__ col_ptr, const int2* __restrict__ sw,
                         float* __restrict__ dinv) {
    int i = blockIdx.x * 256 + threadIdx.x;
    if (i >= NN) return;
    int beg = col_ptr[i], end = col_ptr[i + 1];
    float s = 1.0f;  // self-loop weight
    for (int p = beg; p < end; p++) s += __int_as_float(sw[p].y);
    dinv[i] = rsqrtf(s);
}

// ---------- node-parallel weight normalization ----------
__global__ void k_wnorm(const int* __restrict__ col_ptr, const float* __restrict__ dinv,
                        int2* __restrict__ sw) {
    int i = blockIdx.x * 256 + threadIdx.x;
    if (i >= NN) return;
    int beg = col_ptr[i], end = col_ptr[i + 1];
    float di = dinv[i];
    for (int p = beg; p < end; p++) {
        int2 v = sw[p];
        sw[p] = make_int2(v.x, __float_as_int(dinv[v.x] * __int_as_float(v.y) * di));
    }
}

// ---------- layer-0 transform: m = x @ W0 (K=5), bf16 output ----------
__global__ void k_gemm0(const float* __restrict__ x, const float* __restrict__ W,
                        unsigned* __restrict__ m32) {
    __shared__ float Ws[INF][HD];
    int t = threadIdx.x;  // 256
    for (int i = t; i < INF * HD; i += 256) ((float*)Ws)[i] = W[i];
    __syncthreads();
    int row = blockIdx.x * 4 + (t >> 6);
    if (row >= NN) return;
    int lane = t & 63;
    int c0 = 2 * lane;
    float xv[INF];
#pragma unroll
    for (int k = 0; k < INF; k++) xv[k] = x[row * INF + k];
    float a0 = 0.f, a1 = 0.f;
#pragma unroll
    for (int k = 0; k < INF; k++) {
        a0 += xv[k] * Ws[k][c0];
        a1 += xv[k] * Ws[k][c0 + 1];
    }
    m32[(size_t)row * 64 + lane] = bfpack(a0, a1);
}

// ---------- fused BN(prev)+SiLU + GEMM: m = silu(bn(h32)) @ Wb, bf16 in/out ----------
__global__ __launch_bounds__(256, 4) void k_gemm128(
    const unsigned* __restrict__ h32, const float* __restrict__ stats,
    const float* __restrict__ gamma, const float* __restrict__ beta,
    const unsigned* __restrict__ Wb, unsigned* __restrict__ m32) {
    __shared__ float hs[BM][HD];   // 32 KB
    __shared__ float sc[HD], sh[HD];
    int t = threadIdx.x;
    int r0 = blockIdx.x * BM;
    const float invn = 1.0f / NN;

    if (t < HD) {
        float mu = stats[t] * invn;
        float var = stats[HD + t] * invn - mu * mu;
        float s = gamma[t] * rsqrtf(var + BN_EPS);
        sc[t] = s;
        sh[t] = beta[t] - mu * s;
    }
    __syncthreads();

    // stage h tile: bf16 -> BN+SiLU -> f32 LDS (4 uint4 = 32 channels worth /thread)
#pragma unroll
    for (int j = 0; j < 4; j++) {
        int idx = j * 256 + t;        // uint4 index in tile (16 per row)
        int r = idx >> 4;
        int w8 = idx & 15;
        uint4 v = make_uint4(0u, 0u, 0u, 0u);
        if (r0 + r < NN) v = ((const uint4*)h32)[(size_t)(r0 + r) * 16 + w8];
        int c = w8 * 8;
        float vals[8] = {bflo(v.x), bfhi(v.x), bflo(v.y), bfhi(v.y),
                         bflo(v.z), bfhi(v.z), bflo(v.w), bfhi(v.w)};
#pragma unroll
        for (int q = 0; q < 8; q++) {
            float y = sc[c + q] * vals[q] + sh[c + q];
            hs[r][c + q] = y / (1.f + __expf(-y));
        }
    }
    __syncthreads();

    int rg = t >> 5, cg = t & 31;
    int rr = rg * 8;
    int cc = cg * 4;
    float acc[8][4];
#pragma unroll
    for (int i = 0; i < 8; i++)
#pragma unroll
        for (int j = 0; j < 4; j++) acc[i][j] = 0.f;

    const uint2* Wp = (const uint2*)Wb;  // [HD][32] uint2: k*32+cg = channels 4cg..4cg+3
#pragma unroll 2
    for (int k4 = 0; k4 < HD / 4; k4++) {
        uint2 u0 = Wp[(k4 * 4 + 0) * 32 + cg];
        uint2 u1 = Wp[(k4 * 4 + 1) * 32 + cg];
        uint2 u2 = Wp[(k4 * 4 + 2) * 32 + cg];
        uint2 u3 = Wp[(k4 * 4 + 3) * 32 + cg];
        float4 wv0 = make_float4(bflo(u0.x), bfhi(u0.x), bflo(u0.y), bfhi(u0.y));
        float4 wv1 = make_float4(bflo(u1.x), bfhi(u1.x), bflo(u1.y), bfhi(u1.y));
        float4 wv2 = make_float4(bflo(u2.x), bfhi(u2.x), bflo(u2.y), bfhi(u2.y));
        float4 wv3 = make_float4(bflo(u3.x), bfhi(u3.x), bflo(u3.y), bfhi(u3.y));
#pragma unroll
        for (int i = 0; i < 8; i++) {
            float4 hv = *(const float4*)&hs[rr + i][k4 * 4];
            acc[i][0] += hv.x * wv0.x + hv.y * wv1.x + hv.z * wv2.x + hv.w * wv3.x;
            acc[i][1] += hv.x * wv0.y + hv.y * wv1.y + hv.z * wv2.y + hv.w * wv3.y;
            acc[i][2] += hv.x * wv0.z + hv.y * wv1.z + hv.z * wv2.z + hv.w * wv3.z;
            acc[i][3] += hv.x * wv0.w + hv.y * wv1.w + hv.z * wv2.w + hv.w * wv3.w;
        }
    }

#pragma unroll
    for (int i = 0; i < 8; i++) {
        int r = r0 + rr + i;
        if (r < NN) {
            uint2 pk = make_uint2(bfpack(acc[i][0], acc[i][1]), bfpack(acc[i][2], acc[i][3]));
            ((uint2*)m32)[(size_t)r * 32 + cg] = pk;
        }
    }
}

// ---------- sparse aggregation: bf16 gathers, f32 accumulate, bf16 out ----------
__global__ void k_agg(const unsigned* __restrict__ m32, const int* __restrict__ col_ptr,
                      const int2* __restrict__ sw, const float* __restrict__ dinv,
                      const float* __restrict__ bias, unsigned* __restrict__ hpre32) {
    int node = blockIdx.x * 4 + (threadIdx.x >> 6);
    if (node >= NN) return;
    int lane = threadIdx.x & 63;
    float di = dinv[node];
    unsigned sv = m32[(size_t)node * 64 + lane];
    float a0 = di * di * bflo(sv);
    float a1 = di * di * bfhi(sv);
    int beg = col_ptr[node], end = col_ptr[node + 1];
    int p = beg;
    for (; p + 8 <= end; p += 8) {
        int2 e0 = sw[p], e1 = sw[p + 1], e2 = sw[p + 2], e3 = sw[p + 3];
        int2 e4 = sw[p + 4], e5 = sw[p + 5], e6 = sw[p + 6], e7 = sw[p + 7];
        unsigned v0 = m32[(size_t)e0.x * 64 + lane];
        unsigned v1 = m32[(size_t)e1.x * 64 + lane];
        unsigned v2 = m32[(size_t)e2.x * 64 + lane];
        unsigned v3 = m32[(size_t)e3.x * 64 + lane];
        unsigned v4 = m32[(size_t)e4.x * 64 + lane];
        unsigned v5 = m32[(size_t)e5.x * 64 + lane];
        unsigned v6 = m32[(size_t)e6.x * 64 + lane];
        unsigned v7 = m32[(size_t)e7.x * 64 + lane];
        float w0 = __int_as_float(e0.y), w1 = __int_as_float(e1.y);
        float w2 = __int_as_float(e2.y), w3 = __int_as_float(e3.y);
        float w4 = __int_as_float(e4.y), w5 = __int_as_float(e5.y);
        float w6 = __int_as_float(e6.y), w7 = __int_as_float(e7.y);
        a0 += w0 * bflo(v0) + w1 * bflo(v1) + w2 * bflo(v2) + w3 * bflo(v3);
        a1 += w0 * bfhi(v0) + w1 * bfhi(v1) + w2 * bfhi(v2) + w3 * bfhi(v3);
        a0 += w4 * bflo(v4) + w5 * bflo(v5) + w6 * bflo(v6) + w7 * bflo(v7);
        a1 += w4 * bfhi(v4) + w5 * bfhi(v5) + w6 * bfhi(v6) + w7 * bfhi(v7);
    }
    for (; p < end; p++) {
        int2 e = sw[p];
        unsigned v = m32[(size_t)e.x * 64 + lane];
        float w = __int_as_float(e.y);
        a0 += w * bflo(v);
        a1 += w * bfhi(v);
    }
    float2 b = ((const float2*)bias)[lane];
    hpre32[(size_t)node * 64 + lane] = bfpack(a0 + b.x, a1 + b.y);
}

// ---------- batchnorm stats from bf16 hpre: 256 blocks x 4 waves, LDS combine ----------
__global__ void k_bnstats(const unsigned* __restrict__ h32, float* __restrict__ stats) {
    __shared__ float lss[4][HD];
    __shared__ float lsq[4][HD];
    int t = threadIdx.x;  // 256
    int w = t >> 6, l = t & 63;
    float s0 = 0.f, s1 = 0.f, q0 = 0.f, q1 = 0.f;
    for (int r = blockIdx.x * 4 + w; r < NN; r += 1024) {
        unsigned v = h32[(size_t)r * 64 + l];
        float a = bflo(v), b = bfhi(v);
        s0 += a; q0 += a * a;
        s1 += b; q1 += b * b;
    }
    lss[w][2 * l] = s0;
    lss[w][2 * l + 1] = s1;
    lsq[w][2 * l] = q0;
    lsq[w][2 * l + 1] = q1;
    __syncthreads();
    if (t < HD) {
        float s = lss[0][t] + lss[1][t] + lss[2][t] + lss[3][t];
        atomicAdd(&stats[t], s);
    } else {
        int c = t - HD;
        float q = lsq[0][c] + lsq[1][c] + lsq[2][c] + lsq[3][c];
        atomicAdd(&stats[HD + c], q);
    }
}

// ---------- pooling stage 1 (fused final BN+SiLU), bf16 input ----------
__global__ void k_poolp(const unsigned* __restrict__ h32, const float* __restrict__ stats,
                        const float* __restrict__ gamma, const float* __restrict__ beta,
                        const int* __restrict__ gstart, float* __restrict__ ppool) {
    int g = blockIdx.x / PP, p = blockIdx.x % PP;
    int t = threadIdx.x;          // 256
    int c4 = t & 31;              // 4-channel group
    int ro = t >> 5;
    const float invn = 1.0f / NN;
    float sc[4], sh[4];
#pragma unroll
    for (int q = 0; q < 4; q++) {
        int c = c4 * 4 + q;
        float mu = stats[c] * invn;
        float var = stats[HD + c] * invn - mu * mu;
        float s = gamma[c] * rsqrtf(var + BN_EPS);
        sc[q] = s;
        sh[q] = beta[c] - mu * s;
    }
    int beg = gstart[g], end = gstart[g + 1];
    const uint2* h2 = (const uint2*)h32;
    float4 acc = make_float4(0.f, 0.f, 0.f, 0.f);
    for (int r = beg + p * 8 + ro; r < end; r += PP * 8) {
        uint2 u = h2[(size_t)r * 32 + c4];
        float vals[4] = {bflo(u.x), bfhi(u.x), bflo(u.y), bfhi(u.y)};
#pragma unroll
        for (int q = 0; q < 4; q++) {
            float y = sc[q] * vals[q] + sh[q];
            (&acc.x)[q] += y / (1.f + __expf(-y));
        }
    }
    __shared__ float4 sm[256];
    sm[t] = acc;
    __syncthreads();
    if (t < 128) {
        float4 o = sm[t + 128];
        sm[t].x += o.x; sm[t].y += o.y; sm[t].z += o.z; sm[t].w += o.w;
    }
    __syncthreads();
    if (t < 64) {
        float4 o = sm[t + 64];
        sm[t].x += o.x; sm[t].y += o.y; sm[t].z += o.z; sm[t].w += o.w;
    }
    __syncthreads();
    if (t < 32) {
        float4 o = sm[t + 32];
        float4 r = sm[t];
        r.x += o.x; r.y += o.y; r.z += o.z; r.w += o.w;
        ((float4*)ppool)[(size_t)blockIdx.x * 32 + t] = r;
    }
}

// ---------- pooling stage 2 + head MLP fused ----------
__global__ void k_pool_head(const float* __restrict__ ppool, const int* __restrict__ gstart,
                            const float* __restrict__ fc1w, const float* __restrict__ fc1b,
                            const float* __restrict__ fc2w, const float* __restrict__ fc2b,
                            float* __restrict__ out) {
    int g = blockIdx.x;
    int t = threadIdx.x;  // 128
    __shared__ float pa[HD];
    float s = 0.f;
    for (int p = 0; p < PP; p++) s += ppool[(size_t)(g * PP + p) * HD + t];
    float cnt = (float)(gstart[g + 1] - gstart[g]);
    pa[t] = s / fmaxf(cnt, 1.0f);
    __syncthreads();
    if (t < 64) {
        float a = fc1b[t];
        for (int k = 0; k < HD; k++) a += pa[k] * fc1w[k * 64 + t];
        a = a / (1.f + __expf(-a));  // SiLU
        float v = a * fc2w[t];
        for (int off = 32; off > 0; off >>= 1) v += __shfl_down(v, off);
        if (t == 0) out[g] = 1.f / (1.f + __expf(-(v + fc2b[0])));
    }
}

extern "C" void kernel_launch(void* const* d_in, const int* in_sizes, int n_in,
                              void* d_out, int out_size, void* d_ws, size_t ws_size,
                              hipStream_t stream) {
    const float* x = (const float*)d_in[0];
    const int* ei = (const int*)d_in[1];  // [2, E]: row=ei[0..E), col=ei[E..2E)
    const float* ea = (const float*)d_in[2];
    const int* batch = (const int*)d_in[3];
    const float* conv0_w = (const float*)d_in[5];
    const float* conv0_b = (const float*)d_in[6];
    const float* conv_ws = (const float*)d_in[7];
    const float* conv_bs = (const float*)d_in[8];
    const float* bn_gamma = (const float*)d_in[9];
    const float* bn_beta = (const float*)d_in[10];
    const float* fc1w = (const float*)d_in[11];
    const float* fc1b = (const float*)d_in[12];
    const float* fc2w = (const float*)d_in[13];
    const float* fc2b = (const float*)d_in[14];
    float* out = (float*)d_out;

    char* ws = (char*)d_ws;
    size_t off = 0;
    auto alloc = [&](size_t bytes) -> char* {
        char* p = ws + off;
        off = (off + bytes + 255) & ~(size_t)255;
        return p;
    };
    float* dinv = (float*)alloc(NN * 4);
    int* fill = (int*)alloc(NN * 4);
    int* col_ptr = (int*)alloc((NN + 1) * 4);
    int* pos = (int*)alloc(NE * 4);
    int2* sw = (int2*)alloc((size_t)NE * 8);
    unsigned* mbuf = (unsigned*)alloc((size_t)NN * HD * 2);
    unsigned* hA = (unsigned*)alloc((size_t)NN * HD * 2);
    unsigned* hB = (unsigned*)alloc((size_t)NN * HD * 2);
    unsigned* wbf = (unsigned*)alloc((size_t)NWW * 4);
    float* stats = (float*)alloc(4 * 2 * HD * 4);
    float* ppool = (float*)alloc((size_t)NGR * PP * HD * 4);
    int* gstart = (int*)alloc((NGR + 1) * 4);
    int* bsum = (int*)alloc(SCB * 4);
    int* boff = (int*)alloc((SCB + 1) * 4);

    k_init<<<(NN + 255) / 256, 256, 0, stream>>>(fill, stats, conv_ws, wbf);
    k_pos<<<(NE + 255) / 256, 256, 0, stream>>>(ei, fill, pos);
    k_scan1<<<SCB, SCT, 0, stream>>>(fill, bsum);
    k_scan2_gb<<<2, SCB, 0, stream>>>(bsum, boff, batch, gstart);
    k_scan3<<<SCB, SCT, 0, stream>>>(fill, boff, col_ptr);
    k_scatter<<<(NE + 255) / 256, 256, 0, stream>>>(ei, ea, col_ptr, pos, sw);
    k_degsum<<<(NN + 255) / 256, 256, 0, stream>>>(col_ptr, sw, dinv);
    k_wnorm<<<(NN + 255) / 256, 256, 0, stream>>>(col_ptr, dinv, sw);

    float* st0 = stats;
    float* st1 = stats + 2 * HD;
    float* st2 = stats + 4 * HD;
    float* st3 = stats + 6 * HD;
    const int NG128 = (NN + BM - 1) / BM;

    // L0
    k_gemm0<<<(NN + 3) / 4, 256, 0, stream>>>(x, conv0_w, mbuf);
    k_agg<<<(NN + 3) / 4, 256, 0, stream>>>(mbuf, col_ptr, sw, dinv, conv0_b, hA);
    k_bnstats<<<256, 256, 0, stream>>>(hA, st0);
    // L1
    k_gemm128<<<NG128, 256, 0, stream>>>(hA, st0, bn_gamma, bn_beta, wbf, mbuf);
    k_agg<<<(NN + 3) / 4, 256, 0, stream>>>(mbuf, col_ptr, sw, dinv, conv_bs, hB);
    k_bnstats<<<256, 256, 0, stream>>>(hB, st1);
    // L2
    k_gemm128<<<NG128, 256, 0, stream>>>(hB, st1, bn_gamma + HD, bn_beta + HD,
                                         wbf + (size_t)HD * 64, mbuf);
    k_agg<<<(NN + 3) / 4, 256, 0, stream>>>(mbuf, col_ptr, sw, dinv, conv_bs + HD, hA);
    k_bnstats<<<256, 256, 0, stream>>>(hA, st2);
    // L3
    k_gemm128<<<NG128, 256, 0, stream>>>(hA, st2, bn_gamma + 2 * HD, bn_beta + 2 * HD,
                                         wbf + (size_t)2 * HD * 64, mbuf);
    k_agg<<<(NN + 3) / 4, 256, 0, stream>>>(mbuf, col_ptr, sw, dinv, conv_bs + 2 * HD, hB);
    k_bnstats<<<256, 256, 0, stream>>>(hB, st3);
    // fused final BN+SiLU + pool + head
    k_poolp<<<NGR * PP, 256, 0, stream>>>(hB, st3, bn_gamma + 3 * HD, bn_beta + 3 * HD,
                                          gstart, ppool);
    k_pool_head<<<NGR, HD, 0, stream>>>(ppool, gstart, fc1w, fc1b, fc2w, fc2b, out);
}

// Round 11
// 341.456 us; speedup vs baseline: 8.2168x; 1.2061x over previous
//
#include <hip/hip_runtime.h>

#define NN 50000
#define NE 500000
#define NGR 64
#define HD 128
#define INF 5
#define BN_EPS 1e-5f
#define BM 64
#define SCB 128
#define SCT 256
#define SCH ((NN + SCB - 1) / SCB)
#define PP 16             // pooling parts per graph
#define NWFU (3 * 8 * 4 * 64 * 4)  // wfrag uints: L*t*s*lane*4

typedef __attribute__((ext_vector_type(8))) short short8v;
typedef __attribute__((ext_vector_type(4))) float f32x4;

// ---------- bf16 helpers ----------
__device__ __forceinline__ float bflo(unsigned u) { return __uint_as_float(u << 16); }
__device__ __forceinline__ float bfhi(unsigned u) { return __uint_as_float(u & 0xffff0000u); }
__device__ __forceinline__ unsigned bfpack(float a, float b) {
    unsigned ua = __float_as_uint(a), ub = __float_as_uint(b);
    ua = (ua + 0x7fffu + ((ua >> 16) & 1u)) >> 16;
    ub = (ub + 0x7fffu + ((ub >> 16) & 1u)) >> 16;
    return ua | (ub << 16);
}
__device__ __forceinline__ unsigned short bf1(float a) {
    unsigned ua = __float_as_uint(a);
    return (unsigned short)((ua + 0x7fffu + ((ua >> 16) & 1u)) >> 16);
}

// ---------- init: fill=0, stats=0, pack conv weights into MFMA B-fragment order ----------
// wfrag uint4 index: ((L*8 + t)*4 + s)*64 + lane ; holds B[k..k+7][col] bf16,
// col = t*16 + (lane&15), k = s*32 + (lane>>4)*8 (+j).
__global__ void k_init(int* fill, float* stats, const float* __restrict__ conv_ws,
                       unsigned* __restrict__ wbf) {
    int i = blockIdx.x * 256 + threadIdx.x;
    if (i < NN) fill[i] = 0;
    if (i < 4 * 2 * HD) stats[i] = 0.f;
    if (i < NWFU) {
        int inner = i & 3;
        int u4 = i >> 2;
        int lane = u4 & 63;
        int rest = u4 >> 6;
        int s = rest & 3, tt = (rest >> 2) & 7, L = rest >> 5;
        int col = tt * 16 + (lane & 15);
        int k = s * 32 + (lane >> 4) * 8 + inner * 2;
        const float* Wl = conv_ws + (size_t)L * HD * HD;
        wbf[i] = bfpack(Wl[k * HD + col], Wl[(k + 1) * HD + col]);
    }
}

// ---------- pass A: per-edge bucket position (the ONLY atomic pass) ----------
__global__ void k_pos(const int* __restrict__ ei, int* __restrict__ fill,
                      int* __restrict__ pos) {
    int e = blockIdx.x * 256 + threadIdx.x;
    if (e < NE) pos[e] = atomicAdd(&fill[ei[NE + e]], 1);
}

// ---------- hierarchical scan of fill -> col_ptr ----------
__global__ void k_scan1(const int* __restrict__ cnt, int* __restrict__ bsum) {
    __shared__ int sm[SCT];
    int b = blockIdx.x, t = threadIdx.x;
    int lo = b * SCH, hi = min(lo + SCH, NN);
    int s = 0;
    for (int i = lo + t; i < hi; i += SCT) s += cnt[i];
    sm[t] = s;
    __syncthreads();
    for (int off = SCT / 2; off > 0; off >>= 1) {
        if (t < off) sm[t] += sm[t + off];
        __syncthreads();
    }
    if (t == 0) bsum[b] = sm[0];
}

// block 0: scan of block sums; block 1: graph boundaries
__global__ void k_scan2_gb(const int* __restrict__ bsum, int* __restrict__ boff,
                           const int* __restrict__ batch, int* __restrict__ gstart) {
    int t = threadIdx.x;  // 128
    if (blockIdx.x == 1) {
        int g = t;
        if (g > NGR) return;
        int lo = 0, hi = NN;
        while (lo < hi) {
            int mid = (lo + hi) >> 1;
            if (batch[mid] < g) lo = mid + 1;
            else hi = mid;
        }
        gstart[g] = lo;
        return;
    }
    __shared__ int sm[SCB];
    sm[t] = bsum[t];
    __syncthreads();
    for (int off = 1; off < SCB; off <<= 1) {
        int v = (t >= off) ? sm[t - off] : 0;
        __syncthreads();
        sm[t] += v;
        __syncthreads();
    }
    boff[t] = (t == 0) ? 0 : sm[t - 1];
    if (t == SCB - 1) boff[SCB] = sm[SCB - 1];
}

__global__ void k_scan3(const int* __restrict__ cnt, const int* __restrict__ boff,
                        int* __restrict__ col_ptr) {
    __shared__ int sm[SCT];
    int b = blockIdx.x, t = threadIdx.x;
    int lo = b * SCH, hi = min(lo + SCH, NN);
    int e0 = lo + 2 * t, e1 = e0 + 1;
    int c0 = (e0 < hi) ? cnt[e0] : 0;
    int c1 = (e1 < hi) ? cnt[e1] : 0;
    sm[t] = c0 + c1;
    __syncthreads();
    for (int off = 1; off < SCT; off <<= 1) {
        int v = (t >= off) ? sm[t - off] : 0;
        __syncthreads();
        sm[t] += v;
        __syncthreads();
    }
    int base = boff[b] + ((t == 0) ? 0 : sm[t - 1]);
    if (e0 < hi) col_ptr[e0] = base;
    if (e1 < hi) col_ptr[e1] = base + c0;
    if (b == SCB - 1 && t == SCT - 1) col_ptr[NN] = boff[SCB];
}

// ---------- pass B: scatter {src, ea} as int2, no atomics ----------
__global__ void k_scatter(const int* __restrict__ ei, const float* __restrict__ ea,
                          const int* __restrict__ col_ptr, const int* __restrict__ pos,
                          int2* __restrict__ sw) {
    int e = blockIdx.x * 256 + threadIdx.x;
    if (e >= NE) return;
    int c = ei[NE + e];
    int p = col_ptr[c] + pos[e];
    sw[p] = make_int2(ei[e], __float_as_int(ea[e]));
}

// ---------- weighted degree via segment sum -> dinv (no atomics) ----------
__global__ void k_degsum(const int* __restrict__ col_ptr, const int2* __restrict__ sw,
                         float* __restrict__ dinv) {
    int i = blockIdx.x * 256 + threadIdx.x;
    if (i >= NN) return;
    int beg = col_ptr[i], end = col_ptr[i + 1];
    float s = 1.0f;  // self-loop weight
    for (int p = beg; p < end; p++) s += __int_as_float(sw[p].y);
    dinv[i] = rsqrtf(s);
}

// ---------- node-parallel weight normalization ----------
__global__ void k_wnorm(const int* __restrict__ col_ptr, const float* __restrict__ dinv,
                        int2* __restrict__ sw) {
    int i = blockIdx.x * 256 + threadIdx.x;
    if (i >= NN) return;
    int beg = col_ptr[i], end = col_ptr[i + 1];
    float di = dinv[i];
    for (int p = beg; p < end; p++) {
        int2 v = sw[p];
        sw[p] = make_int2(v.x, __float_as_int(dinv[v.x] * __int_as_float(v.y) * di));
    }
}

// ---------- layer-0 transform: m = x @ W0 (K=5), bf16 output ----------
__global__ void k_gemm0(const float* __restrict__ x, const float* __restrict__ W,
                        unsigned* __restrict__ m32) {
    __shared__ float Ws[INF][HD];
    int t = threadIdx.x;  // 256
    for (int i = t; i < INF * HD; i += 256) ((float*)Ws)[i] = W[i];
    __syncthreads();
    int row = blockIdx.x * 4 + (t >> 6);
    if (row >= NN) return;
    int lane = t & 63;
    int c0 = 2 * lane;
    float xv[INF];
#pragma unroll
    for (int k = 0; k < INF; k++) xv[k] = x[row * INF + k];
    float a0 = 0.f, a1 = 0.f;
#pragma unroll
    for (int k = 0; k < INF; k++) {
        a0 += xv[k] * Ws[k][c0];
        a1 += xv[k] * Ws[k][c0 + 1];
    }
    m32[(size_t)row * 64 + lane] = bfpack(a0, a1);
}

// ---------- fused BN(prev)+SiLU + MFMA GEMM: m = silu(bn(h32)) @ W, bf16 ----------
// 4 waves; wave w computes rows [r0+16w, r0+16w+16) x 128 cols via 16x16x32 MFMA.
// A staged in LDS as packed bf16, uint4-slot XOR-swizzled: slot' = slot ^ (row&7).
__global__ __launch_bounds__(256) void k_gemm128(
    const unsigned* __restrict__ h32, const float* __restrict__ stats,
    const float* __restrict__ gamma, const float* __restrict__ beta,
    const uint4* __restrict__ wfrag, unsigned short* __restrict__ m16) {
    __shared__ __align__(16) unsigned hs[64 * 64];  // 16 KB packed bf16
    __shared__ float sc[HD], sh[HD];
    int t = threadIdx.x;
    int r0 = blockIdx.x * BM;
    const float invn = 1.0f / NN;

    if (t < HD) {
        float mu = stats[t] * invn;
        float var = stats[HD + t] * invn - mu * mu;
        float s = gamma[t] * rsqrtf(var + BN_EPS);
        sc[t] = s;
        sh[t] = beta[t] - mu * s;
    }
    __syncthreads();

    // stage: bf16 -> BN+SiLU -> packed bf16 LDS (uint2 per thread-iter, conflict-free)
#pragma unroll
    for (int j = 0; j < 8; j++) {
        int g = j * 256 + t;      // uint2 slot 0..2047
        int r = g >> 5;           // row 0..63
        int u2 = g & 31;          // uint2 within row
        uint2 v = make_uint2(0u, 0u);
        if (r0 + r < NN) v = ((const uint2*)h32)[(size_t)(r0 + r) * 32 + u2];
        int c = u2 * 4;
        float y0 = sc[c] * bflo(v.x) + sh[c];
        float y1 = sc[c + 1] * bfhi(v.x) + sh[c + 1];
        float y2 = sc[c + 2] * bflo(v.y) + sh[c + 2];
        float y3 = sc[c + 3] * bfhi(v.y) + sh[c + 3];
        y0 = y0 / (1.f + __expf(-y0));
        y1 = y1 / (1.f + __expf(-y1));
        y2 = y2 / (1.f + __expf(-y2));
        y3 = y3 / (1.f + __expf(-y3));
        int slot = u2 >> 1, inner = (u2 & 1) * 2;
        int addr = r * 64 + ((slot ^ (r & 7)) << 2) + inner;
        hs[addr] = bfpack(y0, y1);
        hs[addr + 1] = bfpack(y2, y3);
    }
    __syncthreads();

    int w = t >> 6, l = t & 63;
    int lr = l & 15, lg = l >> 4;
    f32x4 acc[8];
#pragma unroll
    for (int i = 0; i < 8; i++) acc[i] = (f32x4){0.f, 0.f, 0.f, 0.f};

#pragma unroll
    for (int s = 0; s < 4; s++) {  // K steps of 32
        int arow = w * 16 + lr;
        int q = s * 4 + lg;        // uint4 slot of this lane's 8 bf16 A elems
        short8v af = *reinterpret_cast<const short8v*>(
            &hs[arow * 64 + ((q ^ (arow & 7)) << 2)]);
#pragma unroll
        for (int tt = 0; tt < 8; tt++) {  // N tiles of 16
            short8v bf = *reinterpret_cast<const short8v*>(&wfrag[(tt * 4 + s) * 64 + l]);
            acc[tt] = __builtin_amdgcn_mfma_f32_16x16x32_bf16(af, bf, acc[tt], 0, 0, 0);
        }
    }

    // C write: col = tt*16 + (l&15), row = w*16 + (l>>4)*4 + reg  [m89-verified]
    int baserow = r0 + w * 16 + lg * 4;
#pragma unroll
    for (int tt = 0; tt < 8; tt++) {
        int col = tt * 16 + lr;
#pragma unroll
        for (int reg = 0; reg < 4; reg++) {
            int row = baserow + reg;
            if (row < NN) m16[(size_t)row * HD + col] = bf1(acc[tt][reg]);
        }
    }
}

// ---------- sparse aggregation: bf16 gathers, f32 accumulate, bf16 out ----------
__global__ void k_agg(const unsigned* __restrict__ m32, const int* __restrict__ col_ptr,
                      const int2* __restrict__ sw, const float* __restrict__ dinv,
                      const float* __restrict__ bias, unsigned* __restrict__ hpre32) {
    int node = blockIdx.x * 4 + (threadIdx.x >> 6);
    if (node >= NN) return;
    int lane = threadIdx.x & 63;
    float di = dinv[node];
    unsigned sv = m32[(size_t)node * 64 + lane];
    float a0 = di * di * bflo(sv);
    float a1 = di * di * bfhi(sv);
    int beg = col_ptr[node], end = col_ptr[node + 1];
    int p = beg;
    for (; p + 8 <= end; p += 8) {
        int2 e0 = sw[p], e1 = sw[p + 1], e2 = sw[p + 2], e3 = sw[p + 3];
        int2 e4 = sw[p + 4], e5 = sw[p + 5], e6 = sw[p + 6], e7 = sw[p + 7];
        unsigned v0 = m32[(size_t)e0.x * 64 + lane];
        unsigned v1 = m32[(size_t)e1.x * 64 + lane];
        unsigned v2 = m32[(size_t)e2.x * 64 + lane];
        unsigned v3 = m32[(size_t)e3.x * 64 + lane];
        unsigned v4 = m32[(size_t)e4.x * 64 + lane];
        unsigned v5 = m32[(size_t)e5.x * 64 + lane];
        unsigned v6 = m32[(size_t)e6.x * 64 + lane];
        unsigned v7 = m32[(size_t)e7.x * 64 + lane];
        float w0 = __int_as_float(e0.y), w1 = __int_as_float(e1.y);
        float w2 = __int_as_float(e2.y), w3 = __int_as_float(e3.y);
        float w4 = __int_as_float(e4.y), w5 = __int_as_float(e5.y);
        float w6 = __int_as_float(e6.y), w7 = __int_as_float(e7.y);
        a0 += w0 * bflo(v0) + w1 * bflo(v1) + w2 * bflo(v2) + w3 * bflo(v3);
        a1 += w0 * bfhi(v0) + w1 * bfhi(v1) + w2 * bfhi(v2) + w3 * bfhi(v3);
        a0 += w4 * bflo(v4) + w5 * bflo(v5) + w6 * bflo(v6) + w7 * bflo(v7);
        a1 += w4 * bfhi(v4) + w5 * bfhi(v5) + w6 * bfhi(v6) + w7 * bfhi(v7);
    }
    for (; p < end; p++) {
        int2 e = sw[p];
        unsigned v = m32[(size_t)e.x * 64 + lane];
        float w = __int_as_float(e.y);
        a0 += w * bflo(v);
        a1 += w * bfhi(v);
    }
    float2 b = ((const float2*)bias)[lane];
    hpre32[(size_t)node * 64 + lane] = bfpack(a0 + b.x, a1 + b.y);
}

// ---------- batchnorm stats from bf16 hpre: 256 blocks x 4 waves, LDS combine ----------
__global__ void k_bnstats(const unsigned* __restrict__ h32, float* __restrict__ stats) {
    __shared__ float lss[4][HD];
    __shared__ float lsq[4][HD];
    int t = threadIdx.x;  // 256
    int w = t >> 6, l = t & 63;
    float s0 = 0.f, s1 = 0.f, q0 = 0.f, q1 = 0.f;
    for (int r = blockIdx.x * 4 + w; r < NN; r += 1024) {
        unsigned v = h32[(size_t)r * 64 + l];
        float a = bflo(v), b = bfhi(v);
        s0 += a; q0 += a * a;
        s1 += b; q1 += b * b;
    }
    lss[w][2 * l] = s0;
    lss[w][2 * l + 1] = s1;
    lsq[w][2 * l] = q0;
    lsq[w][2 * l + 1] = q1;
    __syncthreads();
    if (t < HD) {
        float s = lss[0][t] + lss[1][t] + lss[2][t] + lss[3][t];
        atomicAdd(&stats[t], s);
    } else {
        int c = t - HD;
        float q = lsq[0][c] + lsq[1][c] + lsq[2][c] + lsq[3][c];
        atomicAdd(&stats[HD + c], q);
    }
}

// ---------- pooling stage 1 (fused final BN+SiLU), bf16 input ----------
__global__ void k_poolp(const unsigned* __restrict__ h32, const float* __restrict__ stats,
                        const float* __restrict__ gamma, const float* __restrict__ beta,
                        const int* __restrict__ gstart, float* __restrict__ ppool) {
    int g = blockIdx.x / PP, p = blockIdx.x % PP;
    int t = threadIdx.x;          // 256
    int c4 = t & 31;              // 4-channel group
    int ro = t >> 5;
    const float invn = 1.0f / NN;
    float sc[4], sh[4];
#pragma unroll
    for (int q = 0; q < 4; q++) {
        int c = c4 * 4 + q;
        float mu = stats[c] * invn;
        float var = stats[HD + c] * invn - mu * mu;
        float s = gamma[c] * rsqrtf(var + BN_EPS);
        sc[q] = s;
        sh[q] = beta[c] - mu * s;
    }
    int beg = gstart[g], end = gstart[g + 1];
    const uint2* h2 = (const uint2*)h32;
    float4 acc = make_float4(0.f, 0.f, 0.f, 0.f);
    for (int r = beg + p * 8 + ro; r < end; r += PP * 8) {
        uint2 u = h2[(size_t)r * 32 + c4];
        float vals[4] = {bflo(u.x), bfhi(u.x), bflo(u.y), bfhi(u.y)};
#pragma unroll
        for (int q = 0; q < 4; q++) {
            float y = sc[q] * vals[q] + sh[q];
            (&acc.x)[q] += y / (1.f + __expf(-y));
        }
    }
    __shared__ float4 sm[256];
    sm[t] = acc;
    __syncthreads();
    if (t < 128) {
        float4 o = sm[t + 128];
        sm[t].x += o.x; sm[t].y += o.y; sm[t].z += o.z; sm[t].w += o.w;
    }
    __syncthreads();
    if (t < 64) {
        float4 o = sm[t + 64];
        sm[t].x += o.x; sm[t].y += o.y; sm[t].z += o.z; sm[t].w += o.w;
    }
    __syncthreads();
    if (t < 32) {
        float4 o = sm[t + 32];
        float4 r = sm[t];
        r.x += o.x; r.y += o.y; r.z += o.z; r.w += o.w;
        ((float4*)ppool)[(size_t)blockIdx.x * 32 + t] = r;
    }
}

// ---------- pooling stage 2 + head MLP fused ----------
__global__ void k_pool_head(const float* __restrict__ ppool, const int* __restrict__ gstart,
                            const float* __restrict__ fc1w, const float* __restrict__ fc1b,
                            const float* __restrict__ fc2w, const float* __restrict__ fc2b,
                            float* __restrict__ out) {
    int g = blockIdx.x;
    int t = threadIdx.x;  // 128
    __shared__ float pa[HD];
    float s = 0.f;
    for (int p = 0; p < PP; p++) s += ppool[(size_t)(g * PP + p) * HD + t];
    float cnt = (float)(gstart[g + 1] - gstart[g]);
    pa[t] = s / fmaxf(cnt, 1.0f);
    __syncthreads();
    if (t < 64) {
        float a = fc1b[t];
        for (int k = 0; k < HD; k++) a += pa[k] * fc1w[k * 64 + t];
        a = a / (1.f + __expf(-a));  // SiLU
        float v = a * fc2w[t];
        for (int off = 32; off > 0; off >>= 1) v += __shfl_down(v, off);
        if (t == 0) out[g] = 1.f / (1.f + __expf(-(v + fc2b[0])));
    }
}

extern "C" void kernel_launch(void* const* d_in, const int* in_sizes, int n_in,
                              void* d_out, int out_size, void* d_ws, size_t ws_size,
                              hipStream_t stream) {
    const float* x = (const float*)d_in[0];
    const int* ei = (const int*)d_in[1];  // [2, E]: row=ei[0..E), col=ei[E..2E)
    const float* ea = (const float*)d_in[2];
    const int* batch = (const int*)d_in[3];
    const float* conv0_w = (const float*)d_in[5];
    const float* conv0_b = (const float*)d_in[6];
    const float* conv_ws = (const float*)d_in[7];
    const float* conv_bs = (const float*)d_in[8];
    const float* bn_gamma = (const float*)d_in[9];
    const float* bn_beta = (const float*)d_in[10];
    const float* fc1w = (const float*)d_in[11];
    const float* fc1b = (const float*)d_in[12];
    const float* fc2w = (const float*)d_in[13];
    const float* fc2b = (const float*)d_in[14];
    float* out = (float*)d_out;

    char* ws = (char*)d_ws;
    size_t off = 0;
    auto alloc = [&](size_t bytes) -> char* {
        char* p = ws + off;
        off = (off + bytes + 255) & ~(size_t)255;
        return p;
    };
    float* dinv = (float*)alloc(NN * 4);
    int* fill = (int*)alloc(NN * 4);
    int* col_ptr = (int*)alloc((NN + 1) * 4);
    int* pos = (int*)alloc(NE * 4);
    int2* sw = (int2*)alloc((size_t)NE * 8);
    unsigned* mbuf = (unsigned*)alloc((size_t)NN * HD * 2);
    unsigned* hA = (unsigned*)alloc((size_t)NN * HD * 2);
    unsigned* hB = (unsigned*)alloc((size_t)NN * HD * 2);
    unsigned* wbf = (unsigned*)alloc((size_t)NWFU * 4);
    float* stats = (float*)alloc(4 * 2 * HD * 4);
    float* ppool = (float*)alloc((size_t)NGR * PP * HD * 4);
    int* gstart = (int*)alloc((NGR + 1) * 4);
    int* bsum = (int*)alloc(SCB * 4);
    int* boff = (int*)alloc((SCB + 1) * 4);

    k_init<<<(NN + 255) / 256, 256, 0, stream>>>(fill, stats, conv_ws, wbf);
    k_pos<<<(NE + 255) / 256, 256, 0, stream>>>(ei, fill, pos);
    k_scan1<<<SCB, SCT, 0, stream>>>(fill, bsum);
    k_scan2_gb<<<2, SCB, 0, stream>>>(bsum, boff, batch, gstart);
    k_scan3<<<SCB, SCT, 0, stream>>>(fill, boff, col_ptr);
    k_scatter<<<(NE + 255) / 256, 256, 0, stream>>>(ei, ea, col_ptr, pos, sw);
    k_degsum<<<(NN + 255) / 256, 256, 0, stream>>>(col_ptr, sw, dinv);
    k_wnorm<<<(NN + 255) / 256, 256, 0, stream>>>(col_ptr, dinv, sw);

    float* st0 = stats;
    float* st1 = stats + 2 * HD;
    float* st2 = stats + 4 * HD;
    float* st3 = stats + 6 * HD;
    const int NG128 = (NN + BM - 1) / BM;
    const uint4* wf = (const uint4*)wbf;  // 2048 uint4 per layer

    // L0
    k_gemm0<<<(NN + 3) / 4, 256, 0, stream>>>(x, conv0_w, mbuf);
    k_agg<<<(NN + 3) / 4, 256, 0, stream>>>(mbuf, col_ptr, sw, dinv, conv0_b, hA);
    k_bnstats<<<256, 256, 0, stream>>>(hA, st0);
    // L1
    k_gemm128<<<NG128, 256, 0, stream>>>(hA, st0, bn_gamma, bn_beta, wf,
                                         (unsigned short*)mbuf);
    k_agg<<<(NN + 3) / 4, 256, 0, stream>>>(mbuf, col_ptr, sw, dinv, conv_bs, hB);
    k_bnstats<<<256, 256, 0, stream>>>(hB, st1);
    // L2
    k_gemm128<<<NG128, 256, 0, stream>>>(hB, st1, bn_gamma + HD, bn_beta + HD, wf + 2048,
                                         (unsigned short*)mbuf);
    k_agg<<<(NN + 3) / 4, 256, 0, stream>>>(mbuf, col_ptr, sw, dinv, conv_bs + HD, hA);
    k_bnstats<<<256, 256, 0, stream>>>(hA, st2);
    // L3
    k_gemm128<<<NG128, 256, 0, stream>>>(hA, st2, bn_gamma + 2 * HD, bn_beta + 2 * HD,
                                         wf + 4096, (unsigned short*)mbuf);
    k_agg<<<(NN + 3) / 4, 256, 0, stream>>>(mbuf, col_ptr, sw, dinv, conv_bs + 2 * HD, hB);
    k_bnstats<<<256, 256, 0, stream>>>(hB, st3);
    // fused final BN+SiLU + pool + head
    k_poolp<<<NGR * PP, 256, 0, stream>>>(hB, st3, bn_gamma + 3 * HD, bn_beta + 3 * HD,
                                          gstart, ppool);
    k_pool_head<<<NGR, HD, 0, stream>>>(ppool, gstart, fc1w, fc1b, fc2w, fc2b, out);
}

// Round 12
// 335.206 us; speedup vs baseline: 8.3700x; 1.0186x over previous
//
#include <hip/hip_runtime.h>

#define NN 50000
#define NE 500000
#define NGR 64
#define HD 128
#define INF 5
#define BN_EPS 1e-5f
#define BM 64
#define SCB 128
#define SCT 256
#define SCH ((NN + SCB - 1) / SCB)
#define PP 16             // pooling parts per graph
#define NWFU (3 * 8 * 4 * 64 * 4)  // wfrag uints: L*t*s*lane*4

typedef __attribute__((ext_vector_type(8))) short short8v;
typedef __attribute__((ext_vector_type(4))) float f32x4;

// ---------- bf16 helpers ----------
__device__ __forceinline__ float bflo(unsigned u) { return __uint_as_float(u << 16); }
__device__ __forceinline__ float bfhi(unsigned u) { return __uint_as_float(u & 0xffff0000u); }
__device__ __forceinline__ unsigned bfpack(float a, float b) {
    unsigned ua = __float_as_uint(a), ub = __float_as_uint(b);
    ua = (ua + 0x7fffu + ((ua >> 16) & 1u)) >> 16;
    ub = (ub + 0x7fffu + ((ub >> 16) & 1u)) >> 16;
    return ua | (ub << 16);
}
__device__ __forceinline__ unsigned short bf1(float a) {
    unsigned ua = __float_as_uint(a);
    return (unsigned short)((ua + 0x7fffu + ((ua >> 16) & 1u)) >> 16);
}

// ---------- init: fill=0, stats=0, pack conv weights into MFMA B-fragment order ----------
__global__ void k_init(int* fill, float* stats, const float* __restrict__ conv_ws,
                       unsigned* __restrict__ wbf) {
    int i = blockIdx.x * 256 + threadIdx.x;
    if (i < NN) fill[i] = 0;
    if (i < 4 * 2 * HD) stats[i] = 0.f;
    if (i < NWFU) {
        int inner = i & 3;
        int u4 = i >> 2;
        int lane = u4 & 63;
        int rest = u4 >> 6;
        int s = rest & 3, tt = (rest >> 2) & 7, L = rest >> 5;
        int col = tt * 16 + (lane & 15);
        int k = s * 32 + (lane >> 4) * 8 + inner * 2;
        const float* Wl = conv_ws + (size_t)L * HD * HD;
        wbf[i] = bfpack(Wl[k * HD + col], Wl[(k + 1) * HD + col]);
    }
}

// ---------- pass A: per-edge bucket position (the ONLY atomic pass) ----------
__global__ void k_pos(const int* __restrict__ ei, int* __restrict__ fill,
                      int* __restrict__ pos) {
    int e = blockIdx.x * 256 + threadIdx.x;
    if (e < NE) pos[e] = atomicAdd(&fill[ei[NE + e]], 1);
}

// ---------- hierarchical scan of fill -> col_ptr ----------
__global__ void k_scan1(const int* __restrict__ cnt, int* __restrict__ bsum) {
    __shared__ int sm[SCT];
    int b = blockIdx.x, t = threadIdx.x;
    int lo = b * SCH, hi = min(lo + SCH, NN);
    int s = 0;
    for (int i = lo + t; i < hi; i += SCT) s += cnt[i];
    sm[t] = s;
    __syncthreads();
    for (int off = SCT / 2; off > 0; off >>= 1) {
        if (t < off) sm[t] += sm[t + off];
        __syncthreads();
    }
    if (t == 0) bsum[b] = sm[0];
}

// block 0: scan of block sums; block 1: graph boundaries
__global__ void k_scan2_gb(const int* __restrict__ bsum, int* __restrict__ boff,
                           const int* __restrict__ batch, int* __restrict__ gstart) {
    int t = threadIdx.x;  // 128
    if (blockIdx.x == 1) {
        int g = t;
        if (g > NGR) return;
        int lo = 0, hi = NN;
        while (lo < hi) {
            int mid = (lo + hi) >> 1;
            if (batch[mid] < g) lo = mid + 1;
            else hi = mid;
        }
        gstart[g] = lo;
        return;
    }
    __shared__ int sm[SCB];
    sm[t] = bsum[t];
    __syncthreads();
    for (int off = 1; off < SCB; off <<= 1) {
        int v = (t >= off) ? sm[t - off] : 0;
        __syncthreads();
        sm[t] += v;
        __syncthreads();
    }
    boff[t] = (t == 0) ? 0 : sm[t - 1];
    if (t == SCB - 1) boff[SCB] = sm[SCB - 1];
}

__global__ void k_scan3(const int* __restrict__ cnt, const int* __restrict__ boff,
                        int* __restrict__ col_ptr) {
    __shared__ int sm[SCT];
    int b = blockIdx.x, t = threadIdx.x;
    int lo = b * SCH, hi = min(lo + SCH, NN);
    int e0 = lo + 2 * t, e1 = e0 + 1;
    int c0 = (e0 < hi) ? cnt[e0] : 0;
    int c1 = (e1 < hi) ? cnt[e1] : 0;
    sm[t] = c0 + c1;
    __syncthreads();
    for (int off = 1; off < SCT; off <<= 1) {
        int v = (t >= off) ? sm[t - off] : 0;
        __syncthreads();
        sm[t] += v;
        __syncthreads();
    }
    int base = boff[b] + ((t == 0) ? 0 : sm[t - 1]);
    if (e0 < hi) col_ptr[e0] = base;
    if (e1 < hi) col_ptr[e1] = base + c0;
    if (b == SCB - 1 && t == SCT - 1) col_ptr[NN] = boff[SCB];
}

// ---------- pass B: scatter {src, ea} as int2, no atomics ----------
__global__ void k_scatter(const int* __restrict__ ei, const float* __restrict__ ea,
                          const int* __restrict__ col_ptr, const int* __restrict__ pos,
                          int2* __restrict__ sw) {
    int e = blockIdx.x * 256 + threadIdx.x;
    if (e >= NE) return;
    int c = ei[NE + e];
    int p = col_ptr[c] + pos[e];
    sw[p] = make_int2(ei[e], __float_as_int(ea[e]));
}

// ---------- weighted degree via segment sum -> dinv (no atomics) ----------
__global__ void k_degsum(const int* __restrict__ col_ptr, const int2* __restrict__ sw,
                         float* __restrict__ dinv) {
    int i = blockIdx.x * 256 + threadIdx.x;
    if (i >= NN) return;
    int beg = col_ptr[i], end = col_ptr[i + 1];
    float s = 1.0f;  // self-loop weight
    for (int p = beg; p < end; p++) s += __int_as_float(sw[p].y);
    dinv[i] = rsqrtf(s);
}

// ---------- layer-0 transform: m = x @ W0 (K=5), bf16 output ----------
__global__ void k_gemm0(const float* __restrict__ x, const float* __restrict__ W,
                        unsigned* __restrict__ m32) {
    __shared__ float Ws[INF][HD];
    int t = threadIdx.x;  // 256
    for (int i = t; i < INF * HD; i += 256) ((float*)Ws)[i] = W[i];
    __syncthreads();
    int row = blockIdx.x * 4 + (t >> 6);
    if (row >= NN) return;
    int lane = t & 63;
    int c0 = 2 * lane;
    float xv[INF];
#pragma unroll
    for (int k = 0; k < INF; k++) xv[k] = x[row * INF + k];
    float a0 = 0.f, a1 = 0.f;
#pragma unroll
    for (int k = 0; k < INF; k++) {
        a0 += xv[k] * Ws[k][c0];
        a1 += xv[k] * Ws[k][c0 + 1];
    }
    m32[(size_t)row * 64 + lane] = bfpack(a0, a1);
}

// ---------- fused BN(prev)+SiLU + MFMA GEMM ----------
__global__ __launch_bounds__(256) void k_gemm128(
    const unsigned* __restrict__ h32, const float* __restrict__ stats,
    const float* __restrict__ gamma, const float* __restrict__ beta,
    const uint4* __restrict__ wfrag, unsigned short* __restrict__ m16) {
    __shared__ __align__(16) unsigned hs[64 * 64];  // 16 KB packed bf16
    __shared__ float sc[HD], sh[HD];
    int t = threadIdx.x;
    int r0 = blockIdx.x * BM;
    const float invn = 1.0f / NN;

    if (t < HD) {
        float mu = stats[t] * invn;
        float var = stats[HD + t] * invn - mu * mu;
        float s = gamma[t] * rsqrtf(var + BN_EPS);
        sc[t] = s;
        sh[t] = beta[t] - mu * s;
    }
    __syncthreads();

#pragma unroll
    for (int j = 0; j < 8; j++) {
        int g = j * 256 + t;      // uint2 slot 0..2047
        int r = g >> 5;           // row 0..63
        int u2 = g & 31;          // uint2 within row
        uint2 v = make_uint2(0u, 0u);
        if (r0 + r < NN) v = ((const uint2*)h32)[(size_t)(r0 + r) * 32 + u2];
        int c = u2 * 4;
        float y0 = sc[c] * bflo(v.x) + sh[c];
        float y1 = sc[c + 1] * bfhi(v.x) + sh[c + 1];
        float y2 = sc[c + 2] * bflo(v.y) + sh[c + 2];
        float y3 = sc[c + 3] * bfhi(v.y) + sh[c + 3];
        y0 = y0 / (1.f + __expf(-y0));
        y1 = y1 / (1.f + __expf(-y1));
        y2 = y2 / (1.f + __expf(-y2));
        y3 = y3 / (1.f + __expf(-y3));
        int slot = u2 >> 1, inner = (u2 & 1) * 2;
        int addr = r * 64 + ((slot ^ (r & 7)) << 2) + inner;
        hs[addr] = bfpack(y0, y1);
        hs[addr + 1] = bfpack(y2, y3);
    }
    __syncthreads();

    int w = t >> 6, l = t & 63;
    int lr = l & 15, lg = l >> 4;
    f32x4 acc[8];
#pragma unroll
    for (int i = 0; i < 8; i++) acc[i] = (f32x4){0.f, 0.f, 0.f, 0.f};

#pragma unroll
    for (int s = 0; s < 4; s++) {  // K steps of 32
        int arow = w * 16 + lr;
        int q = s * 4 + lg;
        short8v af = *reinterpret_cast<const short8v*>(
            &hs[arow * 64 + ((q ^ (arow & 7)) << 2)]);
#pragma unroll
        for (int tt = 0; tt < 8; tt++) {
            short8v bf = *reinterpret_cast<const short8v*>(&wfrag[(tt * 4 + s) * 64 + l]);
            acc[tt] = __builtin_amdgcn_mfma_f32_16x16x32_bf16(af, bf, acc[tt], 0, 0, 0);
        }
    }

    int baserow = r0 + w * 16 + lg * 4;
#pragma unroll
    for (int tt = 0; tt < 8; tt++) {
        int col = tt * 16 + lr;
#pragma unroll
        for (int reg = 0; reg < 4; reg++) {
            int row = baserow + reg;
            if (row < NN) m16[(size_t)row * HD + col] = bf1(acc[tt][reg]);
        }
    }
}

// ---------- sparse aggregation: predicated full-width unroll, bf16 gathers ----------
// NORM: compute w = dinv[src]*ea*dinv[dst] on the fly and write back (replaces k_wnorm).
template <bool NORM>
__global__ void k_agg(const unsigned* __restrict__ m32, const int* __restrict__ col_ptr,
                      int2* __restrict__ sw, const float* __restrict__ dinv,
                      const float* __restrict__ bias, unsigned* __restrict__ hpre32) {
    int node = blockIdx.x * 4 + (threadIdx.x >> 6);
    if (node >= NN) return;
    int lane = threadIdx.x & 63;
    float di = dinv[node];
    unsigned sv = m32[(size_t)node * 64 + lane];
    float a0 = di * di * bflo(sv);
    float a1 = di * di * bfhi(sv);
    int beg = col_ptr[node], end = col_ptr[node + 1];
    for (int p = beg; p < end; p += 8) {
        int lim = end - 1;
        int p0 = p, p1 = min(p + 1, lim), p2 = min(p + 2, lim), p3 = min(p + 3, lim);
        int p4 = min(p + 4, lim), p5 = min(p + 5, lim), p6 = min(p + 6, lim),
            p7 = min(p + 7, lim);
        int2 e0 = sw[p0], e1 = sw[p1], e2 = sw[p2], e3 = sw[p3];
        int2 e4 = sw[p4], e5 = sw[p5], e6 = sw[p6], e7 = sw[p7];
        unsigned v0 = m32[(size_t)e0.x * 64 + lane];
        unsigned v1 = m32[(size_t)e1.x * 64 + lane];
        unsigned v2 = m32[(size_t)e2.x * 64 + lane];
        unsigned v3 = m32[(size_t)e3.x * 64 + lane];
        unsigned v4 = m32[(size_t)e4.x * 64 + lane];
        unsigned v5 = m32[(size_t)e5.x * 64 + lane];
        unsigned v6 = m32[(size_t)e6.x * 64 + lane];
        unsigned v7 = m32[(size_t)e7.x * 64 + lane];
        float w0, w1, w2, w3, w4, w5, w6, w7;
        if (NORM) {
            w0 = dinv[e0.x] * __int_as_float(e0.y) * di;
            w1 = dinv[e1.x] * __int_as_float(e1.y) * di;
            w2 = dinv[e2.x] * __int_as_float(e2.y) * di;
            w3 = dinv[e3.x] * __int_as_float(e3.y) * di;
            w4 = dinv[e4.x] * __int_as_float(e4.y) * di;
            w5 = dinv[e5.x] * __int_as_float(e5.y) * di;
            w6 = dinv[e6.x] * __int_as_float(e6.y) * di;
            w7 = dinv[e7.x] * __int_as_float(e7.y) * di;
            if (lane == 0) {  // write normalized weights back for layers 1..3
                sw[p0].y = __float_as_int(w0);
                if (p + 1 < end) sw[p1].y = __float_as_int(w1);
                if (p + 2 < end) sw[p2].y = __float_as_int(w2);
                if (p + 3 < end) sw[p3].y = __float_as_int(w3);
                if (p + 4 < end) sw[p4].y = __float_as_int(w4);
                if (p + 5 < end) sw[p5].y = __float_as_int(w5);
                if (p + 6 < end) sw[p6].y = __float_as_int(w6);
                if (p + 7 < end) sw[p7].y = __float_as_int(w7);
            }
        } else {
            w0 = __int_as_float(e0.y);
            w1 = __int_as_float(e1.y);
            w2 = __int_as_float(e2.y);
            w3 = __int_as_float(e3.y);
            w4 = __int_as_float(e4.y);
            w5 = __int_as_float(e5.y);
            w6 = __int_as_float(e6.y);
            w7 = __int_as_float(e7.y);
        }
        // zero weights of clamped (out-of-range) slots
        if (p + 1 >= end) w1 = 0.f;
        if (p + 2 >= end) w2 = 0.f;
        if (p + 3 >= end) w3 = 0.f;
        if (p + 4 >= end) w4 = 0.f;
        if (p + 5 >= end) w5 = 0.f;
        if (p + 6 >= end) w6 = 0.f;
        if (p + 7 >= end) w7 = 0.f;
        a0 += w0 * bflo(v0) + w1 * bflo(v1) + w2 * bflo(v2) + w3 * bflo(v3);
        a1 += w0 * bfhi(v0) + w1 * bfhi(v1) + w2 * bfhi(v2) + w3 * bfhi(v3);
        a0 += w4 * bflo(v4) + w5 * bflo(v5) + w6 * bflo(v6) + w7 * bflo(v7);
        a1 += w4 * bfhi(v4) + w5 * bfhi(v5) + w6 * bfhi(v6) + w7 * bfhi(v7);
    }
    float2 b = ((const float2*)bias)[lane];
    hpre32[(size_t)node * 64 + lane] = bfpack(a0 + b.x, a1 + b.y);
}

// ---------- batchnorm stats from bf16 hpre ----------
__global__ void k_bnstats(const unsigned* __restrict__ h32, float* __restrict__ stats) {
    __shared__ float lss[4][HD];
    __shared__ float lsq[4][HD];
    int t = threadIdx.x;  // 256
    int w = t >> 6, l = t & 63;
    float s0 = 0.f, s1 = 0.f, q0 = 0.f, q1 = 0.f;
    for (int r = blockIdx.x * 4 + w; r < NN; r += 1024) {
        unsigned v = h32[(size_t)r * 64 + l];
        float a = bflo(v), b = bfhi(v);
        s0 += a; q0 += a * a;
        s1 += b; q1 += b * b;
    }
    lss[w][2 * l] = s0;
    lss[w][2 * l + 1] = s1;
    lsq[w][2 * l] = q0;
    lsq[w][2 * l + 1] = q1;
    __syncthreads();
    if (t < HD) {
        float s = lss[0][t] + lss[1][t] + lss[2][t] + lss[3][t];
        atomicAdd(&stats[t], s);
    } else {
        int c = t - HD;
        float q = lsq[0][c] + lsq[1][c] + lsq[2][c] + lsq[3][c];
        atomicAdd(&stats[HD + c], q);
    }
}

// ---------- pooling stage 1 (fused final BN+SiLU), bf16 input ----------
__global__ void k_poolp(const unsigned* __restrict__ h32, const float* __restrict__ stats,
                        const float* __restrict__ gamma, const float* __restrict__ beta,
                        const int* __restrict__ gstart, float* __restrict__ ppool) {
    int g = blockIdx.x / PP, p = blockIdx.x % PP;
    int t = threadIdx.x;          // 256
    int c4 = t & 31;              // 4-channel group
    int ro = t >> 5;
    const float invn = 1.0f / NN;
    float sc[4], sh[4];
#pragma unroll
    for (int q = 0; q < 4; q++) {
        int c = c4 * 4 + q;
        float mu = stats[c] * invn;
        float var = stats[HD + c] * invn - mu * mu;
        float s = gamma[c] * rsqrtf(var + BN_EPS);
        sc[q] = s;
        sh[q] = beta[c] - mu * s;
    }
    int beg = gstart[g], end = gstart[g + 1];
    const uint2* h2 = (const uint2*)h32;
    float4 acc = make_float4(0.f, 0.f, 0.f, 0.f);
    for (int r = beg + p * 8 + ro; r < end; r += PP * 8) {
        uint2 u = h2[(size_t)r * 32 + c4];
        float vals[4] = {bflo(u.x), bfhi(u.x), bflo(u.y), bfhi(u.y)};
#pragma unroll
        for (int q = 0; q < 4; q++) {
            float y = sc[q] * vals[q] + sh[q];
            (&acc.x)[q] += y / (1.f + __expf(-y));
        }
    }
    __shared__ float4 sm[256];
    sm[t] = acc;
    __syncthreads();
    if (t < 128) {
        float4 o = sm[t + 128];
        sm[t].x += o.x; sm[t].y += o.y; sm[t].z += o.z; sm[t].w += o.w;
    }
    __syncthreads();
    if (t < 64) {
        float4 o = sm[t + 64];
        sm[t].x += o.x; sm[t].y += o.y; sm[t].z += o.z; sm[t].w += o.w;
    }
    __syncthreads();
    if (t < 32) {
        float4 o = sm[t + 32];
        float4 r = sm[t];
        r.x += o.x; r.y += o.y; r.z += o.z; r.w += o.w;
        ((float4*)ppool)[(size_t)blockIdx.x * 32 + t] = r;
    }
}

// ---------- pooling stage 2 + head MLP fused ----------
__global__ void k_pool_head(const float* __restrict__ ppool, const int* __restrict__ gstart,
                            const float* __restrict__ fc1w, const float* __restrict__ fc1b,
                            const float* __restrict__ fc2w, const float* __restrict__ fc2b,
                            float* __restrict__ out) {
    int g = blockIdx.x;
    int t = threadIdx.x;  // 128
    __shared__ float pa[HD];
    float s = 0.f;
    for (int p = 0; p < PP; p++) s += ppool[(size_t)(g * PP + p) * HD + t];
    float cnt = (float)(gstart[g + 1] - gstart[g]);
    pa[t] = s / fmaxf(cnt, 1.0f);
    __syncthreads();
    if (t < 64) {
        float a = fc1b[t];
        for (int k = 0; k < HD; k++) a += pa[k] * fc1w[k * 64 + t];
        a = a / (1.f + __expf(-a));  // SiLU
        float v = a * fc2w[t];
        for (int off = 32; off > 0; off >>= 1) v += __shfl_down(v, off);
        if (t == 0) out[g] = 1.f / (1.f + __expf(-(v + fc2b[0])));
    }
}

extern "C" void kernel_launch(void* const* d_in, const int* in_sizes, int n_in,
                              void* d_out, int out_size, void* d_ws, size_t ws_size,
                              hipStream_t stream) {
    const float* x = (const float*)d_in[0];
    const int* ei = (const int*)d_in[1];  // [2, E]: row=ei[0..E), col=ei[E..2E)
    const float* ea = (const float*)d_in[2];
    const int* batch = (const int*)d_in[3];
    const float* conv0_w = (const float*)d_in[5];
    const float* conv0_b = (const float*)d_in[6];
    const float* conv_ws = (const float*)d_in[7];
    const float* conv_bs = (const float*)d_in[8];
    const float* bn_gamma = (const float*)d_in[9];
    const float* bn_beta = (const float*)d_in[10];
    const float* fc1w = (const float*)d_in[11];
    const float* fc1b = (const float*)d_in[12];
    const float* fc2w = (const float*)d_in[13];
    const float* fc2b = (const float*)d_in[14];
    float* out = (float*)d_out;

    char* ws = (char*)d_ws;
    size_t off = 0;
    auto alloc = [&](size_t bytes) -> char* {
        char* p = ws + off;
        off = (off + bytes + 255) & ~(size_t)255;
        return p;
    };
    float* dinv = (float*)alloc(NN * 4);
    int* fill = (int*)alloc(NN * 4);
    int* col_ptr = (int*)alloc((NN + 1) * 4);
    int* pos = (int*)alloc(NE * 4);
    int2* sw = (int2*)alloc((size_t)NE * 8);
    unsigned* mbuf = (unsigned*)alloc((size_t)NN * HD * 2);
    unsigned* hA = (unsigned*)alloc((size_t)NN * HD * 2);
    unsigned* hB = (unsigned*)alloc((size_t)NN * HD * 2);
    unsigned* wbf = (unsigned*)alloc((size_t)NWFU * 4);
    float* stats = (float*)alloc(4 * 2 * HD * 4);
    float* ppool = (float*)alloc((size_t)NGR * PP * HD * 4);
    int* gstart = (int*)alloc((NGR + 1) * 4);
    int* bsum = (int*)alloc(SCB * 4);
    int* boff = (int*)alloc((SCB + 1) * 4);

    k_init<<<(NN + 255) / 256, 256, 0, stream>>>(fill, stats, conv_ws, wbf);
    k_pos<<<(NE + 255) / 256, 256, 0, stream>>>(ei, fill, pos);
    k_scan1<<<SCB, SCT, 0, stream>>>(fill, bsum);
    k_scan2_gb<<<2, SCB, 0, stream>>>(bsum, boff, batch, gstart);
    k_scan3<<<SCB, SCT, 0, stream>>>(fill, boff, col_ptr);
    k_scatter<<<(NE + 255) / 256, 256, 0, stream>>>(ei, ea, col_ptr, pos, sw);
    k_degsum<<<(NN + 255) / 256, 256, 0, stream>>>(col_ptr, sw, dinv);

    float* st0 = stats;
    float* st1 = stats + 2 * HD;
    float* st2 = stats + 4 * HD;
    float* st3 = stats + 6 * HD;
    const int NG128 = (NN + BM - 1) / BM;
    const uint4* wf = (const uint4*)wbf;  // 2048 uint4 per layer

    // L0 (agg fuses weight normalization; writes normalized w back to sw)
    k_gemm0<<<(NN + 3) / 4, 256, 0, stream>>>(x, conv0_w, mbuf);
    k_agg<true><<<(NN + 3) / 4, 256, 0, stream>>>(mbuf, col_ptr, sw, dinv, conv0_b, hA);
    k_bnstats<<<256, 256, 0, stream>>>(hA, st0);
    // L1
    k_gemm128<<<NG128, 256, 0, stream>>>(hA, st0, bn_gamma, bn_beta, wf,
                                         (unsigned short*)mbuf);
    k_agg<false><<<(NN + 3) / 4, 256, 0, stream>>>(mbuf, col_ptr, sw, dinv, conv_bs, hB);
    k_bnstats<<<256, 256, 0, stream>>>(hB, st1);
    // L2
    k_gemm128<<<NG128, 256, 0, stream>>>(hB, st1, bn_gamma + HD, bn_beta + HD, wf + 2048,
                                         (unsigned short*)mbuf);
    k_agg<false><<<(NN + 3) / 4, 256, 0, stream>>>(mbuf, col_ptr, sw, dinv, conv_bs + HD, hA);
    k_bnstats<<<256, 256, 0, stream>>>(hA, st2);
    // L3
    k_gemm128<<<NG128, 256, 0, stream>>>(hA, st2, bn_gamma + 2 * HD, bn_beta + 2 * HD,
                                         wf + 4096, (unsigned short*)mbuf);
    k_agg<false><<<(NN + 3) / 4, 256, 0, stream>>>(mbuf, col_ptr, sw, dinv,
                                                   conv_bs + 2 * HD, hB);
    k_bnstats<<<256, 256, 0, stream>>>(hB, st3);
    // fused final BN+SiLU + pool + head
    k_poolp<<<NGR * PP, 256, 0, stream>>>(hB, st3, bn_gamma + 3 * HD, bn_beta + 3 * HD,
                                          gstart, ppool);
    k_pool_head<<<NGR, HD, 0, stream>>>(ppool, gstart, fc1w, fc1b, fc2w, fc2b, out);
}

// Round 13
// 302.929 us; speedup vs baseline: 9.2618x; 1.1065x over previous
//
#include <hip/hip_runtime.h>

#define NN 50000
#define NE 500000
#define NGR 64
#define HD 128
#define INF 5
#define BN_EPS 1e-5f
#define BM 64
#define SCB 128
#define SCT 256
#define SCH ((NN + SCB - 1) / SCB)
#define PP 16             // pooling parts per graph
#define NWFU (3 * 8 * 4 * 64 * 4)  // wfrag uints: L*t*s*lane*4
#define PAD8(c) (((c) + 7) & ~7)

typedef __attribute__((ext_vector_type(8))) short short8v;
typedef __attribute__((ext_vector_type(4))) float f32x4;

// ---------- bf16 helpers ----------
__device__ __forceinline__ float bflo(unsigned u) { return __uint_as_float(u << 16); }
__device__ __forceinline__ float bfhi(unsigned u) { return __uint_as_float(u & 0xffff0000u); }
__device__ __forceinline__ unsigned bfpack(float a, float b) {
    unsigned ua = __float_as_uint(a), ub = __float_as_uint(b);
    ua = (ua + 0x7fffu + ((ua >> 16) & 1u)) >> 16;
    ub = (ub + 0x7fffu + ((ub >> 16) & 1u)) >> 16;
    return ua | (ub << 16);
}
__device__ __forceinline__ unsigned short bf1(float a) {
    unsigned ua = __float_as_uint(a);
    return (unsigned short)((ua + 0x7fffu + ((ua >> 16) & 1u)) >> 16);
}

// ---------- init: fill=0, stats=0, pack conv weights into MFMA B-fragment order ----------
__global__ void k_init(int* fill, float* stats, const float* __restrict__ conv_ws,
                       unsigned* __restrict__ wbf) {
    int i = blockIdx.x * 256 + threadIdx.x;
    if (i < NN) fill[i] = 0;
    if (i < 4 * 2 * HD) stats[i] = 0.f;
    if (i < NWFU) {
        int inner = i & 3;
        int u4 = i >> 2;
        int lane = u4 & 63;
        int rest = u4 >> 6;
        int s = rest & 3, tt = (rest >> 2) & 7, L = rest >> 5;
        int col = tt * 16 + (lane & 15);
        int k = s * 32 + (lane >> 4) * 8 + inner * 2;
        const float* Wl = conv_ws + (size_t)L * HD * HD;
        wbf[i] = bfpack(Wl[k * HD + col], Wl[(k + 1) * HD + col]);
    }
}

// ---------- pass A: per-edge bucket position (the ONLY atomic pass) ----------
__global__ void k_pos(const int* __restrict__ ei, int* __restrict__ fill,
                      int* __restrict__ pos) {
    int e = blockIdx.x * 256 + threadIdx.x;
    if (e < NE) pos[e] = atomicAdd(&fill[ei[NE + e]], 1);
}

// ---------- hierarchical scan of PADDED fill -> col_ptr ----------
__global__ void k_scan1(const int* __restrict__ cnt, int* __restrict__ bsum) {
    __shared__ int sm[SCT];
    int b = blockIdx.x, t = threadIdx.x;
    int lo = b * SCH, hi = min(lo + SCH, NN);
    int s = 0;
    for (int i = lo + t; i < hi; i += SCT) s += PAD8(cnt[i]);
    sm[t] = s;
    __syncthreads();
    for (int off = SCT / 2; off > 0; off >>= 1) {
        if (t < off) sm[t] += sm[t + off];
        __syncthreads();
    }
    if (t == 0) bsum[b] = sm[0];
}

// block 0: scan of block sums; block 1: graph boundaries
__global__ void k_scan2_gb(const int* __restrict__ bsum, int* __restrict__ boff,
                           const int* __restrict__ batch, int* __restrict__ gstart) {
    int t = threadIdx.x;  // 128
    if (blockIdx.x == 1) {
        int g = t;
        if (g > NGR) return;
        int lo = 0, hi = NN;
        while (lo < hi) {
            int mid = (lo + hi) >> 1;
            if (batch[mid] < g) lo = mid + 1;
            else hi = mid;
        }
        gstart[g] = lo;
        return;
    }
    __shared__ int sm[SCB];
    sm[t] = bsum[t];
    __syncthreads();
    for (int off = 1; off < SCB; off <<= 1) {
        int v = (t >= off) ? sm[t - off] : 0;
        __syncthreads();
        sm[t] += v;
        __syncthreads();
    }
    boff[t] = (t == 0) ? 0 : sm[t - 1];
    if (t == SCB - 1) boff[SCB] = sm[SCB - 1];
}

__global__ void k_scan3(const int* __restrict__ cnt, const int* __restrict__ boff,
                        int* __restrict__ col_ptr) {
    __shared__ int sm[SCT];
    int b = blockIdx.x, t = threadIdx.x;
    int lo = b * SCH, hi = min(lo + SCH, NN);
    int e0 = lo + 2 * t, e1 = e0 + 1;
    int c0 = (e0 < hi) ? PAD8(cnt[e0]) : 0;
    int c1 = (e1 < hi) ? PAD8(cnt[e1]) : 0;
    sm[t] = c0 + c1;
    __syncthreads();
    for (int off = 1; off < SCT; off <<= 1) {
        int v = (t >= off) ? sm[t - off] : 0;
        __syncthreads();
        sm[t] += v;
        __syncthreads();
    }
    int base = boff[b] + ((t == 0) ? 0 : sm[t - 1]);
    if (e0 < hi) col_ptr[e0] = base;
    if (e1 < hi) col_ptr[e1] = base + c0;
    if (b == SCB - 1 && t == SCT - 1) col_ptr[NN] = boff[SCB];
}

// ---------- pass B: scatter {src, ea} as int2, no atomics ----------
__global__ void k_scatter(const int* __restrict__ ei, const float* __restrict__ ea,
                          const int* __restrict__ col_ptr, const int* __restrict__ pos,
                          int2* __restrict__ sw) {
    int e = blockIdx.x * 256 + threadIdx.x;
    if (e >= NE) return;
    int c = ei[NE + e];
    int p = col_ptr[c] + pos[e];
    sw[p] = make_int2(ei[e], __float_as_int(ea[e]));
}

// ---------- weighted degree (real count) + write zero pads ----------
__global__ void k_degsum(const int* __restrict__ col_ptr, const int* __restrict__ cnt,
                         int2* __restrict__ sw, float* __restrict__ dinv) {
    int i = blockIdx.x * 256 + threadIdx.x;
    if (i >= NN) return;
    int beg = col_ptr[i], mid = beg + cnt[i], end = col_ptr[i + 1];
    float s = 1.0f;  // self-loop weight
    for (int p = beg; p < mid; p++) s += __int_as_float(sw[p].y);
    for (int p = mid; p < end; p++) sw[p] = make_int2(0, 0);  // pad: src=0, w=0
    dinv[i] = rsqrtf(s);
}

// ---------- layer-0 transform: m = x @ W0 (K=5), bf16 output ----------
__global__ void k_gemm0(const float* __restrict__ x, const float* __restrict__ W,
                        unsigned* __restrict__ m32) {
    __shared__ float Ws[INF][HD];
    int t = threadIdx.x;  // 256
    for (int i = t; i < INF * HD; i += 256) ((float*)Ws)[i] = W[i];
    __syncthreads();
    int row = blockIdx.x * 4 + (t >> 6);
    if (row >= NN) return;
    int lane = t & 63;
    int c0 = 2 * lane;
    float xv[INF];
#pragma unroll
    for (int k = 0; k < INF; k++) xv[k] = x[row * INF + k];
    float a0 = 0.f, a1 = 0.f;
#pragma unroll
    for (int k = 0; k < INF; k++) {
        a0 += xv[k] * Ws[k][c0];
        a1 += xv[k] * Ws[k][c0 + 1];
    }
    m32[(size_t)row * 64 + lane] = bfpack(a0, a1);
}

// ---------- fused BN(prev)+SiLU + MFMA GEMM ----------
__global__ __launch_bounds__(256) void k_gemm128(
    const unsigned* __restrict__ h32, const float* __restrict__ stats,
    const float* __restrict__ gamma, const float* __restrict__ beta,
    const uint4* __restrict__ wfrag, unsigned short* __restrict__ m16) {
    __shared__ __align__(16) unsigned hs[64 * 64];  // 16 KB packed bf16
    __shared__ float sc[HD], sh[HD];
    int t = threadIdx.x;
    int r0 = blockIdx.x * BM;
    const float invn = 1.0f / NN;

    if (t < HD) {
        float mu = stats[t] * invn;
        float var = stats[HD + t] * invn - mu * mu;
        float s = gamma[t] * rsqrtf(var + BN_EPS);
        sc[t] = s;
        sh[t] = beta[t] - mu * s;
    }
    __syncthreads();

#pragma unroll
    for (int j = 0; j < 8; j++) {
        int g = j * 256 + t;      // uint2 slot 0..2047
        int r = g >> 5;           // row 0..63
        int u2 = g & 31;          // uint2 within row
        uint2 v = make_uint2(0u, 0u);
        if (r0 + r < NN) v = ((const uint2*)h32)[(size_t)(r0 + r) * 32 + u2];
        int c = u2 * 4;
        float y0 = sc[c] * bflo(v.x) + sh[c];
        float y1 = sc[c + 1] * bfhi(v.x) + sh[c + 1];
        float y2 = sc[c + 2] * bflo(v.y) + sh[c + 2];
        float y3 = sc[c + 3] * bfhi(v.y) + sh[c + 3];
        y0 = y0 / (1.f + __expf(-y0));
        y1 = y1 / (1.f + __expf(-y1));
        y2 = y2 / (1.f + __expf(-y2));
        y3 = y3 / (1.f + __expf(-y3));
        int slot = u2 >> 1, inner = (u2 & 1) * 2;
        int addr = r * 64 + ((slot ^ (r & 7)) << 2) + inner;
        hs[addr] = bfpack(y0, y1);
        hs[addr + 1] = bfpack(y2, y3);
    }
    __syncthreads();

    int w = t >> 6, l = t & 63;
    int lr = l & 15, lg = l >> 4;
    f32x4 acc[8];
#pragma unroll
    for (int i = 0; i < 8; i++) acc[i] = (f32x4){0.f, 0.f, 0.f, 0.f};

#pragma unroll
    for (int s = 0; s < 4; s++) {  // K steps of 32
        int arow = w * 16 + lr;
        int q = s * 4 + lg;
        short8v af = *reinterpret_cast<const short8v*>(
            &hs[arow * 64 + ((q ^ (arow & 7)) << 2)]);
#pragma unroll
        for (int tt = 0; tt < 8; tt++) {
            short8v bf = *reinterpret_cast<const short8v*>(&wfrag[(tt * 4 + s) * 64 + l]);
            acc[tt] = __builtin_amdgcn_mfma_f32_16x16x32_bf16(af, bf, acc[tt], 0, 0, 0);
        }
    }

    int baserow = r0 + w * 16 + lg * 4;
#pragma unroll
    for (int tt = 0; tt < 8; tt++) {
        int col = tt * 16 + lr;
#pragma unroll
        for (int reg = 0; reg < 4; reg++) {
            int row = baserow + reg;
            if (row < NN) m16[(size_t)row * HD + col] = bf1(acc[tt][reg]);
        }
    }
}

// ---------- sparse aggregation: padded segments, scalar-base gathers ----------
template <bool NORM>
__global__ void k_agg(const unsigned* __restrict__ m32, const int* __restrict__ col_ptr,
                      int2* __restrict__ sw, const float* __restrict__ dinv,
                      const float* __restrict__ bias, unsigned* __restrict__ hpre32) {
    int node = blockIdx.x * 4 + (threadIdx.x >> 6);
    if (node >= NN) return;
    int lane = threadIdx.x & 63;
    float di = dinv[node];
    unsigned sv = m32[(size_t)node * 64 + lane];
    float a0 = di * di * bflo(sv);
    float a1 = di * di * bfhi(sv);
    int beg = col_ptr[node], end = col_ptr[node + 1];  // both 8-aligned
    for (int p = beg; p < end; p += 8) {
        int2 e0 = sw[p], e1 = sw[p + 1], e2 = sw[p + 2], e3 = sw[p + 3];
        int2 e4 = sw[p + 4], e5 = sw[p + 5], e6 = sw[p + 6], e7 = sw[p + 7];
        // wave-uniform scalar indices -> SGPR-based gathers (no per-lane addr math)
        int s0 = __builtin_amdgcn_readfirstlane(e0.x);
        int s1 = __builtin_amdgcn_readfirstlane(e1.x);
        int s2 = __builtin_amdgcn_readfirstlane(e2.x);
        int s3 = __builtin_amdgcn_readfirstlane(e3.x);
        int s4 = __builtin_amdgcn_readfirstlane(e4.x);
        int s5 = __builtin_amdgcn_readfirstlane(e5.x);
        int s6 = __builtin_amdgcn_readfirstlane(e6.x);
        int s7 = __builtin_amdgcn_readfirstlane(e7.x);
        unsigned v0 = m32[(size_t)s0 * 64 + lane];
        unsigned v1 = m32[(size_t)s1 * 64 + lane];
        unsigned v2 = m32[(size_t)s2 * 64 + lane];
        unsigned v3 = m32[(size_t)s3 * 64 + lane];
        unsigned v4 = m32[(size_t)s4 * 64 + lane];
        unsigned v5 = m32[(size_t)s5 * 64 + lane];
        unsigned v6 = m32[(size_t)s6 * 64 + lane];
        unsigned v7 = m32[(size_t)s7 * 64 + lane];
        float w0 = __int_as_float(__builtin_amdgcn_readfirstlane(e0.y));
        float w1 = __int_as_float(__builtin_amdgcn_readfirstlane(e1.y));
        float w2 = __int_as_float(__builtin_amdgcn_readfirstlane(e2.y));
        float w3 = __int_as_float(__builtin_amdgcn_readfirstlane(e3.y));
        float w4 = __int_as_float(__builtin_amdgcn_readfirstlane(e4.y));
        float w5 = __int_as_float(__builtin_amdgcn_readfirstlane(e5.y));
        float w6 = __int_as_float(__builtin_amdgcn_readfirstlane(e6.y));
        float w7 = __int_as_float(__builtin_amdgcn_readfirstlane(e7.y));
        if (NORM) {
            w0 = dinv[s0] * w0 * di;
            w1 = dinv[s1] * w1 * di;
            w2 = dinv[s2] * w2 * di;
            w3 = dinv[s3] * w3 * di;
            w4 = dinv[s4] * w4 * di;
            w5 = dinv[s5] * w5 * di;
            w6 = dinv[s6] * w6 * di;
            w7 = dinv[s7] * w7 * di;
            if (lane == 0) {  // write normalized weights back for layers 1..3
                sw[p].y = __float_as_int(w0);
                sw[p + 1].y = __float_as_int(w1);
                sw[p + 2].y = __float_as_int(w2);
                sw[p + 3].y = __float_as_int(w3);
                sw[p + 4].y = __float_as_int(w4);
                sw[p + 5].y = __float_as_int(w5);
                sw[p + 6].y = __float_as_int(w6);
                sw[p + 7].y = __float_as_int(w7);
            }
        }
        a0 += w0 * bflo(v0) + w1 * bflo(v1) + w2 * bflo(v2) + w3 * bflo(v3);
        a1 += w0 * bfhi(v0) + w1 * bfhi(v1) + w2 * bfhi(v2) + w3 * bfhi(v3);
        a0 += w4 * bflo(v4) + w5 * bflo(v5) + w6 * bflo(v6) + w7 * bflo(v7);
        a1 += w4 * bfhi(v4) + w5 * bfhi(v5) + w6 * bfhi(v6) + w7 * bfhi(v7);
    }
    float2 b = ((const float2*)bias)[lane];
    hpre32[(size_t)node * 64 + lane] = bfpack(a0 + b.x, a1 + b.y);
}

// ---------- batchnorm stats from bf16 hpre ----------
__global__ void k_bnstats(const unsigned* __restrict__ h32, float* __restrict__ stats) {
    __shared__ float lss[4][HD];
    __shared__ float lsq[4][HD];
    int t = threadIdx.x;  // 256
    int w = t >> 6, l = t & 63;
    float s0 = 0.f, s1 = 0.f, q0 = 0.f, q1 = 0.f;
    for (int r = blockIdx.x * 4 + w; r < NN; r += 1024) {
        unsigned v = h32[(size_t)r * 64 + l];
        float a = bflo(v), b = bfhi(v);
        s0 += a; q0 += a * a;
        s1 += b; q1 += b * b;
    }
    lss[w][2 * l] = s0;
    lss[w][2 * l + 1] = s1;
    lsq[w][2 * l] = q0;
    lsq[w][2 * l + 1] = q1;
    __syncthreads();
    if (t < HD) {
        float s = lss[0][t] + lss[1][t] + lss[2][t] + lss[3][t];
        atomicAdd(&stats[t], s);
    } else {
        int c = t - HD;
        float q = lsq[0][c] + lsq[1][c] + lsq[2][c] + lsq[3][c];
        atomicAdd(&stats[HD + c], q);
    }
}

// ---------- pooling stage 1 (fused final BN+SiLU), bf16 input ----------
__global__ void k_poolp(const unsigned* __restrict__ h32, const float* __restrict__ stats,
                        const float* __restrict__ gamma, const float* __restrict__ beta,
                        const int* __restrict__ gstart, float* __restrict__ ppool) {
    int g = blockIdx.x / PP, p = blockIdx.x % PP;
    int t = threadIdx.x;          // 256
    int c4 = t & 31;              // 4-channel group
    int ro = t >> 5;
    const float invn = 1.0f / NN;
    float sc[4], sh[4];
#pragma unroll
    for (int q = 0; q < 4; q++) {
        int c = c4 * 4 + q;
        float mu = stats[c] * invn;
        float var = stats[HD + c] * invn - mu * mu;
        float s = gamma[c] * rsqrtf(var + BN_EPS);
        sc[q] = s;
        sh[q] = beta[c] - mu * s;
    }
    int beg = gstart[g], end = gstart[g + 1];
    const uint2* h2 = (const uint2*)h32;
    float4 acc = make_float4(0.f, 0.f, 0.f, 0.f);
    for (int r = beg + p * 8 + ro; r < end; r += PP * 8) {
        uint2 u = h2[(size_t)r * 32 + c4];
        float vals[4] = {bflo(u.x), bfhi(u.x), bflo(u.y), bfhi(u.y)};
#pragma unroll
        for (int q = 0; q < 4; q++) {
            float y = sc[q] * vals[q] + sh[q];
            (&acc.x)[q] += y / (1.f + __expf(-y));
        }
    }
    __shared__ float4 sm[256];
    sm[t] = acc;
    __syncthreads();
    if (t < 128) {
        float4 o = sm[t + 128];
        sm[t].x += o.x; sm[t].y += o.y; sm[t].z += o.z; sm[t].w += o.w;
    }
    __syncthreads();
    if (t < 64) {
        float4 o = sm[t + 64];
        sm[t].x += o.x; sm[t].y += o.y; sm[t].z += o.z; sm[t].w += o.w;
    }
    __syncthreads();
    if (t < 32) {
        float4 o = sm[t + 32];
        float4 r = sm[t];
        r.x += o.x; r.y += o.y; r.z += o.z; r.w += o.w;
        ((float4*)ppool)[(size_t)blockIdx.x * 32 + t] = r;
    }
}

// ---------- pooling stage 2 + head MLP fused ----------
__global__ void k_pool_head(const float* __restrict__ ppool, const int* __restrict__ gstart,
                            const float* __restrict__ fc1w, const float* __restrict__ fc1b,
                            const float* __restrict__ fc2w, const float* __restrict__ fc2b,
                            float* __restrict__ out) {
    int g = blockIdx.x;
    int t = threadIdx.x;  // 128
    __shared__ float pa[HD];
    float s = 0.f;
    for (int p = 0; p < PP; p++) s += ppool[(size_t)(g * PP + p) * HD + t];
    float cnt = (float)(gstart[g + 1] - gstart[g]);
    pa[t] = s / fmaxf(cnt, 1.0f);
    __syncthreads();
    if (t < 64) {
        float a = fc1b[t];
        for (int k = 0; k < HD; k++) a += pa[k] * fc1w[k * 64 + t];
        a = a / (1.f + __expf(-a));  // SiLU
        float v = a * fc2w[t];
        for (int off = 32; off > 0; off >>= 1) v += __shfl_down(v, off);
        if (t == 0) out[g] = 1.f / (1.f + __expf(-(v + fc2b[0])));
    }
}

extern "C" void kernel_launch(void* const* d_in, const int* in_sizes, int n_in,
                              void* d_out, int out_size, void* d_ws, size_t ws_size,
                              hipStream_t stream) {
    const float* x = (const float*)d_in[0];
    const int* ei = (const int*)d_in[1];  // [2, E]: row=ei[0..E), col=ei[E..2E)
    const float* ea = (const float*)d_in[2];
    const int* batch = (const int*)d_in[3];
    const float* conv0_w = (const float*)d_in[5];
    const float* conv0_b = (const float*)d_in[6];
    const float* conv_ws = (const float*)d_in[7];
    const float* conv_bs = (const float*)d_in[8];
    const float* bn_gamma = (const float*)d_in[9];
    const float* bn_beta = (const float*)d_in[10];
    const float* fc1w = (const float*)d_in[11];
    const float* fc1b = (const float*)d_in[12];
    const float* fc2w = (const float*)d_in[13];
    const float* fc2b = (const float*)d_in[14];
    float* out = (float*)d_out;

    char* ws = (char*)d_ws;
    size_t off = 0;
    auto alloc = [&](size_t bytes) -> char* {
        char* p = ws + off;
        off = (off + bytes + 255) & ~(size_t)255;
        return p;
    };
    float* dinv = (float*)alloc(NN * 4);
    int* fill = (int*)alloc(NN * 4);
    int* col_ptr = (int*)alloc((NN + 1) * 4);
    int* pos = (int*)alloc(NE * 4);
    int2* sw = (int2*)alloc(((size_t)NE + 8 * NN) * 8);  // padded CSR
    unsigned* mbuf = (unsigned*)alloc((size_t)NN * HD * 2);
    unsigned* hA = (unsigned*)alloc((size_t)NN * HD * 2);
    unsigned* hB = (unsigned*)alloc((size_t)NN * HD * 2);
    unsigned* wbf = (unsigned*)alloc((size_t)NWFU * 4);
    float* stats = (float*)alloc(4 * 2 * HD * 4);
    float* ppool = (float*)alloc((size_t)NGR * PP * HD * 4);
    int* gstart = (int*)alloc((NGR + 1) * 4);
    int* bsum = (int*)alloc(SCB * 4);
    int* boff = (int*)alloc((SCB + 1) * 4);

    k_init<<<(NN + 255) / 256, 256, 0, stream>>>(fill, stats, conv_ws, wbf);
    k_pos<<<(NE + 255) / 256, 256, 0, stream>>>(ei, fill, pos);
    k_scan1<<<SCB, SCT, 0, stream>>>(fill, bsum);
    k_scan2_gb<<<2, SCB, 0, stream>>>(bsum, boff, batch, gstart);
    k_scan3<<<SCB, SCT, 0, stream>>>(fill, boff, col_ptr);
    k_scatter<<<(NE + 255) / 256, 256, 0, stream>>>(ei, ea, col_ptr, pos, sw);
    k_degsum<<<(NN + 255) / 256, 256, 0, stream>>>(col_ptr, fill, sw, dinv);

    float* st0 = stats;
    float* st1 = stats + 2 * HD;
    float* st2 = stats + 4 * HD;
    float* st3 = stats + 6 * HD;
    const int NG128 = (NN + BM - 1) / BM;
    const uint4* wf = (const uint4*)wbf;  // 2048 uint4 per layer

    // L0 (agg fuses weight normalization; writes normalized w back to sw)
    k_gemm0<<<(NN + 3) / 4, 256, 0, stream>>>(x, conv0_w, mbuf);
    k_agg<true><<<(NN + 3) / 4, 256, 0, stream>>>(mbuf, col_ptr, sw, dinv, conv0_b, hA);
    k_bnstats<<<256, 256, 0, stream>>>(hA, st0);
    // L1
    k_gemm128<<<NG128, 256, 0, stream>>>(hA, st0, bn_gamma, bn_beta, wf,
                                         (unsigned short*)mbuf);
    k_agg<false><<<(NN + 3) / 4, 256, 0, stream>>>(mbuf, col_ptr, sw, dinv, conv_bs, hB);
    k_bnstats<<<256, 256, 0, stream>>>(hB, st1);
    // L2
    k_gemm128<<<NG128, 256, 0, stream>>>(hB, st1, bn_gamma + HD, bn_beta + HD, wf + 2048,
                                         (unsigned short*)mbuf);
    k_agg<false><<<(NN + 3) / 4, 256, 0, stream>>>(mbuf, col_ptr, sw, dinv, conv_bs + HD, hA);
    k_bnstats<<<256, 256, 0, stream>>>(hA, st2);
    // L3
    k_gemm128<<<NG128, 256, 0, stream>>>(hA, st2, bn_gamma + 2 * HD, bn_beta + 2 * HD,
                                         wf + 4096, (unsigned short*)mbuf);
    k_agg<false><<<(NN + 3) / 4, 256, 0, stream>>>(mbuf, col_ptr, sw, dinv,
                                                   conv_bs + 2 * HD, hB);
    k_bnstats<<<256, 256, 0, stream>>>(hB, st3);
    // fused final BN+SiLU + pool + head
    k_poolp<<<NGR * PP, 256, 0, stream>>>(hB, st3, bn_gamma + 3 * HD, bn_beta + 3 * HD,
                                          gstart, ppool);
    k_pool_head<<<NGR, HD, 0, stream>>>(ppool, gstart, fc1w, fc1b, fc2w, fc2b, out);
}

// Round 14
// 268.115 us; speedup vs baseline: 10.4644x; 1.1298x over previous
//
#include <hip/hip_runtime.h>

#define NN 50000
#define NE 500000
#define NGR 64
#define HD 128
#define INF 5
#define BN_EPS 1e-5f
#define BM 64
#define SCB 128
#define SCT 256
#define SCH ((NN + SCB - 1) / SCB)
#define PP 16             // pooling parts per graph
#define NWFU (3 * 8 * 4 * 64 * 4)  // wfrag uints: L*t*s*lane*4
#define PAD8(c) (((c) + 7) & ~7)
#define AGB 512           // agg blocks
#define AGW (AGB * 16)    // agg waves total

typedef __attribute__((ext_vector_type(8))) short short8v;
typedef __attribute__((ext_vector_type(4))) float f32x4;

// ---------- bf16 helpers ----------
__device__ __forceinline__ float bflo(unsigned u) { return __uint_as_float(u << 16); }
__device__ __forceinline__ float bfhi(unsigned u) { return __uint_as_float(u & 0xffff0000u); }
__device__ __forceinline__ unsigned bfpack(float a, float b) {
    unsigned ua = __float_as_uint(a), ub = __float_as_uint(b);
    ua = (ua + 0x7fffu + ((ua >> 16) & 1u)) >> 16;
    ub = (ub + 0x7fffu + ((ub >> 16) & 1u)) >> 16;
    return ua | (ub << 16);
}
__device__ __forceinline__ unsigned short bf1(float a) {
    unsigned ua = __float_as_uint(a);
    return (unsigned short)((ua + 0x7fffu + ((ua >> 16) & 1u)) >> 16);
}

// ---------- init: fill=0, stats=0, pack conv weights into MFMA B-fragment order ----------
__global__ void k_init(int* fill, float* stats, const float* __restrict__ conv_ws,
                       unsigned* __restrict__ wbf) {
    int i = blockIdx.x * 256 + threadIdx.x;
    if (i < NN) fill[i] = 0;
    if (i < 4 * 2 * HD) stats[i] = 0.f;
    if (i < NWFU) {
        int inner = i & 3;
        int u4 = i >> 2;
        int lane = u4 & 63;
        int rest = u4 >> 6;
        int s = rest & 3, tt = (rest >> 2) & 7, L = rest >> 5;
        int col = tt * 16 + (lane & 15);
        int k = s * 32 + (lane >> 4) * 8 + inner * 2;
        const float* Wl = conv_ws + (size_t)L * HD * HD;
        wbf[i] = bfpack(Wl[k * HD + col], Wl[(k + 1) * HD + col]);
    }
}

// ---------- pass A: per-edge bucket position (the ONLY atomic pass) ----------
__global__ void k_pos(const int* __restrict__ ei, int* __restrict__ fill,
                      int* __restrict__ pos) {
    int e = blockIdx.x * 256 + threadIdx.x;
    if (e < NE) pos[e] = atomicAdd(&fill[ei[NE + e]], 1);
}

// ---------- hierarchical scan of PADDED fill -> col_ptr ----------
__global__ void k_scan1(const int* __restrict__ cnt, int* __restrict__ bsum) {
    __shared__ int sm[SCT];
    int b = blockIdx.x, t = threadIdx.x;
    int lo = b * SCH, hi = min(lo + SCH, NN);
    int s = 0;
    for (int i = lo + t; i < hi; i += SCT) s += PAD8(cnt[i]);
    sm[t] = s;
    __syncthreads();
    for (int off = SCT / 2; off > 0; off >>= 1) {
        if (t < off) sm[t] += sm[t + off];
        __syncthreads();
    }
    if (t == 0) bsum[b] = sm[0];
}

// block 0: scan of block sums; block 1: graph boundaries
__global__ void k_scan2_gb(const int* __restrict__ bsum, int* __restrict__ boff,
                           const int* __restrict__ batch, int* __restrict__ gstart) {
    int t = threadIdx.x;  // 128
    if (blockIdx.x == 1) {
        int g = t;
        if (g > NGR) return;
        int lo = 0, hi = NN;
        while (lo < hi) {
            int mid = (lo + hi) >> 1;
            if (batch[mid] < g) lo = mid + 1;
            else hi = mid;
        }
        gstart[g] = lo;
        return;
    }
    __shared__ int sm[SCB];
    sm[t] = bsum[t];
    __syncthreads();
    for (int off = 1; off < SCB; off <<= 1) {
        int v = (t >= off) ? sm[t - off] : 0;
        __syncthreads();
        sm[t] += v;
        __syncthreads();
    }
    boff[t] = (t == 0) ? 0 : sm[t - 1];
    if (t == SCB - 1) boff[SCB] = sm[SCB - 1];
}

__global__ void k_scan3(const int* __restrict__ cnt, const int* __restrict__ boff,
                        int* __restrict__ col_ptr) {
    __shared__ int sm[SCT];
    int b = blockIdx.x, t = threadIdx.x;
    int lo = b * SCH, hi = min(lo + SCH, NN);
    int e0 = lo + 2 * t, e1 = e0 + 1;
    int c0 = (e0 < hi) ? PAD8(cnt[e0]) : 0;
    int c1 = (e1 < hi) ? PAD8(cnt[e1]) : 0;
    sm[t] = c0 + c1;
    __syncthreads();
    for (int off = 1; off < SCT; off <<= 1) {
        int v = (t >= off) ? sm[t - off] : 0;
        __syncthreads();
        sm[t] += v;
        __syncthreads();
    }
    int base = boff[b] + ((t == 0) ? 0 : sm[t - 1]);
    if (e0 < hi) col_ptr[e0] = base;
    if (e1 < hi) col_ptr[e1] = base + c0;
    if (b == SCB - 1 && t == SCT - 1) col_ptr[NN] = boff[SCB];
}

// ---------- pass B: scatter {src, ea} as int2, no atomics ----------
__global__ void k_scatter(const int* __restrict__ ei, const float* __restrict__ ea,
                          const int* __restrict__ col_ptr, const int* __restrict__ pos,
                          int2* __restrict__ sw) {
    int e = blockIdx.x * 256 + threadIdx.x;
    if (e >= NE) return;
    int c = ei[NE + e];
    int p = col_ptr[c] + pos[e];
    sw[p] = make_int2(ei[e], __float_as_int(ea[e]));
}

// ---------- weighted degree (real count) + write zero pads ----------
__global__ void k_degsum(const int* __restrict__ col_ptr, const int* __restrict__ cnt,
                         int2* __restrict__ sw, float* __restrict__ dinv) {
    int i = blockIdx.x * 256 + threadIdx.x;
    if (i >= NN) return;
    int beg = col_ptr[i], mid = beg + cnt[i], end = col_ptr[i + 1];
    float s = 1.0f;  // self-loop weight
    for (int p = beg; p < mid; p++) s += __int_as_float(sw[p].y);
    for (int p = mid; p < end; p++) sw[p] = make_int2(0, 0);  // pad: src=0, w=0
    dinv[i] = rsqrtf(s);
}

// ---------- layer-0 transform: m = x @ W0 (K=5), bf16 output ----------
__global__ void k_gemm0(const float* __restrict__ x, const float* __restrict__ W,
                        unsigned* __restrict__ m32) {
    __shared__ float Ws[INF][HD];
    int t = threadIdx.x;  // 256
    for (int i = t; i < INF * HD; i += 256) ((float*)Ws)[i] = W[i];
    __syncthreads();
    int row = blockIdx.x * 4 + (t >> 6);
    if (row >= NN) return;
    int lane = t & 63;
    int c0 = 2 * lane;
    float xv[INF];
#pragma unroll
    for (int k = 0; k < INF; k++) xv[k] = x[row * INF + k];
    float a0 = 0.f, a1 = 0.f;
#pragma unroll
    for (int k = 0; k < INF; k++) {
        a0 += xv[k] * Ws[k][c0];
        a1 += xv[k] * Ws[k][c0 + 1];
    }
    m32[(size_t)row * 64 + lane] = bfpack(a0, a1);
}

// ---------- fused BN(prev)+SiLU + MFMA GEMM ----------
__global__ __launch_bounds__(256) void k_gemm128(
    const unsigned* __restrict__ h32, const float* __restrict__ stats,
    const float* __restrict__ gamma, const float* __restrict__ beta,
    const uint4* __restrict__ wfrag, unsigned short* __restrict__ m16) {
    __shared__ __align__(16) unsigned hs[64 * 64];  // 16 KB packed bf16
    __shared__ float sc[HD], sh[HD];
    int t = threadIdx.x;
    int r0 = blockIdx.x * BM;
    const float invn = 1.0f / NN;

    if (t < HD) {
        float mu = stats[t] * invn;
        float var = stats[HD + t] * invn - mu * mu;
        float s = gamma[t] * rsqrtf(var + BN_EPS);
        sc[t] = s;
        sh[t] = beta[t] - mu * s;
    }
    __syncthreads();

#pragma unroll
    for (int j = 0; j < 8; j++) {
        int g = j * 256 + t;      // uint2 slot 0..2047
        int r = g >> 5;           // row 0..63
        int u2 = g & 31;          // uint2 within row
        uint2 v = make_uint2(0u, 0u);
        if (r0 + r < NN) v = ((const uint2*)h32)[(size_t)(r0 + r) * 32 + u2];
        int c = u2 * 4;
        float y0 = sc[c] * bflo(v.x) + sh[c];
        float y1 = sc[c + 1] * bfhi(v.x) + sh[c + 1];
        float y2 = sc[c + 2] * bflo(v.y) + sh[c + 2];
        float y3 = sc[c + 3] * bfhi(v.y) + sh[c + 3];
        y0 = y0 / (1.f + __expf(-y0));
        y1 = y1 / (1.f + __expf(-y1));
        y2 = y2 / (1.f + __expf(-y2));
        y3 = y3 / (1.f + __expf(-y3));
        int slot = u2 >> 1, inner = (u2 & 1) * 2;
        int addr = r * 64 + ((slot ^ (r & 7)) << 2) + inner;
        hs[addr] = bfpack(y0, y1);
        hs[addr + 1] = bfpack(y2, y3);
    }
    __syncthreads();

    int w = t >> 6, l = t & 63;
    int lr = l & 15, lg = l >> 4;
    f32x4 acc[8];
#pragma unroll
    for (int i = 0; i < 8; i++) acc[i] = (f32x4){0.f, 0.f, 0.f, 0.f};

#pragma unroll
    for (int s = 0; s < 4; s++) {  // K steps of 32
        int arow = w * 16 + lr;
        int q = s * 4 + lg;
        short8v af = *reinterpret_cast<const short8v*>(
            &hs[arow * 64 + ((q ^ (arow & 7)) << 2)]);
#pragma unroll
        for (int tt = 0; tt < 8; tt++) {
            short8v bf = *reinterpret_cast<const short8v*>(&wfrag[(tt * 4 + s) * 64 + l]);
            acc[tt] = __builtin_amdgcn_mfma_f32_16x16x32_bf16(af, bf, acc[tt], 0, 0, 0);
        }
    }

    int baserow = r0 + w * 16 + lg * 4;
#pragma unroll
    for (int tt = 0; tt < 8; tt++) {
        int col = tt * 16 + lr;
#pragma unroll
        for (int reg = 0; reg < 4; reg++) {
            int row = baserow + reg;
            if (row < NN) m16[(size_t)row * HD + col] = bf1(acc[tt][reg]);
        }
    }
}

// ---------- sparse aggregation + fused BN stats ----------
// Grid-stride: AGB blocks x 16 waves, one node per wave per iteration.
// Per-lane stat accumulators (2 channels) -> 16-wave LDS combine -> 256 atomics/block.
template <bool NORM>
__global__ __launch_bounds__(1024, 8) void k_agg(
    const unsigned* __restrict__ m32, const int* __restrict__ col_ptr,
    int2* __restrict__ sw, const float* __restrict__ dinv,
    const float* __restrict__ bias, unsigned* __restrict__ hpre32,
    float* __restrict__ stats) {
    int t = threadIdx.x;
    int w = t >> 6, lane = t & 63;
    int gwave = blockIdx.x * 16 + w;
    float2 b = ((const float2*)bias)[lane];
    float ss0 = 0.f, ss1 = 0.f, sq0 = 0.f, sq1 = 0.f;

    for (int node = gwave; node < NN; node += AGW) {
        float di = dinv[node];
        unsigned sv = m32[(size_t)node * 64 + lane];
        float a0 = di * di * bflo(sv);
        float a1 = di * di * bfhi(sv);
        int beg = col_ptr[node], end = col_ptr[node + 1];  // both 8-aligned
        for (int p = beg; p < end; p += 8) {
            int2 e0 = sw[p], e1 = sw[p + 1], e2 = sw[p + 2], e3 = sw[p + 3];
            int2 e4 = sw[p + 4], e5 = sw[p + 5], e6 = sw[p + 6], e7 = sw[p + 7];
            int s0 = __builtin_amdgcn_readfirstlane(e0.x);
            int s1 = __builtin_amdgcn_readfirstlane(e1.x);
            int s2 = __builtin_amdgcn_readfirstlane(e2.x);
            int s3 = __builtin_amdgcn_readfirstlane(e3.x);
            int s4 = __builtin_amdgcn_readfirstlane(e4.x);
            int s5 = __builtin_amdgcn_readfirstlane(e5.x);
            int s6 = __builtin_amdgcn_readfirstlane(e6.x);
            int s7 = __builtin_amdgcn_readfirstlane(e7.x);
            unsigned v0 = m32[(size_t)s0 * 64 + lane];
            unsigned v1 = m32[(size_t)s1 * 64 + lane];
            unsigned v2 = m32[(size_t)s2 * 64 + lane];
            unsigned v3 = m32[(size_t)s3 * 64 + lane];
            unsigned v4 = m32[(size_t)s4 * 64 + lane];
            unsigned v5 = m32[(size_t)s5 * 64 + lane];
            unsigned v6 = m32[(size_t)s6 * 64 + lane];
            unsigned v7 = m32[(size_t)s7 * 64 + lane];
            float w0 = __int_as_float(__builtin_amdgcn_readfirstlane(e0.y));
            float w1 = __int_as_float(__builtin_amdgcn_readfirstlane(e1.y));
            float w2 = __int_as_float(__builtin_amdgcn_readfirstlane(e2.y));
            float w3 = __int_as_float(__builtin_amdgcn_readfirstlane(e3.y));
            float w4 = __int_as_float(__builtin_amdgcn_readfirstlane(e4.y));
            float w5 = __int_as_float(__builtin_amdgcn_readfirstlane(e5.y));
            float w6 = __int_as_float(__builtin_amdgcn_readfirstlane(e6.y));
            float w7 = __int_as_float(__builtin_amdgcn_readfirstlane(e7.y));
            if (NORM) {
                w0 = dinv[s0] * w0 * di;
                w1 = dinv[s1] * w1 * di;
                w2 = dinv[s2] * w2 * di;
                w3 = dinv[s3] * w3 * di;
                w4 = dinv[s4] * w4 * di;
                w5 = dinv[s5] * w5 * di;
                w6 = dinv[s6] * w6 * di;
                w7 = dinv[s7] * w7 * di;
                if (lane == 0) {  // write normalized weights back for layers 1..3
                    sw[p].y = __float_as_int(w0);
                    sw[p + 1].y = __float_as_int(w1);
                    sw[p + 2].y = __float_as_int(w2);
                    sw[p + 3].y = __float_as_int(w3);
                    sw[p + 4].y = __float_as_int(w4);
                    sw[p + 5].y = __float_as_int(w5);
                    sw[p + 6].y = __float_as_int(w6);
                    sw[p + 7].y = __float_as_int(w7);
                }
            }
            a0 += w0 * bflo(v0) + w1 * bflo(v1) + w2 * bflo(v2) + w3 * bflo(v3);
            a1 += w0 * bfhi(v0) + w1 * bfhi(v1) + w2 * bfhi(v2) + w3 * bfhi(v3);
            a0 += w4 * bflo(v4) + w5 * bflo(v5) + w6 * bflo(v6) + w7 * bflo(v7);
            a1 += w4 * bfhi(v4) + w5 * bfhi(v5) + w6 * bfhi(v6) + w7 * bfhi(v7);
        }
        unsigned pk = bfpack(a0 + b.x, a1 + b.y);
        hpre32[(size_t)node * 64 + lane] = pk;
        float r0 = bflo(pk), r1 = bfhi(pk);
        ss0 += r0; sq0 += r0 * r0;
        ss1 += r1; sq1 += r1 * r1;
    }

    // fused BN stats: 16-wave LDS combine, then one atomic per stat slot
    __shared__ float lsum[16][HD];
    __shared__ float lsqr[16][HD];
    lsum[w][2 * lane] = ss0;
    lsum[w][2 * lane + 1] = ss1;
    lsqr[w][2 * lane] = sq0;
    lsqr[w][2 * lane + 1] = sq1;
    __syncthreads();
    if (t < HD) {
        float s = 0.f;
#pragma unroll
        for (int i = 0; i < 16; i++) s += lsum[i][t];
        atomicAdd(&stats[t], s);
    } else if (t < 2 * HD) {
        int c = t - HD;
        float q = 0.f;
#pragma unroll
        for (int i = 0; i < 16; i++) q += lsqr[i][c];
        atomicAdd(&stats[HD + c], q);
    }
}

// ---------- pooling stage 1 (fused final BN+SiLU), bf16 input ----------
__global__ void k_poolp(const unsigned* __restrict__ h32, const float* __restrict__ stats,
                        const float* __restrict__ gamma, const float* __restrict__ beta,
                        const int* __restrict__ gstart, float* __restrict__ ppool) {
    int g = blockIdx.x / PP, p = blockIdx.x % PP;
    int t = threadIdx.x;          // 256
    int c4 = t & 31;              // 4-channel group
    int ro = t >> 5;
    const float invn = 1.0f / NN;
    float sc[4], sh[4];
#pragma unroll
    for (int q = 0; q < 4; q++) {
        int c = c4 * 4 + q;
        float mu = stats[c] * invn;
        float var = stats[HD + c] * invn - mu * mu;
        float s = gamma[c] * rsqrtf(var + BN_EPS);
        sc[q] = s;
        sh[q] = beta[c] - mu * s;
    }
    int beg = gstart[g], end = gstart[g + 1];
    const uint2* h2 = (const uint2*)h32;
    float4 acc = make_float4(0.f, 0.f, 0.f, 0.f);
    for (int r = beg + p * 8 + ro; r < end; r += PP * 8) {
        uint2 u = h2[(size_t)r * 32 + c4];
        float vals[4] = {bflo(u.x), bfhi(u.x), bflo(u.y), bfhi(u.y)};
#pragma unroll
        for (int q = 0; q < 4; q++) {
            float y = sc[q] * vals[q] + sh[q];
            (&acc.x)[q] += y / (1.f + __expf(-y));
        }
    }
    __shared__ float4 sm[256];
    sm[t] = acc;
    __syncthreads();
    if (t < 128) {
        float4 o = sm[t + 128];
        sm[t].x += o.x; sm[t].y += o.y; sm[t].z += o.z; sm[t].w += o.w;
    }
    __syncthreads();
    if (t < 64) {
        float4 o = sm[t + 64];
        sm[t].x += o.x; sm[t].y += o.y; sm[t].z += o.z; sm[t].w += o.w;
    }
    __syncthreads();
    if (t < 32) {
        float4 o = sm[t + 32];
        float4 r = sm[t];
        r.x += o.x; r.y += o.y; r.z += o.z; r.w += o.w;
        ((float4*)ppool)[(size_t)blockIdx.x * 32 + t] = r;
    }
}

// ---------- pooling stage 2 + head MLP fused ----------
__global__ void k_pool_head(const float* __restrict__ ppool, const int* __restrict__ gstart,
                            const float* __restrict__ fc1w, const float* __restrict__ fc1b,
                            const float* __restrict__ fc2w, const float* __restrict__ fc2b,
                            float* __restrict__ out) {
    int g = blockIdx.x;
    int t = threadIdx.x;  // 128
    __shared__ float pa[HD];
    float s = 0.f;
    for (int p = 0; p < PP; p++) s += ppool[(size_t)(g * PP + p) * HD + t];
    float cnt = (float)(gstart[g + 1] - gstart[g]);
    pa[t] = s / fmaxf(cnt, 1.0f);
    __syncthreads();
    if (t < 64) {
        float a = fc1b[t];
        for (int k = 0; k < HD; k++) a += pa[k] * fc1w[k * 64 + t];
        a = a / (1.f + __expf(-a));  // SiLU
        float v = a * fc2w[t];
        for (int off = 32; off > 0; off >>= 1) v += __shfl_down(v, off);
        if (t == 0) out[g] = 1.f / (1.f + __expf(-(v + fc2b[0])));
    }
}

extern "C" void kernel_launch(void* const* d_in, const int* in_sizes, int n_in,
                              void* d_out, int out_size, void* d_ws, size_t ws_size,
                              hipStream_t stream) {
    const float* x = (const float*)d_in[0];
    const int* ei = (const int*)d_in[1];  // [2, E]: row=ei[0..E), col=ei[E..2E)
    const float* ea = (const float*)d_in[2];
    const int* batch = (const int*)d_in[3];
    const float* conv0_w = (const float*)d_in[5];
    const float* conv0_b = (const float*)d_in[6];
    const float* conv_ws = (const float*)d_in[7];
    const float* conv_bs = (const float*)d_in[8];
    const float* bn_gamma = (const float*)d_in[9];
    const float* bn_beta = (const float*)d_in[10];
    const float* fc1w = (const float*)d_in[11];
    const float* fc1b = (const float*)d_in[12];
    const float* fc2w = (const float*)d_in[13];
    const float* fc2b = (const float*)d_in[14];
    float* out = (float*)d_out;

    char* ws = (char*)d_ws;
    size_t off = 0;
    auto alloc = [&](size_t bytes) -> char* {
        char* p = ws + off;
        off = (off + bytes + 255) & ~(size_t)255;
        return p;
    };
    float* dinv = (float*)alloc(NN * 4);
    int* fill = (int*)alloc(NN * 4);
    int* col_ptr = (int*)alloc((NN + 1) * 4);
    int* pos = (int*)alloc(NE * 4);
    int2* sw = (int2*)alloc(((size_t)NE + 8 * NN) * 8);  // padded CSR
    unsigned* mbuf = (unsigned*)alloc((size_t)NN * HD * 2);
    unsigned* hA = (unsigned*)alloc((size_t)NN * HD * 2);
    unsigned* hB = (unsigned*)alloc((size_t)NN * HD * 2);
    unsigned* wbf = (unsigned*)alloc((size_t)NWFU * 4);
    float* stats = (float*)alloc(4 * 2 * HD * 4);
    float* ppool = (float*)alloc((size_t)NGR * PP * HD * 4);
    int* gstart = (int*)alloc((NGR + 1) * 4);
    int* bsum = (int*)alloc(SCB * 4);
    int* boff = (int*)alloc((SCB + 1) * 4);

    k_init<<<(NN + 255) / 256, 256, 0, stream>>>(fill, stats, conv_ws, wbf);
    k_pos<<<(NE + 255) / 256, 256, 0, stream>>>(ei, fill, pos);
    k_scan1<<<SCB, SCT, 0, stream>>>(fill, bsum);
    k_scan2_gb<<<2, SCB, 0, stream>>>(bsum, boff, batch, gstart);
    k_scan3<<<SCB, SCT, 0, stream>>>(fill, boff, col_ptr);
    k_scatter<<<(NE + 255) / 256, 256, 0, stream>>>(ei, ea, col_ptr, pos, sw);
    k_degsum<<<(NN + 255) / 256, 256, 0, stream>>>(col_ptr, fill, sw, dinv);

    float* st0 = stats;
    float* st1 = stats + 2 * HD;
    float* st2 = stats + 4 * HD;
    float* st3 = stats + 6 * HD;
    const int NG128 = (NN + BM - 1) / BM;
    const uint4* wf = (const uint4*)wbf;  // 2048 uint4 per layer

    // L0 (agg fuses weight normalization + BN0 stats)
    k_gemm0<<<(NN + 3) / 4, 256, 0, stream>>>(x, conv0_w, mbuf);
    k_agg<true><<<AGB, 1024, 0, stream>>>(mbuf, col_ptr, sw, dinv, conv0_b, hA, st0);
    // L1
    k_gemm128<<<NG128, 256, 0, stream>>>(hA, st0, bn_gamma, bn_beta, wf,
                                         (unsigned short*)mbuf);
    k_agg<false><<<AGB, 1024, 0, stream>>>(mbuf, col_ptr, sw, dinv, conv_bs, hB, st1);
    // L2
    k_gemm128<<<NG128, 256, 0, stream>>>(hB, st1, bn_gamma + HD, bn_beta + HD, wf + 2048,
                                         (unsigned short*)mbuf);
    k_agg<false><<<AGB, 1024, 0, stream>>>(mbuf, col_ptr, sw, dinv, conv_bs + HD, hA, st2);
    // L3
    k_gemm128<<<NG128, 256, 0, stream>>>(hA, st2, bn_gamma + 2 * HD, bn_beta + 2 * HD,
                                         wf + 4096, (unsigned short*)mbuf);
    k_agg<false><<<AGB, 1024, 0, stream>>>(mbuf, col_ptr, sw, dinv, conv_bs + 2 * HD, hB,
                                           st3);
    // fused final BN+SiLU + pool + head
    k_poolp<<<NGR * PP, 256, 0, stream>>>(hB, st3, bn_gamma + 3 * HD, bn_beta + 3 * HD,
                                          gstart, ppool);
    k_pool_head<<<NGR, HD, 0, stream>>>(ppool, gstart, fc1w, fc1b, fc2w, fc2b, out);
}

// Round 15
// 265.147 us; speedup vs baseline: 10.5815x; 1.0112x over previous
//
#include <hip/hip_runtime.h>

#define NN 50000
#define NE 500000
#define NGR 64
#define HD 128
#define INF 5
#define BN_EPS 1e-5f
#define BM 64
#define SCB 128
#define SCT 256
#define SCH ((NN + SCB - 1) / SCB)
#define PP 16             // pooling parts per graph
#define NWFU (3 * 8 * 4 * 64 * 4)  // wfrag uints: L*t*s*lane*4
#define PAD8(c) (((c) + 7) & ~7)
#define AGB 512           // agg blocks
#define AGW (AGB * 16)    // agg waves total

typedef __attribute__((ext_vector_type(8))) short short8v;
typedef __attribute__((ext_vector_type(4))) float f32x4;

// ---------- bf16 helpers ----------
__device__ __forceinline__ float bflo(unsigned u) { return __uint_as_float(u << 16); }
__device__ __forceinline__ float bfhi(unsigned u) { return __uint_as_float(u & 0xffff0000u); }
__device__ __forceinline__ unsigned bfpack(float a, float b) {
    unsigned ua = __float_as_uint(a), ub = __float_as_uint(b);
    ua = (ua + 0x7fffu + ((ua >> 16) & 1u)) >> 16;
    ub = (ub + 0x7fffu + ((ub >> 16) & 1u)) >> 16;
    return ua | (ub << 16);
}
__device__ __forceinline__ unsigned short bf1(float a) {
    unsigned ua = __float_as_uint(a);
    return (unsigned short)((ua + 0x7fffu + ((ua >> 16) & 1u)) >> 16);
}

// ---------- init: fill=0, stats=0, pack conv weights into MFMA B-fragment order ----------
__global__ void k_init(int* fill, float* stats, const float* __restrict__ conv_ws,
                       unsigned* __restrict__ wbf) {
    int i = blockIdx.x * 256 + threadIdx.x;
    if (i < NN) fill[i] = 0;
    if (i < 4 * 2 * HD) stats[i] = 0.f;
    if (i < NWFU) {
        int inner = i & 3;
        int u4 = i >> 2;
        int lane = u4 & 63;
        int rest = u4 >> 6;
        int s = rest & 3, tt = (rest >> 2) & 7, L = rest >> 5;
        int col = tt * 16 + (lane & 15);
        int k = s * 32 + (lane >> 4) * 8 + inner * 2;
        const float* Wl = conv_ws + (size_t)L * HD * HD;
        wbf[i] = bfpack(Wl[k * HD + col], Wl[(k + 1) * HD + col]);
    }
}

// ---------- pass A: per-edge bucket position (the ONLY atomic pass) ----------
__global__ void k_pos(const int* __restrict__ ei, int* __restrict__ fill,
                      int* __restrict__ pos) {
    int e = blockIdx.x * 256 + threadIdx.x;
    if (e < NE) pos[e] = atomicAdd(&fill[ei[NE + e]], 1);
}

// ---------- hierarchical scan of PADDED fill -> col_ptr ----------
__global__ void k_scan1(const int* __restrict__ cnt, int* __restrict__ bsum) {
    __shared__ int sm[SCT];
    int b = blockIdx.x, t = threadIdx.x;
    int lo = b * SCH, hi = min(lo + SCH, NN);
    int s = 0;
    for (int i = lo + t; i < hi; i += SCT) s += PAD8(cnt[i]);
    sm[t] = s;
    __syncthreads();
    for (int off = SCT / 2; off > 0; off >>= 1) {
        if (t < off) sm[t] += sm[t + off];
        __syncthreads();
    }
    if (t == 0) bsum[b] = sm[0];
}

// block 0: scan of block sums; block 1: graph boundaries
__global__ void k_scan2_gb(const int* __restrict__ bsum, int* __restrict__ boff,
                           const int* __restrict__ batch, int* __restrict__ gstart) {
    int t = threadIdx.x;  // 128
    if (blockIdx.x == 1) {
        int g = t;
        if (g > NGR) return;
        int lo = 0, hi = NN;
        while (lo < hi) {
            int mid = (lo + hi) >> 1;
            if (batch[mid] < g) lo = mid + 1;
            else hi = mid;
        }
        gstart[g] = lo;
        return;
    }
    __shared__ int sm[SCB];
    sm[t] = bsum[t];
    __syncthreads();
    for (int off = 1; off < SCB; off <<= 1) {
        int v = (t >= off) ? sm[t - off] : 0;
        __syncthreads();
        sm[t] += v;
        __syncthreads();
    }
    boff[t] = (t == 0) ? 0 : sm[t - 1];
    if (t == SCB - 1) boff[SCB] = sm[SCB - 1];
}

__global__ void k_scan3(const int* __restrict__ cnt, const int* __restrict__ boff,
                        int* __restrict__ col_ptr) {
    __shared__ int sm[SCT];
    int b = blockIdx.x, t = threadIdx.x;
    int lo = b * SCH, hi = min(lo + SCH, NN);
    int e0 = lo + 2 * t, e1 = e0 + 1;
    int c0 = (e0 < hi) ? PAD8(cnt[e0]) : 0;
    int c1 = (e1 < hi) ? PAD8(cnt[e1]) : 0;
    sm[t] = c0 + c1;
    __syncthreads();
    for (int off = 1; off < SCT; off <<= 1) {
        int v = (t >= off) ? sm[t - off] : 0;
        __syncthreads();
        sm[t] += v;
        __syncthreads();
    }
    int base = boff[b] + ((t == 0) ? 0 : sm[t - 1]);
    if (e0 < hi) col_ptr[e0] = base;
    if (e1 < hi) col_ptr[e1] = base + c0;
    if (b == SCB - 1 && t == SCT - 1) col_ptr[NN] = boff[SCB];
}

// ---------- pass B: scatter {src, ea} as int2, no atomics ----------
__global__ void k_scatter(const int* __restrict__ ei, const float* __restrict__ ea,
                          const int* __restrict__ col_ptr, const int* __restrict__ pos,
                          int2* __restrict__ sw) {
    int e = blockIdx.x * 256 + threadIdx.x;
    if (e >= NE) return;
    int c = ei[NE + e];
    int p = col_ptr[c] + pos[e];
    sw[p] = make_int2(ei[e], __float_as_int(ea[e]));
}

// ---------- weighted degree (real count) + write zero pads ----------
__global__ void k_degsum(const int* __restrict__ col_ptr, const int* __restrict__ cnt,
                         int2* __restrict__ sw, float* __restrict__ dinv) {
    int i = blockIdx.x * 256 + threadIdx.x;
    if (i >= NN) return;
    int beg = col_ptr[i], mid = beg + cnt[i], end = col_ptr[i + 1];
    float s = 1.0f;  // self-loop weight
    for (int p = beg; p < mid; p++) s += __int_as_float(sw[p].y);
    for (int p = mid; p < end; p++) sw[p] = make_int2(0, 0);  // pad: src=0, w=0
    dinv[i] = rsqrtf(s);
}

// ---------- layer-0 transform: m = x @ W0 (K=5), bf16 output ----------
__global__ void k_gemm0(const float* __restrict__ x, const float* __restrict__ W,
                        unsigned* __restrict__ m32) {
    __shared__ float Ws[INF][HD];
    int t = threadIdx.x;  // 256
    for (int i = t; i < INF * HD; i += 256) ((float*)Ws)[i] = W[i];
    __syncthreads();
    int row = blockIdx.x * 4 + (t >> 6);
    if (row >= NN) return;
    int lane = t & 63;
    int c0 = 2 * lane;
    float xv[INF];
#pragma unroll
    for (int k = 0; k < INF; k++) xv[k] = x[row * INF + k];
    float a0 = 0.f, a1 = 0.f;
#pragma unroll
    for (int k = 0; k < INF; k++) {
        a0 += xv[k] * Ws[k][c0];
        a1 += xv[k] * Ws[k][c0 + 1];
    }
    m32[(size_t)row * 64 + lane] = bfpack(a0, a1);
}

// ---------- fused BN(prev)+SiLU + MFMA GEMM ----------
__global__ __launch_bounds__(256) void k_gemm128(
    const unsigned* __restrict__ h32, const float* __restrict__ stats,
    const float* __restrict__ gamma, const float* __restrict__ beta,
    const uint4* __restrict__ wfrag, unsigned short* __restrict__ m16) {
    __shared__ __align__(16) unsigned hs[64 * 64];  // 16 KB packed bf16
    __shared__ float sc[HD], sh[HD];
    int t = threadIdx.x;
    int r0 = blockIdx.x * BM;
    const float invn = 1.0f / NN;

    if (t < HD) {
        float mu = stats[t] * invn;
        float var = stats[HD + t] * invn - mu * mu;
        float s = gamma[t] * rsqrtf(var + BN_EPS);
        sc[t] = s;
        sh[t] = beta[t] - mu * s;
    }
    __syncthreads();

#pragma unroll
    for (int j = 0; j < 8; j++) {
        int g = j * 256 + t;      // uint2 slot 0..2047
        int r = g >> 5;           // row 0..63
        int u2 = g & 31;          // uint2 within row
        uint2 v = make_uint2(0u, 0u);
        if (r0 + r < NN) v = ((const uint2*)h32)[(size_t)(r0 + r) * 32 + u2];
        int c = u2 * 4;
        float y0 = sc[c] * bflo(v.x) + sh[c];
        float y1 = sc[c + 1] * bfhi(v.x) + sh[c + 1];
        float y2 = sc[c + 2] * bflo(v.y) + sh[c + 2];
        float y3 = sc[c + 3] * bfhi(v.y) + sh[c + 3];
        y0 = y0 / (1.f + __expf(-y0));
        y1 = y1 / (1.f + __expf(-y1));
        y2 = y2 / (1.f + __expf(-y2));
        y3 = y3 / (1.f + __expf(-y3));
        int slot = u2 >> 1, inner = (u2 & 1) * 2;
        int addr = r * 64 + ((slot ^ (r & 7)) << 2) + inner;
        hs[addr] = bfpack(y0, y1);
        hs[addr + 1] = bfpack(y2, y3);
    }
    __syncthreads();

    int w = t >> 6, l = t & 63;
    int lr = l & 15, lg = l >> 4;
    f32x4 acc[8];
#pragma unroll
    for (int i = 0; i < 8; i++) acc[i] = (f32x4){0.f, 0.f, 0.f, 0.f};

#pragma unroll
    for (int s = 0; s < 4; s++) {  // K steps of 32
        int arow = w * 16 + lr;
        int q = s * 4 + lg;
        short8v af = *reinterpret_cast<const short8v*>(
            &hs[arow * 64 + ((q ^ (arow & 7)) << 2)]);
#pragma unroll
        for (int tt = 0; tt < 8; tt++) {
            short8v bf = *reinterpret_cast<const short8v*>(&wfrag[(tt * 4 + s) * 64 + l]);
            acc[tt] = __builtin_amdgcn_mfma_f32_16x16x32_bf16(af, bf, acc[tt], 0, 0, 0);
        }
    }

    int baserow = r0 + w * 16 + lg * 4;
#pragma unroll
    for (int tt = 0; tt < 8; tt++) {
        int col = tt * 16 + lr;
#pragma unroll
        for (int reg = 0; reg < 4; reg++) {
            int row = baserow + reg;
            if (row < NN) m16[(size_t)row * HD + col] = bf1(acc[tt][reg]);
        }
    }
}

// ---------- sparse aggregation + fused BN stats: scalar edge records ----------
// beg/end/edge-records are wave-uniform -> SGPR path; gathers use saddr+lane.
template <bool NORM>
__global__ __launch_bounds__(1024, 8) void k_agg(
    const unsigned* __restrict__ m32, const int* __restrict__ col_ptr,
    int2* __restrict__ sw, const float* __restrict__ dinv,
    const float* __restrict__ bias, unsigned* __restrict__ hpre32,
    float* __restrict__ stats) {
    int t = threadIdx.x;
    int w = t >> 6, lane = t & 63;
    int gwave = blockIdx.x * 16 + w;
    float2 b = ((const float2*)bias)[lane];
    float ss0 = 0.f, ss1 = 0.f, sq0 = 0.f, sq1 = 0.f;

    for (int node = gwave; node < NN; node += AGW) {
        float di = dinv[node];
        unsigned sv = m32[(size_t)node * 64 + lane];
        float a0 = di * di * bflo(sv);
        float a1 = di * di * bfhi(sv);
        int beg = __builtin_amdgcn_readfirstlane(col_ptr[node]);
        int end = __builtin_amdgcn_readfirstlane(col_ptr[node + 1]);  // 8-aligned
        for (int p = beg; p < end; p += 8) {
            // 4 x int4 = 8 edge records from a wave-uniform address
            const int4* sp = (const int4*)(sw + p);
            int4 q0 = sp[0], q1 = sp[1], q2 = sp[2], q3 = sp[3];
            int s0 = __builtin_amdgcn_readfirstlane(q0.x);
            int s1 = __builtin_amdgcn_readfirstlane(q0.z);
            int s2 = __builtin_amdgcn_readfirstlane(q1.x);
            int s3 = __builtin_amdgcn_readfirstlane(q1.z);
            int s4 = __builtin_amdgcn_readfirstlane(q2.x);
            int s5 = __builtin_amdgcn_readfirstlane(q2.z);
            int s6 = __builtin_amdgcn_readfirstlane(q3.x);
            int s7 = __builtin_amdgcn_readfirstlane(q3.z);
            unsigned v0 = m32[(size_t)s0 * 64 + lane];
            unsigned v1 = m32[(size_t)s1 * 64 + lane];
            unsigned v2 = m32[(size_t)s2 * 64 + lane];
            unsigned v3 = m32[(size_t)s3 * 64 + lane];
            unsigned v4 = m32[(size_t)s4 * 64 + lane];
            unsigned v5 = m32[(size_t)s5 * 64 + lane];
            unsigned v6 = m32[(size_t)s6 * 64 + lane];
            unsigned v7 = m32[(size_t)s7 * 64 + lane];
            float w0 = __int_as_float(__builtin_amdgcn_readfirstlane(q0.y));
            float w1 = __int_as_float(__builtin_amdgcn_readfirstlane(q0.w));
            float w2 = __int_as_float(__builtin_amdgcn_readfirstlane(q1.y));
            float w3 = __int_as_float(__builtin_amdgcn_readfirstlane(q1.w));
            float w4 = __int_as_float(__builtin_amdgcn_readfirstlane(q2.y));
            float w5 = __int_as_float(__builtin_amdgcn_readfirstlane(q2.w));
            float w6 = __int_as_float(__builtin_amdgcn_readfirstlane(q3.y));
            float w7 = __int_as_float(__builtin_amdgcn_readfirstlane(q3.w));
            if (NORM) {
                w0 = dinv[s0] * w0 * di;
                w1 = dinv[s1] * w1 * di;
                w2 = dinv[s2] * w2 * di;
                w3 = dinv[s3] * w3 * di;
                w4 = dinv[s4] * w4 * di;
                w5 = dinv[s5] * w5 * di;
                w6 = dinv[s6] * w6 * di;
                w7 = dinv[s7] * w7 * di;
                if (lane == 0) {  // write normalized weights back for layers 1..3
                    sw[p].y = __float_as_int(w0);
                    sw[p + 1].y = __float_as_int(w1);
                    sw[p + 2].y = __float_as_int(w2);
                    sw[p + 3].y = __float_as_int(w3);
                    sw[p + 4].y = __float_as_int(w4);
                    sw[p + 5].y = __float_as_int(w5);
                    sw[p + 6].y = __float_as_int(w6);
                    sw[p + 7].y = __float_as_int(w7);
                }
            }
            a0 += w0 * bflo(v0) + w1 * bflo(v1) + w2 * bflo(v2) + w3 * bflo(v3);
            a1 += w0 * bfhi(v0) + w1 * bfhi(v1) + w2 * bfhi(v2) + w3 * bfhi(v3);
            a0 += w4 * bflo(v4) + w5 * bflo(v5) + w6 * bflo(v6) + w7 * bflo(v7);
            a1 += w4 * bfhi(v4) + w5 * bfhi(v5) + w6 * bfhi(v6) + w7 * bfhi(v7);
        }
        unsigned pk = bfpack(a0 + b.x, a1 + b.y);
        hpre32[(size_t)node * 64 + lane] = pk;
        float r0 = bflo(pk), r1 = bfhi(pk);
        ss0 += r0; sq0 += r0 * r0;
        ss1 += r1; sq1 += r1 * r1;
    }

    // fused BN stats: 16-wave LDS combine, then one atomic per stat slot
    __shared__ float lsum[16][HD];
    __shared__ float lsqr[16][HD];
    lsum[w][2 * lane] = ss0;
    lsum[w][2 * lane + 1] = ss1;
    lsqr[w][2 * lane] = sq0;
    lsqr[w][2 * lane + 1] = sq1;
    __syncthreads();
    if (t < HD) {
        float s = 0.f;
#pragma unroll
        for (int i = 0; i < 16; i++) s += lsum[i][t];
        atomicAdd(&stats[t], s);
    } else if (t < 2 * HD) {
        int c = t - HD;
        float q = 0.f;
#pragma unroll
        for (int i = 0; i < 16; i++) q += lsqr[i][c];
        atomicAdd(&stats[HD + c], q);
    }
}

// ---------- pooling stage 1 (fused final BN+SiLU), bf16 input ----------
__global__ void k_poolp(const unsigned* __restrict__ h32, const float* __restrict__ stats,
                        const float* __restrict__ gamma, const float* __restrict__ beta,
                        const int* __restrict__ gstart, float* __restrict__ ppool) {
    int g = blockIdx.x / PP, p = blockIdx.x % PP;
    int t = threadIdx.x;          // 256
    int c4 = t & 31;              // 4-channel group
    int ro = t >> 5;
    const float invn = 1.0f / NN;
    float sc[4], sh[4];
#pragma unroll
    for (int q = 0; q < 4; q++) {
        int c = c4 * 4 + q;
        float mu = stats[c] * invn;
        float var = stats[HD + c] * invn - mu * mu;
        float s = gamma[c] * rsqrtf(var + BN_EPS);
        sc[q] = s;
        sh[q] = beta[c] - mu * s;
    }
    int beg = gstart[g], end = gstart[g + 1];
    const uint2* h2 = (const uint2*)h32;
    float4 acc = make_float4(0.f, 0.f, 0.f, 0.f);
    for (int r = beg + p * 8 + ro; r < end; r += PP * 8) {
        uint2 u = h2[(size_t)r * 32 + c4];
        float vals[4] = {bflo(u.x), bfhi(u.x), bflo(u.y), bfhi(u.y)};
#pragma unroll
        for (int q = 0; q < 4; q++) {
            float y = sc[q] * vals[q] + sh[q];
            (&acc.x)[q] += y / (1.f + __expf(-y));
        }
    }
    __shared__ float4 sm[256];
    sm[t] = acc;
    __syncthreads();
    if (t < 128) {
        float4 o = sm[t + 128];
        sm[t].x += o.x; sm[t].y += o.y; sm[t].z += o.z; sm[t].w += o.w;
    }
    __syncthreads();
    if (t < 64) {
        float4 o = sm[t + 64];
        sm[t].x += o.x; sm[t].y += o.y; sm[t].z += o.z; sm[t].w += o.w;
    }
    __syncthreads();
    if (t < 32) {
        float4 o = sm[t + 32];
        float4 r = sm[t];
        r.x += o.x; r.y += o.y; r.z += o.z; r.w += o.w;
        ((float4*)ppool)[(size_t)blockIdx.x * 32 + t] = r;
    }
}

// ---------- pooling stage 2 + head MLP fused ----------
__global__ void k_pool_head(const float* __restrict__ ppool, const int* __restrict__ gstart,
                            const float* __restrict__ fc1w, const float* __restrict__ fc1b,
                            const float* __restrict__ fc2w, const float* __restrict__ fc2b,
                            float* __restrict__ out) {
    int g = blockIdx.x;
    int t = threadIdx.x;  // 128
    __shared__ float pa[HD];
    float s = 0.f;
    for (int p = 0; p < PP; p++) s += ppool[(size_t)(g * PP + p) * HD + t];
    float cnt = (float)(gstart[g + 1] - gstart[g]);
    pa[t] = s / fmaxf(cnt, 1.0f);
    __syncthreads();
    if (t < 64) {
        float a = fc1b[t];
        for (int k = 0; k < HD; k++) a += pa[k] * fc1w[k * 64 + t];
        a = a / (1.f + __expf(-a));  // SiLU
        float v = a * fc2w[t];
        for (int off = 32; off > 0; off >>= 1) v += __shfl_down(v, off);
        if (t == 0) out[g] = 1.f / (1.f + __expf(-(v + fc2b[0])));
    }
}

extern "C" void kernel_launch(void* const* d_in, const int* in_sizes, int n_in,
                              void* d_out, int out_size, void* d_ws, size_t ws_size,
                              hipStream_t stream) {
    const float* x = (const float*)d_in[0];
    const int* ei = (const int*)d_in[1];  // [2, E]: row=ei[0..E), col=ei[E..2E)
    const float* ea = (const float*)d_in[2];
    const int* batch = (const int*)d_in[3];
    const float* conv0_w = (const float*)d_in[5];
    const float* conv0_b = (const float*)d_in[6];
    const float* conv_ws = (const float*)d_in[7];
    const float* conv_bs = (const float*)d_in[8];
    const float* bn_gamma = (const float*)d_in[9];
    const float* bn_beta = (const float*)d_in[10];
    const float* fc1w = (const float*)d_in[11];
    const float* fc1b = (const float*)d_in[12];
    const float* fc2w = (const float*)d_in[13];
    const float* fc2b = (const float*)d_in[14];
    float* out = (float*)d_out;

    char* ws = (char*)d_ws;
    size_t off = 0;
    auto alloc = [&](size_t bytes) -> char* {
        char* p = ws + off;
        off = (off + bytes + 255) & ~(size_t)255;
        return p;
    };
    float* dinv = (float*)alloc(NN * 4);
    int* fill = (int*)alloc(NN * 4);
    int* col_ptr = (int*)alloc((NN + 1) * 4);
    int* pos = (int*)alloc(NE * 4);
    int2* sw = (int2*)alloc(((size_t)NE + 8 * NN) * 8);  // padded CSR
    unsigned* mbuf = (unsigned*)alloc((size_t)NN * HD * 2);
    unsigned* hA = (unsigned*)alloc((size_t)NN * HD * 2);
    unsigned* hB = (unsigned*)alloc((size_t)NN * HD * 2);
    unsigned* wbf = (unsigned*)alloc((size_t)NWFU * 4);
    float* stats = (float*)alloc(4 * 2 * HD * 4);
    float* ppool = (float*)alloc((size_t)NGR * PP * HD * 4);
    int* gstart = (int*)alloc((NGR + 1) * 4);
    int* bsum = (int*)alloc(SCB * 4);
    int* boff = (int*)alloc((SCB + 1) * 4);

    k_init<<<(NN + 255) / 256, 256, 0, stream>>>(fill, stats, conv_ws, wbf);
    k_pos<<<(NE + 255) / 256, 256, 0, stream>>>(ei, fill, pos);
    k_scan1<<<SCB, SCT, 0, stream>>>(fill, bsum);
    k_scan2_gb<<<2, SCB, 0, stream>>>(bsum, boff, batch, gstart);
    k_scan3<<<SCB, SCT, 0, stream>>>(fill, boff, col_ptr);
    k_scatter<<<(NE + 255) / 256, 256, 0, stream>>>(ei, ea, col_ptr, pos, sw);
    k_degsum<<<(NN + 255) / 256, 256, 0, stream>>>(col_ptr, fill, sw, dinv);

    float* st0 = stats;
    float* st1 = stats + 2 * HD;
    float* st2 = stats + 4 * HD;
    float* st3 = stats + 6 * HD;
    const int NG128 = (NN + BM - 1) / BM;
    const uint4* wf = (const uint4*)wbf;  // 2048 uint4 per layer

    // L0 (agg fuses weight normalization + BN0 stats)
    k_gemm0<<<(NN + 3) / 4, 256, 0, stream>>>(x, conv0_w, mbuf);
    k_agg<true><<<AGB, 1024, 0, stream>>>(mbuf, col_ptr, sw, dinv, conv0_b, hA, st0);
    // L1
    k_gemm128<<<NG128, 256, 0, stream>>>(hA, st0, bn_gamma, bn_beta, wf,
                                         (unsigned short*)mbuf);
    k_agg<false><<<AGB, 1024, 0, stream>>>(mbuf, col_ptr, sw, dinv, conv_bs, hB, st1);
    // L2
    k_gemm128<<<NG128, 256, 0, stream>>>(hB, st1, bn_gamma + HD, bn_beta + HD, wf + 2048,
                                         (unsigned short*)mbuf);
    k_agg<false><<<AGB, 1024, 0, stream>>>(mbuf, col_ptr, sw, dinv, conv_bs + HD, hA, st2);
    // L3
    k_gemm128<<<NG128, 256, 0, stream>>>(hA, st2, bn_gamma + 2 * HD, bn_beta + 2 * HD,
                                         wf + 4096, (unsigned short*)mbuf);
    k_agg<false><<<AGB, 1024, 0, stream>>>(mbuf, col_ptr, sw, dinv, conv_bs + 2 * HD, hB,
                                           st3);
    // fused final BN+SiLU + pool + head
    k_poolp<<<NGR * PP, 256, 0, stream>>>(hB, st3, bn_gamma + 3 * HD, bn_beta + 3 * HD,
                                          gstart, ppool);
    k_pool_head<<<NGR, HD, 0, stream>>>(ppool, gstart, fc1w, fc1b, fc2w, fc2b, out);
}